// Round 2
// baseline (1721.479 us; speedup 1.0000x reference)
//
#include <hip/hip_runtime.h>
#include <hip/hip_bf16.h>

// ---------------------------------------------------------------------------
// Swin block ×2 + CrossAttnFFN. FP32 inputs/outputs (per reference dtype),
// bf16 MFMA GEMMs with fp32 accumulation, fp32 residual stream.
// ---------------------------------------------------------------------------

typedef unsigned short u16;
typedef u16  u16x4 __attribute__((ext_vector_type(4)));
typedef u16  u16x8 __attribute__((ext_vector_type(8)));
typedef short s16x8 __attribute__((ext_vector_type(8)));
typedef float f32x4 __attribute__((ext_vector_type(4)));

static __device__ __forceinline__ float bf2f(u16 u) {
    union { unsigned int i; float f; } v; v.i = ((unsigned int)u) << 16; return v.f;
}
static __device__ __forceinline__ u16 f2bf(float f) {
    unsigned int x = __float_as_uint(f);
    unsigned int r = x + 0x7fffu + ((x >> 16) & 1u);   // RNE
    return (u16)(r >> 16);
}

// ---------------------------------------------------------------------------
// Fused fp32 -> bf16 conversion of all GEMM operand tensors (8 weights + query).
// Quad-granular; segment boundaries are all multiples of 4 elements.
// ---------------------------------------------------------------------------
__launch_bounds__(256)
__global__ void cvt_weights(const float* __restrict__ qkvw, const float* __restrict__ outw,
                            const float* __restrict__ f1w,  const float* __restrict__ f2w,
                            const float* __restrict__ cpq,  const float* __restrict__ cfc,
                            const float* __restrict__ cf1,  const float* __restrict__ cf2,
                            const float* __restrict__ qry,  u16* __restrict__ dst) {
    const int q = blockIdx.x * 256 + threadIdx.x;      // quad index, < 557056
    const int gid = q * 4;
    const float* s; int off;
    if      (gid <  393216) { s = qkvw; off = 0;       }
    else if (gid <  524288) { s = outw; off = 393216;  }
    else if (gid < 1048576) { s = f1w;  off = 524288;  }
    else if (gid < 1572864) { s = f2w;  off = 1048576; }
    else if (gid < 1638400) { s = cpq;  off = 1572864; }
    else if (gid < 1703936) { s = cfc;  off = 1638400; }
    else if (gid < 1835008) { s = cf1;  off = 1703936; }
    else if (gid < 1966080) { s = cf2;  off = 1835008; }
    else                    { s = qry;  off = 1966080; }
    float4 v = *(const float4*)(s + (gid - off));
    u16x4 o; o[0] = f2bf(v.x); o[1] = f2bf(v.y); o[2] = f2bf(v.z); o[3] = f2bf(v.w);
    *(u16x4*)(dst + gid) = o;
}

__launch_bounds__(256)
__global__ void cvt_f2b(const float* __restrict__ s, u16* __restrict__ d, int n) {
    const int i = (blockIdx.x * 256 + threadIdx.x) * 4;
    if (i >= n) return;
    float4 v = *(const float4*)(s + i);
    u16x4 o; o[0] = f2bf(v.x); o[1] = f2bf(v.y); o[2] = f2bf(v.z); o[3] = f2bf(v.w);
    *(u16x4*)(d + i) = o;
}

// ---------------------------------------------------------------------------
// LayerNorm: one wave per row, C=256 (4 elems/lane). fp32 in -> bf16 out.
// ---------------------------------------------------------------------------
__launch_bounds__(256)
__global__ void ln_kernel(const float* __restrict__ in, u16* __restrict__ out,
                          const float* __restrict__ g, const float* __restrict__ b,
                          int rows) {
    const int wave = threadIdx.x >> 6, lane = threadIdx.x & 63;
    const int row = blockIdx.x * 4 + wave;
    if (row >= rows) return;
    const int c = lane * 4;
    float4 v = *(const float4*)(in + (size_t)row * 256 + c);
    float s1 = v.x + v.y + v.z + v.w;
    float s2 = v.x*v.x + v.y*v.y + v.z*v.z + v.w*v.w;
    #pragma unroll
    for (int off = 32; off; off >>= 1) {
        s1 += __shfl_xor(s1, off);
        s2 += __shfl_xor(s2, off);
    }
    const float mean = s1 * (1.f/256.f);
    const float var  = s2 * (1.f/256.f) - mean*mean;
    const float rstd = rsqrtf(var + 1e-5f);
    float4 gg = *(const float4*)(g + c);
    float4 bb = *(const float4*)(b + c);
    u16x4 og;
    og[0] = f2bf((v.x-mean)*rstd*gg.x + bb.x);
    og[1] = f2bf((v.y-mean)*rstd*gg.y + bb.y);
    og[2] = f2bf((v.z-mean)*rstd*gg.z + bb.z);
    og[3] = f2bf((v.w-mean)*rstd*gg.w + bb.w);
    *(u16x4*)(out + (size_t)row * 256 + c) = og;
}

// ---------------------------------------------------------------------------
// GEMM: out[M,N] = A[M,K] @ W[N,K]^T (+ epilogue). A,W bf16; bias/resid fp32.
// Tile 64x64, BK=64, 4 waves (each 32x32 via 2x2 16x16x32 MFMA fragments).
// EPI: 0 none, 1 +bias, 2 +bias+gelu, 3 +bias+resid, 4 +bias+relu, 5 +bias+clip32
// F32O: write float, else bf16.
// ---------------------------------------------------------------------------
template<int EPI, bool F32O>
__launch_bounds__(256)
__global__ void gemm_bt(const u16* __restrict__ A, const u16* __restrict__ W,
                        const float* __restrict__ bias, const float* __restrict__ resid,
                        void* __restrict__ outv, int M, int N, int K) {
    __shared__ u16 As[64][72];   // row stride 144B (16B-aligned)
    __shared__ u16 Bs[64][72];
    const int m0 = blockIdx.y * 64;
    const int n0 = blockIdx.x * 64;
    const int tid = threadIdx.x;
    const int lane = tid & 63, wave = tid >> 6;
    const int wm = (wave >> 1) * 32, wn = (wave & 1) * 32;

    f32x4 acc[2][2];
    #pragma unroll
    for (int i = 0; i < 2; ++i)
        #pragma unroll
        for (int j = 0; j < 2; ++j)
            acc[i][j] = f32x4{0.f, 0.f, 0.f, 0.f};

    for (int k0 = 0; k0 < K; k0 += 64) {
        #pragma unroll
        for (int rep = 0; rep < 2; ++rep) {
            int i = tid + rep * 256;
            int r = i >> 3, c = (i & 7) * 8;
            *(s16x8*)&As[r][c] = *(const s16x8*)&A[(size_t)(m0 + r) * K + k0 + c];
            *(s16x8*)&Bs[r][c] = *(const s16x8*)&W[(size_t)(n0 + r) * K + k0 + c];
        }
        __syncthreads();
        #pragma unroll
        for (int kk = 0; kk < 64; kk += 32) {
            s16x8 af[2], bfr[2];
            #pragma unroll
            for (int i = 0; i < 2; ++i) {
                af[i]  = *(const s16x8*)&As[wm + i*16 + (lane & 15)][kk + (lane >> 4) * 8];
                bfr[i] = *(const s16x8*)&Bs[wn + i*16 + (lane & 15)][kk + (lane >> 4) * 8];
            }
            #pragma unroll
            for (int mi = 0; mi < 2; ++mi)
                #pragma unroll
                for (int ni = 0; ni < 2; ++ni)
                    acc[mi][ni] = __builtin_amdgcn_mfma_f32_16x16x32_bf16(
                        af[mi], bfr[ni], acc[mi][ni], 0, 0, 0);
        }
        __syncthreads();
    }

    // epilogue: D row = (lane>>4)*4 + j, col = lane&15  [guide §3, m89]
    #pragma unroll
    for (int mi = 0; mi < 2; ++mi) {
        #pragma unroll
        for (int ni = 0; ni < 2; ++ni) {
            const int col = n0 + wn + ni*16 + (lane & 15);
            #pragma unroll
            for (int j = 0; j < 4; ++j) {
                const int row = m0 + wm + mi*16 + (lane >> 4)*4 + j;
                float v = acc[mi][ni][j];
                if (EPI >= 1) v += bias[col];
                if (EPI == 2) v = 0.5f * v * (1.f + erff(v * 0.70710678118654752f));
                if (EPI == 3) v += resid[(size_t)row * N + col];
                if (EPI == 4) v = fmaxf(v, 0.f);
                if (EPI == 5) v = fminf(fmaxf(v, -32.f), 32.f);
                if (F32O) ((float*)outv)[(size_t)row * N + col] = v;
                else      ((u16*)outv)[(size_t)row * N + col]   = f2bf(v);
            }
        }
    }
}

// ---------------------------------------------------------------------------
// Windowed self-attention + relative position bias.
// 1 wave per (window, head). lane = query token (ty,tx) in 8x8 window.
// qkv: (B*L, 768) bf16, natural token order; q[0:256] k[256:512] v[512:768].
// ---------------------------------------------------------------------------
__launch_bounds__(64)
__global__ void win_attn(const u16* __restrict__ qkv, const float* __restrict__ rb,
                         u16* __restrict__ o) {
    __shared__ float ksh[64][33];
    __shared__ float vsh[64][33];
    __shared__ float bsh[1800];     // (225,8) rel bias
    const int lane = threadIdx.x;
    const int head = blockIdx.x & 7;
    const int win  = blockIdx.x >> 3;
    const int b = win >> 8, wy = (win >> 4) & 15, wx = win & 15;
    const int ty = lane >> 3, tx = lane & 7;
    const size_t row = (size_t)b * 16384 + (size_t)(wy*8 + ty) * 128 + (wx*8 + tx);
    const u16* base = qkv + row * 768;

    for (int i = lane; i < 1800; i += 64) bsh[i] = rb[i];

    float q[32];
    {
        const u16* qp = base + head * 32;
        const u16* kp = base + 256 + head * 32;
        const u16* vp = base + 512 + head * 32;
        #pragma unroll
        for (int gix = 0; gix < 4; ++gix) {
            u16x8 qv = *(const u16x8*)(qp + gix*8);
            u16x8 kv = *(const u16x8*)(kp + gix*8);
            u16x8 vv = *(const u16x8*)(vp + gix*8);
            #pragma unroll
            for (int j = 0; j < 8; ++j) {
                q[gix*8 + j] = bf2f(qv[j]);
                ksh[lane][gix*8 + j] = bf2f(kv[j]);
                vsh[lane][gix*8 + j] = bf2f(vv[j]);
            }
        }
    }
    __syncthreads();

    const float scale = 0.17677669529663687f;   // 1/sqrt(32)
    float mx = -1e30f;
    for (int m = 0; m < 64; ++m) {
        float d = 0.f;
        #pragma unroll
        for (int dd = 0; dd < 32; ++dd) d += q[dd] * ksh[m][dd];
        float s = d * scale + bsh[((ty - (m >> 3) + 7) * 15 + (tx - (m & 7) + 7)) * 8 + head];
        mx = fmaxf(mx, s);
    }
    float sum = 0.f;
    float acc[32];
    #pragma unroll
    for (int dd = 0; dd < 32; ++dd) acc[dd] = 0.f;
    for (int m = 0; m < 64; ++m) {
        float d = 0.f;
        #pragma unroll
        for (int dd = 0; dd < 32; ++dd) d += q[dd] * ksh[m][dd];
        float s = d * scale + bsh[((ty - (m >> 3) + 7) * 15 + (tx - (m & 7) + 7)) * 8 + head];
        float p = __expf(s - mx);
        sum += p;
        #pragma unroll
        for (int dd = 0; dd < 32; ++dd) acc[dd] += p * vsh[m][dd];
    }
    const float inv = 1.f / sum;
    u16* op = o + row * 256 + head * 32;
    #pragma unroll
    for (int dd = 0; dd < 32; ++dd) op[dd] = f2bf(acc[dd] * inv);
}

// ---------------------------------------------------------------------------
// Cross-attention: 1 wave per (b, head, t). K=V = xb[b, :, h*32:+32], Tk=16384.
// Per-lane online softmax over 256 keys, then 64-lane merge.
// ---------------------------------------------------------------------------
__launch_bounds__(256)
__global__ void ca_attn(const u16* __restrict__ qb, const u16* __restrict__ x,
                        u16* __restrict__ ctx) {
    const int gw = (int)((blockIdx.x * 256 + threadIdx.x) >> 6);  // 0..8191
    const int lane = threadIdx.x & 63;
    const int b = gw >> 12, h = (gw >> 9) & 7, t = gw & 511;

    float q[32];
    {
        const u16* qp = qb + ((size_t)t * 2 + b) * 256 + h * 32;
        #pragma unroll
        for (int gix = 0; gix < 4; ++gix) {
            u16x8 v = *(const u16x8*)(qp + gix*8);
            #pragma unroll
            for (int j = 0; j < 8; ++j) q[gix*8 + j] = bf2f(v[j]);
        }
    }
    const u16* kb = x + (size_t)b * 16384 * 256 + h * 32;
    const float scale = 0.17677669529663687f;

    float m = -1e30f, denom = 0.f;
    float acc[32];
    #pragma unroll
    for (int d = 0; d < 32; ++d) acc[d] = 0.f;

    for (int it = 0; it < 256; ++it) {
        const u16* kp = kb + (size_t)(it * 64 + lane) * 256;
        float kv[32];
        #pragma unroll
        for (int gix = 0; gix < 4; ++gix) {
            u16x8 v = *(const u16x8*)(kp + gix*8);
            #pragma unroll
            for (int j = 0; j < 8; ++j) kv[gix*8 + j] = bf2f(v[j]);
        }
        float s = 0.f;
        #pragma unroll
        for (int d = 0; d < 32; ++d) s += q[d] * kv[d];
        s *= scale;
        if (s > m) {
            const float c = __expf(m - s);
            denom *= c;
            #pragma unroll
            for (int d = 0; d < 32; ++d) acc[d] *= c;
            m = s;
        }
        const float p = __expf(s - m);
        denom += p;
        #pragma unroll
        for (int d = 0; d < 32; ++d) acc[d] += p * kv[d];
    }

    float gm = m;
    #pragma unroll
    for (int off = 32; off; off >>= 1) gm = fmaxf(gm, __shfl_xor(gm, off));
    const float c = __expf(m - gm);
    denom *= c;
    #pragma unroll
    for (int d = 0; d < 32; ++d) acc[d] *= c;
    #pragma unroll
    for (int off = 32; off; off >>= 1) denom += __shfl_xor(denom, off);
    #pragma unroll
    for (int d = 0; d < 32; ++d) {
        #pragma unroll
        for (int off = 32; off; off >>= 1) acc[d] += __shfl_xor(acc[d], off);
    }
    if (lane == 0) {
        const float inv = 1.f / denom;
        u16* cp = ctx + ((size_t)b * 512 + t) * 256 + h * 32;
        #pragma unroll
        for (int d = 0; d < 32; ++d) cp[d] = f2bf(acc[d] * inv);
    }
}

// ---------------------------------------------------------------------------
// Final: out = LN(query + ctx^T). query fp32 (Tq,B,C), ctx4 bf16 (B,Tq,C).
// ---------------------------------------------------------------------------
__launch_bounds__(256)
__global__ void final_ln(const float* __restrict__ query, const u16* __restrict__ ctx4,
                         const float* __restrict__ g, const float* __restrict__ b,
                         float* __restrict__ out) {
    const int wave = threadIdx.x >> 6, lane = threadIdx.x & 63;
    const int row = blockIdx.x * 4 + wave;        // 0..1023 = t*2+bb
    const int t = row >> 1, bb = row & 1;
    const int c = lane * 4;
    float4 rq = *(const float4*)(query + (size_t)row * 256 + c);
    u16x4 rc = *(const u16x4*)(ctx4 + ((size_t)bb * 512 + t) * 256 + c);
    float x0 = rq.x + bf2f(rc[0]);
    float x1 = rq.y + bf2f(rc[1]);
    float x2 = rq.z + bf2f(rc[2]);
    float x3 = rq.w + bf2f(rc[3]);
    float s1 = x0 + x1 + x2 + x3;
    float s2 = x0*x0 + x1*x1 + x2*x2 + x3*x3;
    #pragma unroll
    for (int off = 32; off; off >>= 1) {
        s1 += __shfl_xor(s1, off);
        s2 += __shfl_xor(s2, off);
    }
    const float mean = s1 * (1.f/256.f);
    const float var  = s2 * (1.f/256.f) - mean*mean;
    const float rstd = rsqrtf(var + 1e-5f);
    float4 gg = *(const float4*)(g + c);
    float4 bv = *(const float4*)(b + c);
    float4 og;
    og.x = (x0-mean)*rstd*gg.x + bv.x;
    og.y = (x1-mean)*rstd*gg.y + bv.y;
    og.z = (x2-mean)*rstd*gg.z + bv.z;
    og.w = (x3-mean)*rstd*gg.w + bv.w;
    *(float4*)(out + (size_t)row * 256 + c) = og;
}

// ---------------------------------------------------------------------------

static inline void launch_gemm(int epi, bool f32o, const u16* A, const u16* W,
                               const float* bias, const float* resid, void* out,
                               int M, int N, int K, hipStream_t s) {
    dim3 grid(N / 64, M / 64), blk(256);
    if (f32o) {
        gemm_bt<3, true><<<grid, blk, 0, s>>>(A, W, bias, resid, out, M, N, K);
    } else {
        switch (epi) {
            case 0: gemm_bt<0,false><<<grid, blk, 0, s>>>(A, W, bias, resid, out, M, N, K); break;
            case 1: gemm_bt<1,false><<<grid, blk, 0, s>>>(A, W, bias, resid, out, M, N, K); break;
            case 2: gemm_bt<2,false><<<grid, blk, 0, s>>>(A, W, bias, resid, out, M, N, K); break;
            case 4: gemm_bt<4,false><<<grid, blk, 0, s>>>(A, W, bias, resid, out, M, N, K); break;
            case 5: gemm_bt<5,false><<<grid, blk, 0, s>>>(A, W, bias, resid, out, M, N, K); break;
        }
    }
}

extern "C" void kernel_launch(void* const* d_in, const int* in_sizes, int n_in,
                              void* d_out, int out_size, void* d_ws, size_t ws_size,
                              hipStream_t stream) {
    const float* x_in  = (const float*)d_in[0];
    const float* query = (const float*)d_in[1];
    const float* n1_g  = (const float*)d_in[2];
    const float* n1_b  = (const float*)d_in[3];
    const float* qkv_w = (const float*)d_in[4];
    const float* qkv_b = (const float*)d_in[5];
    const float* out_w = (const float*)d_in[6];
    const float* out_b = (const float*)d_in[7];
    const float* rel   = (const float*)d_in[8];
    const float* n2_g  = (const float*)d_in[9];
    const float* n2_b  = (const float*)d_in[10];
    const float* fc1_w = (const float*)d_in[11];
    const float* fc1_b = (const float*)d_in[12];
    const float* fc2_w = (const float*)d_in[13];
    const float* fc2_b = (const float*)d_in[14];
    const float* can_g = (const float*)d_in[15];
    const float* can_b = (const float*)d_in[16];
    const float* cpq_w = (const float*)d_in[17];
    const float* cfc_w = (const float*)d_in[18];
    const float* cfc_b = (const float*)d_in[19];
    const float* cf1_w = (const float*)d_in[20];
    const float* cf1_b = (const float*)d_in[21];
    const float* cf2_w = (const float*)d_in[22];
    const float* cf2_b = (const float*)d_in[23];

    const int M = 32768;   // 2 * 128 * 128 tokens

    char* w = (char*)d_ws;
    float* xs  = (float*)w;  w += (size_t)M * 256 * 4;        // fp32 residual stream
    u16* hbuf  = (u16*)w;    w += (size_t)M * 256 * 2;        // bf16 LN/attn out
    u16* big   = (u16*)w;    w += (size_t)M * 1024 * 2;       // bf16 qkv / mlp hidden
    u16* arena = (u16*)w;    w += (size_t)2228224 * 2;        // bf16 weights + query
    u16* qbuf  = (u16*)w;    w += 524288;
    u16* ctx1  = (u16*)w;    w += 524288;
    u16* ctx2  = (u16*)w;    w += 524288;
    u16* ctx3  = (u16*)w;    w += 1048576;
    u16* ctx4  = (u16*)w;    w += 524288;
    u16* xb    = (u16*)w;    w += (size_t)M * 256 * 2;        // bf16 copy of final xs

    u16* wq   = arena;            // 393216
    u16* wo   = arena + 393216;   // 131072
    u16* wf1  = arena + 524288;   // 524288
    u16* wf2  = arena + 1048576;  // 524288
    u16* wcpq = arena + 1572864;  // 65536
    u16* wcfc = arena + 1638400;  // 65536
    u16* wcf1 = arena + 1703936;  // 131072
    u16* wcf2 = arena + 1835008;  // 131072
    u16* qcvt = arena + 1966080;  // 262144

    cvt_weights<<<2176, 256, 0, stream>>>(qkv_w, out_w, fc1_w, fc2_w, cpq_w,
                                          cfc_w, cf1_w, cf2_w, query, arena);
    hipMemcpyAsync(xs, x_in, (size_t)M * 256 * 4, hipMemcpyDeviceToDevice, stream);

    for (int i = 0; i < 2; ++i) {
        ln_kernel<<<M/4, 256, 0, stream>>>(xs, hbuf, n1_g + i*256, n1_b + i*256, M);
        launch_gemm(1, false, hbuf, wq + (size_t)i*768*256, qkv_b + i*768, nullptr,
                    big, M, 768, 256, stream);
        win_attn<<<4096, 64, 0, stream>>>(big, rel + i*1800, hbuf);
        launch_gemm(3, true, hbuf, wo + (size_t)i*65536, out_b + i*256, xs,
                    xs, M, 256, 256, stream);
        ln_kernel<<<M/4, 256, 0, stream>>>(xs, hbuf, n2_g + i*256, n2_b + i*256, M);
        launch_gemm(2, false, hbuf, wf1 + (size_t)i*262144, fc1_b + i*1024, nullptr,
                    big, M, 1024, 256, stream);
        launch_gemm(3, true, big, wf2 + (size_t)i*262144, fc2_b + i*256, xs,
                    xs, M, 256, 1024, stream);
    }

    // cross-attention
    cvt_f2b<<<(M*256)/1024, 256, 0, stream>>>(xs, xb, M * 256);
    launch_gemm(0, false, qcvt, wcpq, nullptr, nullptr, qbuf, 1024, 256, 256, stream);
    ca_attn<<<2048, 256, 0, stream>>>(qbuf, xb, ctx1);
    launch_gemm(5, false, ctx1, wcfc, cfc_b, nullptr, ctx2, 1024, 256, 256, stream);
    launch_gemm(4, false, ctx2, wcf1, cf1_b, nullptr, ctx3, 1024, 512, 256, stream);
    launch_gemm(1, false, ctx3, wcf2, cf2_b, nullptr, ctx4, 1024, 256, 512, stream);
    final_ln<<<256, 256, 0, stream>>>(query, ctx4, can_g, can_b, (float*)d_out);

    (void)in_sizes; (void)n_in; (void)out_size; (void)ws_size;
}

// Round 3
// 753.850 us; speedup vs baseline: 2.2836x; 2.2836x over previous
//
#include <hip/hip_runtime.h>
#include <hip/hip_bf16.h>

// ---------------------------------------------------------------------------
// Swin block ×2 + CrossAttnFFN. FP32 inputs/outputs, bf16 MFMA GEMMs with
// fp32 accumulation, fp32 residual stream.
// Round 3: MFMA flash cross-attention (was 1067 µs scalar ca_attn),
//          register-scores win_attn.
// ---------------------------------------------------------------------------

typedef unsigned short u16;
typedef u16  u16x4 __attribute__((ext_vector_type(4)));
typedef u16  u16x8 __attribute__((ext_vector_type(8)));
typedef short s16x8 __attribute__((ext_vector_type(8)));
typedef float f32x4 __attribute__((ext_vector_type(4)));
typedef unsigned int u32x4 __attribute__((ext_vector_type(4)));

static __device__ __forceinline__ float bf2f(u16 u) {
    union { unsigned int i; float f; } v; v.i = ((unsigned int)u) << 16; return v.f;
}
static __device__ __forceinline__ u16 f2bf(float f) {
    unsigned int x = __float_as_uint(f);
    unsigned int r = x + 0x7fffu + ((x >> 16) & 1u);   // RNE
    return (u16)(r >> 16);
}

// ---------------------------------------------------------------------------
// Fused fp32 -> bf16 conversion of all GEMM operand tensors (8 weights + query).
// ---------------------------------------------------------------------------
__launch_bounds__(256)
__global__ void cvt_weights(const float* __restrict__ qkvw, const float* __restrict__ outw,
                            const float* __restrict__ f1w,  const float* __restrict__ f2w,
                            const float* __restrict__ cpq,  const float* __restrict__ cfc,
                            const float* __restrict__ cf1,  const float* __restrict__ cf2,
                            const float* __restrict__ qry,  u16* __restrict__ dst) {
    const int q = blockIdx.x * 256 + threadIdx.x;      // quad index, < 557056
    const int gid = q * 4;
    const float* s; int off;
    if      (gid <  393216) { s = qkvw; off = 0;       }
    else if (gid <  524288) { s = outw; off = 393216;  }
    else if (gid < 1048576) { s = f1w;  off = 524288;  }
    else if (gid < 1572864) { s = f2w;  off = 1048576; }
    else if (gid < 1638400) { s = cpq;  off = 1572864; }
    else if (gid < 1703936) { s = cfc;  off = 1638400; }
    else if (gid < 1835008) { s = cf1;  off = 1703936; }
    else if (gid < 1966080) { s = cf2;  off = 1835008; }
    else                    { s = qry;  off = 1966080; }
    float4 v = *(const float4*)(s + (gid - off));
    u16x4 o; o[0] = f2bf(v.x); o[1] = f2bf(v.y); o[2] = f2bf(v.z); o[3] = f2bf(v.w);
    *(u16x4*)(dst + gid) = o;
}

__launch_bounds__(256)
__global__ void cvt_f2b(const float* __restrict__ s, u16* __restrict__ d, int n) {
    const int i = (blockIdx.x * 256 + threadIdx.x) * 4;
    if (i >= n) return;
    float4 v = *(const float4*)(s + i);
    u16x4 o; o[0] = f2bf(v.x); o[1] = f2bf(v.y); o[2] = f2bf(v.z); o[3] = f2bf(v.w);
    *(u16x4*)(d + i) = o;
}

// ---------------------------------------------------------------------------
// Transpose: xbT[b][c][n] = xb[b][n][c].  b=2, n=16384, c=256.
// ---------------------------------------------------------------------------
__launch_bounds__(256)
__global__ void tr_kernel(const u16* __restrict__ src, u16* __restrict__ dst) {
    __shared__ u16 T[64][72];
    const int b = blockIdx.z;
    const int n0 = blockIdx.x * 64, c0 = blockIdx.y * 64;
    const int r = threadIdx.x >> 3, cc = (threadIdx.x & 7) * 8;
    const u16* S = src + (size_t)b * 16384 * 256;
    u16* D = dst + (size_t)b * 256 * 16384;
    #pragma unroll
    for (int rr = 0; rr < 64; rr += 32)
        *(u16x8*)&T[r + rr][cc] = *(const u16x8*)&S[(size_t)(n0 + r + rr) * 256 + c0 + cc];
    __syncthreads();
    #pragma unroll
    for (int rr = 0; rr < 64; rr += 32) {
        u16x8 v;
        #pragma unroll
        for (int k2 = 0; k2 < 8; ++k2) v[k2] = T[cc + k2][r + rr];
        *(u16x8*)&D[(size_t)(c0 + r + rr) * 16384 + n0 + cc] = v;
    }
}

// ---------------------------------------------------------------------------
// LayerNorm: one wave per row, C=256. fp32 in -> bf16 out.
// ---------------------------------------------------------------------------
__launch_bounds__(256)
__global__ void ln_kernel(const float* __restrict__ in, u16* __restrict__ out,
                          const float* __restrict__ g, const float* __restrict__ b,
                          int rows) {
    const int wave = threadIdx.x >> 6, lane = threadIdx.x & 63;
    const int row = blockIdx.x * 4 + wave;
    if (row >= rows) return;
    const int c = lane * 4;
    float4 v = *(const float4*)(in + (size_t)row * 256 + c);
    float s1 = v.x + v.y + v.z + v.w;
    float s2 = v.x*v.x + v.y*v.y + v.z*v.z + v.w*v.w;
    #pragma unroll
    for (int off = 32; off; off >>= 1) {
        s1 += __shfl_xor(s1, off);
        s2 += __shfl_xor(s2, off);
    }
    const float mean = s1 * (1.f/256.f);
    const float var  = s2 * (1.f/256.f) - mean*mean;
    const float rstd = rsqrtf(var + 1e-5f);
    float4 gg = *(const float4*)(g + c);
    float4 bb = *(const float4*)(b + c);
    u16x4 og;
    og[0] = f2bf((v.x-mean)*rstd*gg.x + bb.x);
    og[1] = f2bf((v.y-mean)*rstd*gg.y + bb.y);
    og[2] = f2bf((v.z-mean)*rstd*gg.z + bb.z);
    og[3] = f2bf((v.w-mean)*rstd*gg.w + bb.w);
    *(u16x4*)(out + (size_t)row * 256 + c) = og;
}

// ---------------------------------------------------------------------------
// GEMM: out[M,N] = A[M,K] @ W[N,K]^T (+ epilogue). A,W bf16; bias/resid fp32.
// EPI: 0 none, 1 +bias, 2 +bias+gelu, 3 +bias+resid, 4 +bias+relu,
//      5 +bias+clip32, 6 *softmax-scale (no bias)
// ---------------------------------------------------------------------------
template<int EPI, bool F32O>
__launch_bounds__(256)
__global__ void gemm_bt(const u16* __restrict__ A, const u16* __restrict__ W,
                        const float* __restrict__ bias, const float* __restrict__ resid,
                        void* __restrict__ outv, int M, int N, int K) {
    __shared__ u16 As[64][72];
    __shared__ u16 Bs[64][72];
    const int m0 = blockIdx.y * 64;
    const int n0 = blockIdx.x * 64;
    const int tid = threadIdx.x;
    const int lane = tid & 63, wave = tid >> 6;
    const int wm = (wave >> 1) * 32, wn = (wave & 1) * 32;

    f32x4 acc[2][2];
    #pragma unroll
    for (int i = 0; i < 2; ++i)
        #pragma unroll
        for (int j = 0; j < 2; ++j)
            acc[i][j] = f32x4{0.f, 0.f, 0.f, 0.f};

    for (int k0 = 0; k0 < K; k0 += 64) {
        #pragma unroll
        for (int rep = 0; rep < 2; ++rep) {
            int i = tid + rep * 256;
            int r = i >> 3, c = (i & 7) * 8;
            *(s16x8*)&As[r][c] = *(const s16x8*)&A[(size_t)(m0 + r) * K + k0 + c];
            *(s16x8*)&Bs[r][c] = *(const s16x8*)&W[(size_t)(n0 + r) * K + k0 + c];
        }
        __syncthreads();
        #pragma unroll
        for (int kk = 0; kk < 64; kk += 32) {
            s16x8 af[2], bfr[2];
            #pragma unroll
            for (int i = 0; i < 2; ++i) {
                af[i]  = *(const s16x8*)&As[wm + i*16 + (lane & 15)][kk + (lane >> 4) * 8];
                bfr[i] = *(const s16x8*)&Bs[wn + i*16 + (lane & 15)][kk + (lane >> 4) * 8];
            }
            #pragma unroll
            for (int mi = 0; mi < 2; ++mi)
                #pragma unroll
                for (int ni = 0; ni < 2; ++ni)
                    acc[mi][ni] = __builtin_amdgcn_mfma_f32_16x16x32_bf16(
                        af[mi], bfr[ni], acc[mi][ni], 0, 0, 0);
        }
        __syncthreads();
    }

    #pragma unroll
    for (int mi = 0; mi < 2; ++mi) {
        #pragma unroll
        for (int ni = 0; ni < 2; ++ni) {
            const int col = n0 + wn + ni*16 + (lane & 15);
            #pragma unroll
            for (int j = 0; j < 4; ++j) {
                const int row = m0 + wm + mi*16 + (lane >> 4)*4 + j;
                float v = acc[mi][ni][j];
                if (EPI >= 1 && EPI <= 5) v += bias[col];
                if (EPI == 2) v = 0.5f * v * (1.f + erff(v * 0.70710678118654752f));
                if (EPI == 3) v += resid[(size_t)row * N + col];
                if (EPI == 4) v = fmaxf(v, 0.f);
                if (EPI == 5) v = fminf(fmaxf(v, -32.f), 32.f);
                if (EPI == 6) v *= 0.17677669529663687f;
                if (F32O) ((float*)outv)[(size_t)row * N + col] = v;
                else      ((u16*)outv)[(size_t)row * N + col]   = f2bf(v);
            }
        }
    }
}

// ---------------------------------------------------------------------------
// Windowed self-attention + relative position bias.
// 1 wave per (window, head). Scores kept in registers (single dot pass).
// ---------------------------------------------------------------------------
__launch_bounds__(64)
__global__ void win_attn(const u16* __restrict__ qkv, const float* __restrict__ rb,
                         u16* __restrict__ o) {
    __shared__ float ksh[64][33];
    __shared__ float vsh[64][33];
    __shared__ float bsh[1800];     // (225,8) rel bias
    const int lane = threadIdx.x;
    const int head = blockIdx.x & 7;
    const int win  = blockIdx.x >> 3;
    const int b = win >> 8, wy = (win >> 4) & 15, wx = win & 15;
    const int ty = lane >> 3, tx = lane & 7;
    const size_t row = (size_t)b * 16384 + (size_t)(wy*8 + ty) * 128 + (wx*8 + tx);
    const u16* base = qkv + row * 768;

    for (int i = lane; i < 1800; i += 64) bsh[i] = rb[i];

    const float scale = 0.17677669529663687f;   // 1/sqrt(32)
    float q[32];
    {
        const u16* qp = base + head * 32;
        const u16* kp = base + 256 + head * 32;
        const u16* vp = base + 512 + head * 32;
        #pragma unroll
        for (int gix = 0; gix < 4; ++gix) {
            u16x8 qv = *(const u16x8*)(qp + gix*8);
            u16x8 kv = *(const u16x8*)(kp + gix*8);
            u16x8 vv = *(const u16x8*)(vp + gix*8);
            #pragma unroll
            for (int j = 0; j < 8; ++j) {
                q[gix*8 + j] = bf2f(qv[j]) * scale;
                ksh[lane][gix*8 + j] = bf2f(kv[j]);
                vsh[lane][gix*8 + j] = bf2f(vv[j]);
            }
        }
    }
    __syncthreads();

    float sv[64];
    float mx = -1e30f;
    #pragma unroll
    for (int mm = 0; mm < 64; ++mm) {
        float d = 0.f;
        #pragma unroll
        for (int dd = 0; dd < 32; ++dd) d += q[dd] * ksh[mm][dd];
        const float s = d + bsh[((ty - (mm >> 3) + 7) * 15 + (tx - (mm & 7) + 7)) * 8 + head];
        sv[mm] = s;
        mx = fmaxf(mx, s);
    }
    float sum = 0.f;
    float acc[32];
    #pragma unroll
    for (int dd = 0; dd < 32; ++dd) acc[dd] = 0.f;
    #pragma unroll
    for (int mm = 0; mm < 64; ++mm) {
        const float p = __expf(sv[mm] - mx);
        sum += p;
        #pragma unroll
        for (int dd = 0; dd < 32; ++dd) acc[dd] += p * vsh[mm][dd];
    }
    const float inv = 1.f / sum;
    u16* op = o + row * 256 + head * 32;
    #pragma unroll
    for (int dd = 0; dd < 32; ++dd) op[dd] = f2bf(acc[dd] * inv);
}

// ---------------------------------------------------------------------------
// MFMA flash cross-attention.
// Wave = (b, h, qtile of 32 queries, ks of 8 key-splits), 2048 keys per wave.
// S^T = mfma(K, Q) per 32-key step; online softmax (per-q stats via 2 shfl);
// P^T group-exchange -> PV MFMAs into O^T accum. Partials to pbuf.
// qb is pre-scaled by 1/sqrt(32) (projq epilogue EPI=6).
// ---------------------------------------------------------------------------
static __device__ __forceinline__ void ca_step(
    const f32x4& sA, const f32x4& sB, const s16x8& vf0, const s16x8& vf1,
    f32x4& acc0, f32x4& acc1, float& m, float& l, int g, int c)
{
    float smax = fmaxf(fmaxf(fmaxf(sA[0],sA[1]), fmaxf(sA[2],sA[3])),
                       fmaxf(fmaxf(sB[0],sB[1]), fmaxf(sB[2],sB[3])));
    smax = fmaxf(smax, __shfl_xor(smax, 16));
    smax = fmaxf(smax, __shfl_xor(smax, 32));
    const float mnew = fmaxf(m, smax);
    const float cc = __expf(m - mnew);
    float p[8];
    #pragma unroll
    for (int j = 0; j < 4; ++j) { p[j] = __expf(sA[j] - mnew); p[4+j] = __expf(sB[j] - mnew); }
    float ss = ((p[0]+p[1]) + (p[2]+p[3])) + ((p[4]+p[5]) + (p[6]+p[7]));
    ss += __shfl_xor(ss, 16);
    ss += __shfl_xor(ss, 32);
    l = l * cc + ss;
    #pragma unroll
    for (int j = 0; j < 4; ++j) { acc0[j] *= cc; acc1[j] *= cc; }
    m = mnew;
    // pack P (bf16 pairs): u[mi][w] covers keys 16*mi + 4g + {0..3}
    const unsigned int u00 = (unsigned int)f2bf(p[0]) | ((unsigned int)f2bf(p[1]) << 16);
    const unsigned int u01 = (unsigned int)f2bf(p[2]) | ((unsigned int)f2bf(p[3]) << 16);
    const unsigned int u10 = (unsigned int)f2bf(p[4]) | ((unsigned int)f2bf(p[5]) << 16);
    const unsigned int u11 = (unsigned int)f2bf(p[6]) | ((unsigned int)f2bf(p[7]) << 16);
    // exchange: dest lane (g,c) needs keys 8g+0..7 at query c
    const int srcA = ((g & 1) * 2) * 16 + c;   // source group 2*(g&1)
    const int srcB = srcA + 16;                // source group 2*(g&1)+1
    const unsigned int a0 = __shfl((int)u00, srcA), a1 = __shfl((int)u01, srcA);
    const unsigned int a2 = __shfl((int)u10, srcA), a3 = __shfl((int)u11, srcA);
    const unsigned int b0 = __shfl((int)u00, srcB), b1 = __shfl((int)u01, srcB);
    const unsigned int b2 = __shfl((int)u10, srcB), b3 = __shfl((int)u11, srcB);
    const bool hi = (g >> 1) != 0;             // frag selector = dest's key>>4
    u32x4 w;
    w[0] = hi ? a2 : a0;  w[1] = hi ? a3 : a1;
    w[2] = hi ? b2 : b0;  w[3] = hi ? b3 : b1;
    const s16x8 pf = __builtin_bit_cast(s16x8, w);
    acc0 = __builtin_amdgcn_mfma_f32_16x16x32_bf16(vf0, pf, acc0, 0, 0, 0);
    acc1 = __builtin_amdgcn_mfma_f32_16x16x32_bf16(vf1, pf, acc1, 0, 0, 0);
}

__launch_bounds__(256)
__global__ void ca_flash(const u16* __restrict__ qb, const u16* __restrict__ xb,
                         const u16* __restrict__ xbT, float* __restrict__ pbuf) {
    const int wid = blockIdx.x * 4 + (threadIdx.x >> 6);   // 0..2047
    const int lane = threadIdx.x & 63;
    const int ks = wid & 7, qt = (wid >> 3) & 15, h = (wid >> 7) & 7, b = wid >> 10;
    const int g = lane >> 4, c = lane & 15;

    s16x8 qf[2];
    #pragma unroll
    for (int nt = 0; nt < 2; ++nt) {
        const int q = qt * 32 + nt * 16 + c;
        qf[nt] = *(const s16x8*)&qb[((size_t)q * 2 + b) * 256 + h * 32 + g * 8];
    }
    const u16* Kb = xb  + (size_t)b * 16384 * 256 + h * 32;
    const u16* Vb = xbT + (size_t)b * 256 * 16384 + (size_t)(h * 32) * 16384;

    float m[2] = {-1e30f, -1e30f}, l[2] = {0.f, 0.f};
    f32x4 acc[2][2];   // [mi=d-tile][nt=q-tile]
    #pragma unroll
    for (int i = 0; i < 2; ++i)
        #pragma unroll
        for (int j = 0; j < 2; ++j)
            acc[i][j] = f32x4{0.f, 0.f, 0.f, 0.f};

    const int base = ks * 2048;
    const f32x4 zero = f32x4{0.f, 0.f, 0.f, 0.f};
    for (int step = 0; step < 64; ++step) {
        const int n0 = base + step * 32;
        const s16x8 kf0 = *(const s16x8*)&Kb[(size_t)(n0 + c) * 256 + g * 8];
        const s16x8 kf1 = *(const s16x8*)&Kb[(size_t)(n0 + 16 + c) * 256 + g * 8];
        const s16x8 vf0 = *(const s16x8*)&Vb[(size_t)c * 16384 + n0 + g * 8];
        const s16x8 vf1 = *(const s16x8*)&Vb[(size_t)(16 + c) * 16384 + n0 + g * 8];
        const f32x4 s00 = __builtin_amdgcn_mfma_f32_16x16x32_bf16(kf0, qf[0], zero, 0, 0, 0);
        const f32x4 s01 = __builtin_amdgcn_mfma_f32_16x16x32_bf16(kf1, qf[0], zero, 0, 0, 0);
        const f32x4 s10 = __builtin_amdgcn_mfma_f32_16x16x32_bf16(kf0, qf[1], zero, 0, 0, 0);
        const f32x4 s11 = __builtin_amdgcn_mfma_f32_16x16x32_bf16(kf1, qf[1], zero, 0, 0, 0);
        ca_step(s00, s01, vf0, vf1, acc[0][0], acc[1][0], m[0], l[0], g, c);
        ca_step(s10, s11, vf0, vf1, acc[0][1], acc[1][1], m[1], l[1], g, c);
    }

    float* P = pbuf + (size_t)wid * 1088;
    if (g == 0) {
        P[c]      = m[0];  P[16 + c] = m[1];
        P[32 + c] = l[0];  P[48 + c] = l[1];
    }
    #pragma unroll
    for (int mi = 0; mi < 2; ++mi)
        #pragma unroll
        for (int nt = 0; nt < 2; ++nt)
            *(f32x4*)&P[64 + (c + 16*nt) * 32 + 16*mi + g*4] = acc[mi][nt];
}

// ---------------------------------------------------------------------------
// Merge 8 key-split partials -> ctx (b, Tq, C) bf16.
// ---------------------------------------------------------------------------
__launch_bounds__(256)
__global__ void ca_merge(const float* __restrict__ pbuf, u16* __restrict__ ctx) {
    const int wave = threadIdx.x >> 6, lane = threadIdx.x & 63;
    const int sub = lane >> 5, d = lane & 31;
    const int rowid = blockIdx.x * 8 + wave * 2 + sub;     // 0..8191
    const int q = rowid & 31, qt = (rowid >> 5) & 15, h = (rowid >> 9) & 7, b = rowid >> 12;
    const size_t w0 = (size_t)((b * 8 + h) * 16 + qt) * 8;
    float mv[8], lv[8];
    float M = -1e30f;
    #pragma unroll
    for (int i = 0; i < 8; ++i) {
        mv[i] = pbuf[(w0 + i) * 1088 + q];
        lv[i] = pbuf[(w0 + i) * 1088 + 32 + q];
        M = fmaxf(M, mv[i]);
    }
    float L = 0.f, o = 0.f;
    #pragma unroll
    for (int i = 0; i < 8; ++i) {
        const float e = __expf(mv[i] - M);
        L += lv[i] * e;
        o += e * pbuf[(w0 + i) * 1088 + 64 + q * 32 + d];
    }
    const int t = qt * 32 + q;
    ctx[((size_t)b * 512 + t) * 256 + h * 32 + d] = f2bf(o / L);
}

// ---------------------------------------------------------------------------
// Final: out = LN(query + ctx^T). query fp32 (Tq,B,C), ctx4 bf16 (B,Tq,C).
// ---------------------------------------------------------------------------
__launch_bounds__(256)
__global__ void final_ln(const float* __restrict__ query, const u16* __restrict__ ctx4,
                         const float* __restrict__ g, const float* __restrict__ b,
                         float* __restrict__ out) {
    const int wave = threadIdx.x >> 6, lane = threadIdx.x & 63;
    const int row = blockIdx.x * 4 + wave;        // 0..1023 = t*2+bb
    const int t = row >> 1, bb = row & 1;
    const int c = lane * 4;
    float4 rq = *(const float4*)(query + (size_t)row * 256 + c);
    u16x4 rc = *(const u16x4*)(ctx4 + ((size_t)bb * 512 + t) * 256 + c);
    float x0 = rq.x + bf2f(rc[0]);
    float x1 = rq.y + bf2f(rc[1]);
    float x2 = rq.z + bf2f(rc[2]);
    float x3 = rq.w + bf2f(rc[3]);
    float s1 = x0 + x1 + x2 + x3;
    float s2 = x0*x0 + x1*x1 + x2*x2 + x3*x3;
    #pragma unroll
    for (int off = 32; off; off >>= 1) {
        s1 += __shfl_xor(s1, off);
        s2 += __shfl_xor(s2, off);
    }
    const float mean = s1 * (1.f/256.f);
    const float var  = s2 * (1.f/256.f) - mean*mean;
    const float rstd = rsqrtf(var + 1e-5f);
    float4 gg = *(const float4*)(g + c);
    float4 bv = *(const float4*)(b + c);
    float4 og;
    og.x = (x0-mean)*rstd*gg.x + bv.x;
    og.y = (x1-mean)*rstd*gg.y + bv.y;
    og.z = (x2-mean)*rstd*gg.z + bv.z;
    og.w = (x3-mean)*rstd*gg.w + bv.w;
    *(float4*)(out + (size_t)row * 256 + c) = og;
}

// ---------------------------------------------------------------------------

static inline void launch_gemm(int epi, bool f32o, const u16* A, const u16* W,
                               const float* bias, const float* resid, void* out,
                               int M, int N, int K, hipStream_t s) {
    dim3 grid(N / 64, M / 64), blk(256);
    if (f32o) {
        gemm_bt<3, true><<<grid, blk, 0, s>>>(A, W, bias, resid, out, M, N, K);
    } else {
        switch (epi) {
            case 0: gemm_bt<0,false><<<grid, blk, 0, s>>>(A, W, bias, resid, out, M, N, K); break;
            case 1: gemm_bt<1,false><<<grid, blk, 0, s>>>(A, W, bias, resid, out, M, N, K); break;
            case 2: gemm_bt<2,false><<<grid, blk, 0, s>>>(A, W, bias, resid, out, M, N, K); break;
            case 4: gemm_bt<4,false><<<grid, blk, 0, s>>>(A, W, bias, resid, out, M, N, K); break;
            case 5: gemm_bt<5,false><<<grid, blk, 0, s>>>(A, W, bias, resid, out, M, N, K); break;
            case 6: gemm_bt<6,false><<<grid, blk, 0, s>>>(A, W, bias, resid, out, M, N, K); break;
        }
    }
}

extern "C" void kernel_launch(void* const* d_in, const int* in_sizes, int n_in,
                              void* d_out, int out_size, void* d_ws, size_t ws_size,
                              hipStream_t stream) {
    const float* x_in  = (const float*)d_in[0];
    const float* query = (const float*)d_in[1];
    const float* n1_g  = (const float*)d_in[2];
    const float* n1_b  = (const float*)d_in[3];
    const float* qkv_w = (const float*)d_in[4];
    const float* qkv_b = (const float*)d_in[5];
    const float* out_w = (const float*)d_in[6];
    const float* out_b = (const float*)d_in[7];
    const float* rel   = (const float*)d_in[8];
    const float* n2_g  = (const float*)d_in[9];
    const float* n2_b  = (const float*)d_in[10];
    const float* fc1_w = (const float*)d_in[11];
    const float* fc1_b = (const float*)d_in[12];
    const float* fc2_w = (const float*)d_in[13];
    const float* fc2_b = (const float*)d_in[14];
    const float* can_g = (const float*)d_in[15];
    const float* can_b = (const float*)d_in[16];
    const float* cpq_w = (const float*)d_in[17];
    const float* cfc_w = (const float*)d_in[18];
    const float* cfc_b = (const float*)d_in[19];
    const float* cf1_w = (const float*)d_in[20];
    const float* cf1_b = (const float*)d_in[21];
    const float* cf2_w = (const float*)d_in[22];
    const float* cf2_b = (const float*)d_in[23];

    const int M = 32768;   // 2 * 128 * 128 tokens

    char* w = (char*)d_ws;
    float* xs  = (float*)w;  w += (size_t)M * 256 * 4;        // fp32 residual stream
    u16* hbuf  = (u16*)w;    w += (size_t)M * 256 * 2;        // bf16 LN/attn out
    u16* big   = (u16*)w;    w += (size_t)M * 1024 * 2;       // bf16 qkv / mlp hidden
    u16* arena = (u16*)w;    w += (size_t)2228224 * 2;        // bf16 weights + query
    u16* qbuf  = (u16*)w;    w += 524288;
    u16* ctx1  = (u16*)w;    w += 524288;
    u16* ctx2  = (u16*)w;    w += 524288;
    u16* ctx3  = (u16*)w;    w += 1048576;
    u16* ctx4  = (u16*)w;    w += 524288;
    u16* xb    = (u16*)w;    w += (size_t)M * 256 * 2;        // bf16 copy of final xs

    // CA-phase scratch aliases into `big` (free after the block loop):
    u16*   xbT  = big;                         // (2,256,16384) bf16 = 16 MB
    float* pbuf = (float*)(big + 8388608);     // 2048 partials * 1088 f32 = 8.9 MB

    u16* wq   = arena;            // qkv  (2,768,256)
    u16* wo   = arena + 393216;   // out  (2,256,256)
    u16* wf1  = arena + 524288;   // fc1  (2,1024,256)
    u16* wf2  = arena + 1048576;  // fc2  (2,256,1024)
    u16* wcpq = arena + 1572864;
    u16* wcfc = arena + 1638400;
    u16* wcf1 = arena + 1703936;
    u16* wcf2 = arena + 1835008;
    u16* qcvt = arena + 1966080;  // query bf16 (512,2,256)

    cvt_weights<<<2176, 256, 0, stream>>>(qkv_w, out_w, fc1_w, fc2_w, cpq_w,
                                          cfc_w, cf1_w, cf2_w, query, arena);
    hipMemcpyAsync(xs, x_in, (size_t)M * 256 * 4, hipMemcpyDeviceToDevice, stream);

    for (int i = 0; i < 2; ++i) {
        ln_kernel<<<M/4, 256, 0, stream>>>(xs, hbuf, n1_g + i*256, n1_b + i*256, M);
        launch_gemm(1, false, hbuf, wq + (size_t)i*768*256, qkv_b + i*768, nullptr,
                    big, M, 768, 256, stream);
        win_attn<<<4096, 64, 0, stream>>>(big, rel + i*1800, hbuf);
        launch_gemm(3, true, hbuf, wo + (size_t)i*65536, out_b + i*256, xs,
                    xs, M, 256, 256, stream);
        ln_kernel<<<M/4, 256, 0, stream>>>(xs, hbuf, n2_g + i*256, n2_b + i*256, M);
        launch_gemm(2, false, hbuf, wf1 + (size_t)i*262144, fc1_b + i*1024, nullptr,
                    big, M, 1024, 256, stream);
        launch_gemm(3, true, big, wf2 + (size_t)i*262144, fc2_b + i*256, xs,
                    xs, M, 256, 1024, stream);
    }

    // ---- cross-attention ----
    cvt_f2b<<<(M*256)/1024, 256, 0, stream>>>(xs, xb, M * 256);
    tr_kernel<<<dim3(256, 4, 2), 256, 0, stream>>>(xb, xbT);
    launch_gemm(6, false, qcvt, wcpq, nullptr, nullptr, qbuf, 1024, 256, 256, stream);
    ca_flash<<<512, 256, 0, stream>>>(qbuf, xb, xbT, pbuf);
    ca_merge<<<1024, 256, 0, stream>>>(pbuf, ctx1);
    launch_gemm(5, false, ctx1, wcfc, cfc_b, nullptr, ctx2, 1024, 256, 256, stream);
    launch_gemm(4, false, ctx2, wcf1, cf1_b, nullptr, ctx3, 1024, 512, 256, stream);
    launch_gemm(1, false, ctx3, wcf2, cf2_b, nullptr, ctx4, 1024, 256, 512, stream);
    final_ln<<<256, 256, 0, stream>>>(query, ctx4, can_g, can_b, (float*)d_out);

    (void)in_sizes; (void)n_in; (void)out_size; (void)ws_size;
}

// Round 4
// 539.857 us; speedup vs baseline: 3.1888x; 1.3964x over previous
//
#include <hip/hip_runtime.h>
#include <hip/hip_bf16.h>

// ---------------------------------------------------------------------------
// Swin block ×2 + CrossAttnFFN. FP32 in/out, bf16 MFMA everywhere, fp32 accum.
// Round 4: MFMA win_attn (bias as C-fragment, V^T from qkv epilogue),
//          m97-style 128x128 global_load_lds GEMM for the M=32768 GEMMs.
// ---------------------------------------------------------------------------

typedef unsigned short u16;
typedef u16  u16x4 __attribute__((ext_vector_type(4)));
typedef u16  u16x8 __attribute__((ext_vector_type(8)));
typedef short s16x8 __attribute__((ext_vector_type(8)));
typedef float f32x4 __attribute__((ext_vector_type(4)));
typedef unsigned int u32x4 __attribute__((ext_vector_type(4)));

static __device__ __forceinline__ float bf2f(u16 u) {
    union { unsigned int i; float f; } v; v.i = ((unsigned int)u) << 16; return v.f;
}
static __device__ __forceinline__ u16 f2bf(float f) {
    unsigned int x = __float_as_uint(f);
    unsigned int r = x + 0x7fffu + ((x >> 16) & 1u);   // RNE
    return (u16)(r >> 16);
}
static __device__ __forceinline__ unsigned int packbf(float a, float b) {
    return (unsigned int)f2bf(a) | ((unsigned int)f2bf(b) << 16);
}
static __device__ __forceinline__ void gld16(const u16* g, u16* l) {
    __builtin_amdgcn_global_load_lds(
        (const __attribute__((address_space(1))) unsigned int*)g,
        (__attribute__((address_space(3))) unsigned int*)l, 16, 0, 0);
}

// ---------------------------------------------------------------------------
// fp32 -> bf16 weight/query conversion (one fused kernel).
// ---------------------------------------------------------------------------
__launch_bounds__(256)
__global__ void cvt_weights(const float* __restrict__ qkvw, const float* __restrict__ outw,
                            const float* __restrict__ f1w,  const float* __restrict__ f2w,
                            const float* __restrict__ cpq,  const float* __restrict__ cfc,
                            const float* __restrict__ cf1,  const float* __restrict__ cf2,
                            const float* __restrict__ qry,  u16* __restrict__ dst) {
    const int q = blockIdx.x * 256 + threadIdx.x;
    const int gid = q * 4;
    const float* s; int off;
    if      (gid <  393216) { s = qkvw; off = 0;       }
    else if (gid <  524288) { s = outw; off = 393216;  }
    else if (gid < 1048576) { s = f1w;  off = 524288;  }
    else if (gid < 1572864) { s = f2w;  off = 1048576; }
    else if (gid < 1638400) { s = cpq;  off = 1572864; }
    else if (gid < 1703936) { s = cfc;  off = 1638400; }
    else if (gid < 1835008) { s = cf1;  off = 1703936; }
    else if (gid < 1966080) { s = cf2;  off = 1835008; }
    else                    { s = qry;  off = 1966080; }
    float4 v = *(const float4*)(s + (gid - off));
    u16x4 o; o[0] = f2bf(v.x); o[1] = f2bf(v.y); o[2] = f2bf(v.z); o[3] = f2bf(v.w);
    *(u16x4*)(dst + gid) = o;
}

__launch_bounds__(256)
__global__ void cvt_f2b(const float* __restrict__ s, u16* __restrict__ d, int n) {
    const int i = (blockIdx.x * 256 + threadIdx.x) * 4;
    if (i >= n) return;
    float4 v = *(const float4*)(s + i);
    u16x4 o; o[0] = f2bf(v.x); o[1] = f2bf(v.y); o[2] = f2bf(v.z); o[3] = f2bf(v.w);
    *(u16x4*)(d + i) = o;
}

// ---------------------------------------------------------------------------
// Relative-position bias, pre-arranged into MFMA C-fragment layout.
// bfrag[layer][h][kt][qt][lane][j]; key = kt*16+(lane>>4)*4+j, query = qt*16+(lane&15)
// ---------------------------------------------------------------------------
__launch_bounds__(256)
__global__ void bias_frag_kernel(const float* __restrict__ rel, float* __restrict__ bfrag) {
    const int idx = blockIdx.x * 256 + threadIdx.x;      // 0..16383
    #pragma unroll
    for (int j = 0; j < 4; ++j) {
        const int i = idx * 4 + j;
        const int layer = i >> 15, h = (i >> 12) & 7, kt = (i >> 10) & 3,
                  qt = (i >> 8) & 3, lane = (i >> 2) & 63, jj = i & 3;
        const int key   = kt * 16 + (lane >> 4) * 4 + jj;
        const int query = qt * 16 + (lane & 15);
        const int dy = (query >> 3) - (key >> 3) + 7;
        const int dx = (query & 7)  - (key & 7)  + 7;
        bfrag[i] = rel[layer * 1800 + (dy * 15 + dx) * 8 + h];
    }
}

// ---------------------------------------------------------------------------
// LayerNorm: one wave per row, C=256. fp32 in -> bf16 out.
// ---------------------------------------------------------------------------
__launch_bounds__(256)
__global__ void ln_kernel(const float* __restrict__ in, u16* __restrict__ out,
                          const float* __restrict__ g, const float* __restrict__ b,
                          int rows) {
    const int wave = threadIdx.x >> 6, lane = threadIdx.x & 63;
    const int row = blockIdx.x * 4 + wave;
    if (row >= rows) return;
    const int c = lane * 4;
    float4 v = *(const float4*)(in + (size_t)row * 256 + c);
    float s1 = v.x + v.y + v.z + v.w;
    float s2 = v.x*v.x + v.y*v.y + v.z*v.z + v.w*v.w;
    #pragma unroll
    for (int off = 32; off; off >>= 1) {
        s1 += __shfl_xor(s1, off);
        s2 += __shfl_xor(s2, off);
    }
    const float mean = s1 * (1.f/256.f);
    const float var  = s2 * (1.f/256.f) - mean*mean;
    const float rstd = rsqrtf(var + 1e-5f);
    float4 gg = *(const float4*)(g + c);
    float4 bb = *(const float4*)(b + c);
    u16x4 og;
    og[0] = f2bf((v.x-mean)*rstd*gg.x + bb.x);
    og[1] = f2bf((v.y-mean)*rstd*gg.y + bb.y);
    og[2] = f2bf((v.z-mean)*rstd*gg.z + bb.z);
    og[3] = f2bf((v.w-mean)*rstd*gg.w + bb.w);
    *(u16x4*)(out + (size_t)row * 256 + c) = og;
}

// ---------------------------------------------------------------------------
// 128x128 GEMM (m97 structure): linear LDS + global_load_lds(16B), BK=64,
// 4 waves each computing a 64x64 quadrant (4x4 16x16x32 MFMA frags).
// EPI: 2 +bias+gelu, 3 +bias+resid, 7 qkv (+bias, scale q cols, v cols->vtbuf)
// ---------------------------------------------------------------------------
template<int EPI, bool F32O>
__launch_bounds__(256)
__global__ void gemm128(const u16* __restrict__ A, const u16* __restrict__ W,
                        const float* __restrict__ bias, const float* __restrict__ resid,
                        void* __restrict__ outv, u16* __restrict__ vtbuf,
                        int M, int N, int K) {
    __shared__ u16 As[128 * 64];
    __shared__ u16 Bs[128 * 64];
    const int m0 = blockIdx.y * 128, n0 = blockIdx.x * 128;
    const int tid = threadIdx.x, lane = tid & 63, wave = tid >> 6;
    const int g = lane >> 4, c = lane & 15;
    const int wm = (wave >> 1) * 64, wn = (wave & 1) * 64;

    f32x4 acc[4][4];
    #pragma unroll
    for (int i = 0; i < 4; ++i)
        #pragma unroll
        for (int j = 0; j < 4; ++j) acc[i][j] = f32x4{0.f,0.f,0.f,0.f};

    const int srow = (lane >> 3), scol = (lane & 7) * 8;   // within 8-row chunk
    for (int k0 = 0; k0 < K; k0 += 64) {
        #pragma unroll
        for (int i = 0; i < 4; ++i) {
            const int ch = wave * 4 + i;             // chunk 0..15 (8 rows each)
            const int r = ch * 8 + srow;
            gld16(&A[(size_t)(m0 + r) * K + k0 + scol], &As[ch * 512]);
            gld16(&W[(size_t)(n0 + r) * K + k0 + scol], &Bs[ch * 512]);
        }
        __syncthreads();
        #pragma unroll
        for (int kk = 0; kk < 64; kk += 32) {
            s16x8 af[4], bf_[4];
            #pragma unroll
            for (int mi = 0; mi < 4; ++mi)
                af[mi] = *(const s16x8*)&As[(wm + mi*16 + c) * 64 + kk + g * 8];
            #pragma unroll
            for (int ni = 0; ni < 4; ++ni)
                bf_[ni] = *(const s16x8*)&Bs[(wn + ni*16 + c) * 64 + kk + g * 8];
            #pragma unroll
            for (int mi = 0; mi < 4; ++mi)
                #pragma unroll
                for (int ni = 0; ni < 4; ++ni)
                    acc[mi][ni] = __builtin_amdgcn_mfma_f32_16x16x32_bf16(
                        af[mi], bf_[ni], acc[mi][ni], 0, 0, 0);
        }
        __syncthreads();
    }

    #pragma unroll
    for (int mi = 0; mi < 4; ++mi) {
        #pragma unroll
        for (int ni = 0; ni < 4; ++ni) {
            const int col = n0 + wn + ni*16 + c;
            #pragma unroll
            for (int j = 0; j < 4; ++j) {
                const int row = m0 + wm + mi*16 + g*4 + j;
                float v = acc[mi][ni][j];
                v += bias[col];
                if (EPI == 2) v = 0.5f * v * (1.f + erff(v * 0.70710678118654752f));
                if (EPI == 3) v += resid[(size_t)row * N + col];
                if (EPI == 7) {
                    if (col < 256) v *= 0.17677669529663687f;
                    if (col >= 512) {
                        const int bidx = row >> 14, y = (row >> 7) & 127, xx = row & 127;
                        const int wini = (bidx*16 + (y>>3))*16 + (xx>>3);
                        const int key  = ((y&7)<<3) | (xx&7);
                        vtbuf[((size_t)wini*256 + (col-512))*64 + key] = f2bf(v);
                        continue;
                    }
                }
                if (F32O) ((float*)outv)[(size_t)row * N + col] = v;
                else      ((u16*)outv)[(size_t)row * N + col]   = f2bf(v);
            }
        }
    }
}

// ---------------------------------------------------------------------------
// 64x64 GEMM (kept for M=1024 CA GEMMs). EPI: 1 bias, 4 bias+relu,
// 5 bias+clip32, 6 softmax-scale (no bias).
// ---------------------------------------------------------------------------
template<int EPI>
__launch_bounds__(256)
__global__ void gemm_bt(const u16* __restrict__ A, const u16* __restrict__ W,
                        const float* __restrict__ bias, u16* __restrict__ out,
                        int M, int N, int K) {
    __shared__ u16 As[64][72];
    __shared__ u16 Bs[64][72];
    const int m0 = blockIdx.y * 64;
    const int n0 = blockIdx.x * 64;
    const int tid = threadIdx.x;
    const int lane = tid & 63, wave = tid >> 6;
    const int wm = (wave >> 1) * 32, wn = (wave & 1) * 32;

    f32x4 acc[2][2];
    #pragma unroll
    for (int i = 0; i < 2; ++i)
        #pragma unroll
        for (int j = 0; j < 2; ++j) acc[i][j] = f32x4{0.f,0.f,0.f,0.f};

    for (int k0 = 0; k0 < K; k0 += 64) {
        #pragma unroll
        for (int rep = 0; rep < 2; ++rep) {
            int i = tid + rep * 256;
            int r = i >> 3, c = (i & 7) * 8;
            *(s16x8*)&As[r][c] = *(const s16x8*)&A[(size_t)(m0 + r) * K + k0 + c];
            *(s16x8*)&Bs[r][c] = *(const s16x8*)&W[(size_t)(n0 + r) * K + k0 + c];
        }
        __syncthreads();
        #pragma unroll
        for (int kk = 0; kk < 64; kk += 32) {
            s16x8 af[2], bfr[2];
            #pragma unroll
            for (int i = 0; i < 2; ++i) {
                af[i]  = *(const s16x8*)&As[wm + i*16 + (lane & 15)][kk + (lane >> 4) * 8];
                bfr[i] = *(const s16x8*)&Bs[wn + i*16 + (lane & 15)][kk + (lane >> 4) * 8];
            }
            #pragma unroll
            for (int mi = 0; mi < 2; ++mi)
                #pragma unroll
                for (int ni = 0; ni < 2; ++ni)
                    acc[mi][ni] = __builtin_amdgcn_mfma_f32_16x16x32_bf16(
                        af[mi], bfr[ni], acc[mi][ni], 0, 0, 0);
        }
        __syncthreads();
    }

    #pragma unroll
    for (int mi = 0; mi < 2; ++mi) {
        #pragma unroll
        for (int ni = 0; ni < 2; ++ni) {
            const int col = n0 + wn + ni*16 + (lane & 15);
            #pragma unroll
            for (int j = 0; j < 4; ++j) {
                const int row = m0 + wm + mi*16 + (lane >> 4)*4 + j;
                float v = acc[mi][ni][j];
                if (EPI >= 1 && EPI <= 5) v += bias[col];
                if (EPI == 4) v = fmaxf(v, 0.f);
                if (EPI == 5) v = fminf(fmaxf(v, -32.f), 32.f);
                if (EPI == 6) v *= 0.17677669529663687f;
                out[(size_t)row * N + col] = f2bf(v);
            }
        }
    }
}

// ---------------------------------------------------------------------------
// MFMA windowed self-attention. 1 wave per (window, head), no LDS.
// S^T tiles = mfma(K, Q, bias_frag); softmax per query col; P exchange ->
// A-frags; O = P·V with V^T fragments from vtbuf.
// ---------------------------------------------------------------------------
__launch_bounds__(256)
__global__ void win_attn(const u16* __restrict__ qkv, const u16* __restrict__ vtbuf,
                         const float* __restrict__ bfrag, u16* __restrict__ o,
                         int layer) {
    const int wid = blockIdx.x * 4 + (threadIdx.x >> 6);   // 0..4095
    const int lane = threadIdx.x & 63;
    const int h = wid & 7, win = wid >> 3;
    const int b = win >> 8, wy = (win >> 4) & 15, wx = win & 15;
    const int g = lane >> 4, c = lane & 15;
    const size_t rowbase = (size_t)b * 16384 + (size_t)wy * 8 * 128 + wx * 8;

    // fragments: Q (B-operand), K (A-operand) — 16B contiguous loads
    s16x8 qf[4], kf[4];
    #pragma unroll
    for (int qt = 0; qt < 4; ++qt) {
        const int t = qt * 16 + c;
        qf[qt] = *(const s16x8*)&qkv[(rowbase + (size_t)(t >> 3) * 128 + (t & 7)) * 768
                                     + h * 32 + g * 8];
    }
    #pragma unroll
    for (int kt = 0; kt < 4; ++kt) {
        const int t = kt * 16 + c;
        kf[kt] = *(const s16x8*)&qkv[(rowbase + (size_t)(t >> 3) * 128 + (t & 7)) * 768
                                     + 256 + h * 32 + g * 8];
    }

    // S^T = K·Q^T + bias (bias preloaded as C fragments)
    const float* bb = bfrag + (size_t)((layer * 8 + h) * 16) * 256;
    f32x4 st[4][4];
    #pragma unroll
    for (int kt = 0; kt < 4; ++kt)
        #pragma unroll
        for (int qt = 0; qt < 4; ++qt)
            st[kt][qt] = *(const f32x4*)&bb[(kt * 4 + qt) * 256 + lane * 4];
    #pragma unroll
    for (int kt = 0; kt < 4; ++kt)
        #pragma unroll
        for (int qt = 0; qt < 4; ++qt)
            st[kt][qt] = __builtin_amdgcn_mfma_f32_16x16x32_bf16(
                kf[kt], qf[qt], st[kt][qt], 0, 0, 0);

    // softmax per qt (this lane covers query qt*16 + c)
    float linv[4];
    #pragma unroll
    for (int qt = 0; qt < 4; ++qt) {
        float mx = -1e30f;
        #pragma unroll
        for (int kt = 0; kt < 4; ++kt)
            #pragma unroll
            for (int j = 0; j < 4; ++j) mx = fmaxf(mx, st[kt][qt][j]);
        mx = fmaxf(mx, __shfl_xor(mx, 16));
        mx = fmaxf(mx, __shfl_xor(mx, 32));
        float sum = 0.f;
        #pragma unroll
        for (int kt = 0; kt < 4; ++kt)
            #pragma unroll
            for (int j = 0; j < 4; ++j) {
                const float p = __expf(st[kt][qt][j] - mx);
                st[kt][qt][j] = p;
                sum += p;
            }
        sum += __shfl_xor(sum, 16);
        sum += __shfl_xor(sum, 32);
        linv[qt] = 1.f / sum;
    }

    // V^T B-fragments (16B contiguous from vtbuf)
    const u16* vb = vtbuf + ((size_t)win * 256 + h * 32) * 64;
    s16x8 vf[2][2];
    #pragma unroll
    for (int dt = 0; dt < 2; ++dt)
        #pragma unroll
        for (int ks = 0; ks < 2; ++ks)
            vf[dt][ks] = *(const s16x8*)&vb[(size_t)(dt * 16 + c) * 64 + ks * 32 + g * 8];

    // PV: exchange P^T -> P A-frags (ca_flash-validated pattern), 16 MFMAs
    f32x4 acc[4][2];
    #pragma unroll
    for (int i = 0; i < 4; ++i)
        #pragma unroll
        for (int j = 0; j < 2; ++j) acc[i][j] = f32x4{0.f,0.f,0.f,0.f};

    const int srcA = ((g & 1) * 2) * 16 + c, srcB = srcA + 16;
    const bool hi = (g >> 1) != 0;
    #pragma unroll
    for (int qt = 0; qt < 4; ++qt) {
        const float li = linv[qt];
        #pragma unroll
        for (int ks = 0; ks < 2; ++ks) {
            const unsigned int u00 = packbf(st[2*ks][qt][0]*li,   st[2*ks][qt][1]*li);
            const unsigned int u01 = packbf(st[2*ks][qt][2]*li,   st[2*ks][qt][3]*li);
            const unsigned int u10 = packbf(st[2*ks+1][qt][0]*li, st[2*ks+1][qt][1]*li);
            const unsigned int u11 = packbf(st[2*ks+1][qt][2]*li, st[2*ks+1][qt][3]*li);
            const unsigned int a0 = __shfl((int)u00, srcA), a1 = __shfl((int)u01, srcA);
            const unsigned int a2 = __shfl((int)u10, srcA), a3 = __shfl((int)u11, srcA);
            const unsigned int b0 = __shfl((int)u00, srcB), b1 = __shfl((int)u01, srcB);
            const unsigned int b2 = __shfl((int)u10, srcB), b3 = __shfl((int)u11, srcB);
            u32x4 w;
            w[0] = hi ? a2 : a0;  w[1] = hi ? a3 : a1;
            w[2] = hi ? b2 : b0;  w[3] = hi ? b3 : b1;
            const s16x8 pfrag = __builtin_bit_cast(s16x8, w);
            acc[qt][0] = __builtin_amdgcn_mfma_f32_16x16x32_bf16(pfrag, vf[0][ks], acc[qt][0], 0,0,0);
            acc[qt][1] = __builtin_amdgcn_mfma_f32_16x16x32_bf16(pfrag, vf[1][ks], acc[qt][1], 0,0,0);
        }
    }

    #pragma unroll
    for (int qt = 0; qt < 4; ++qt)
        #pragma unroll
        for (int dt = 0; dt < 2; ++dt)
            #pragma unroll
            for (int j = 0; j < 4; ++j) {
                const int t = qt * 16 + g * 4 + j;
                o[(rowbase + (size_t)(t >> 3) * 128 + (t & 7)) * 256
                  + h * 32 + dt * 16 + c] = f2bf(acc[qt][dt][j]);
            }
}

// ---------------------------------------------------------------------------
// Transpose: xbT[b][c][n] = xb[b][n][c].
// ---------------------------------------------------------------------------
__launch_bounds__(256)
__global__ void tr_kernel(const u16* __restrict__ src, u16* __restrict__ dst) {
    __shared__ u16 T[64][72];
    const int b = blockIdx.z;
    const int n0 = blockIdx.x * 64, c0 = blockIdx.y * 64;
    const int r = threadIdx.x >> 3, cc = (threadIdx.x & 7) * 8;
    const u16* S = src + (size_t)b * 16384 * 256;
    u16* D = dst + (size_t)b * 256 * 16384;
    #pragma unroll
    for (int rr = 0; rr < 64; rr += 32)
        *(u16x8*)&T[r + rr][cc] = *(const u16x8*)&S[(size_t)(n0 + r + rr) * 256 + c0 + cc];
    __syncthreads();
    #pragma unroll
    for (int rr = 0; rr < 64; rr += 32) {
        u16x8 v;
        #pragma unroll
        for (int k2 = 0; k2 < 8; ++k2) v[k2] = T[cc + k2][r + rr];
        *(u16x8*)&D[(size_t)(c0 + r + rr) * 16384 + n0 + cc] = v;
    }
}

// ---------------------------------------------------------------------------
// MFMA flash cross-attention (unchanged from round 3).
// ---------------------------------------------------------------------------
static __device__ __forceinline__ void ca_step(
    const f32x4& sA, const f32x4& sB, const s16x8& vf0, const s16x8& vf1,
    f32x4& acc0, f32x4& acc1, float& m, float& l, int g, int c)
{
    float smax = fmaxf(fmaxf(fmaxf(sA[0],sA[1]), fmaxf(sA[2],sA[3])),
                       fmaxf(fmaxf(sB[0],sB[1]), fmaxf(sB[2],sB[3])));
    smax = fmaxf(smax, __shfl_xor(smax, 16));
    smax = fmaxf(smax, __shfl_xor(smax, 32));
    const float mnew = fmaxf(m, smax);
    const float cc = __expf(m - mnew);
    float p[8];
    #pragma unroll
    for (int j = 0; j < 4; ++j) { p[j] = __expf(sA[j] - mnew); p[4+j] = __expf(sB[j] - mnew); }
    float ss = ((p[0]+p[1]) + (p[2]+p[3])) + ((p[4]+p[5]) + (p[6]+p[7]));
    ss += __shfl_xor(ss, 16);
    ss += __shfl_xor(ss, 32);
    l = l * cc + ss;
    #pragma unroll
    for (int j = 0; j < 4; ++j) { acc0[j] *= cc; acc1[j] *= cc; }
    m = mnew;
    const unsigned int u00 = packbf(p[0], p[1]);
    const unsigned int u01 = packbf(p[2], p[3]);
    const unsigned int u10 = packbf(p[4], p[5]);
    const unsigned int u11 = packbf(p[6], p[7]);
    const int srcA = ((g & 1) * 2) * 16 + c;
    const int srcB = srcA + 16;
    const unsigned int a0 = __shfl((int)u00, srcA), a1 = __shfl((int)u01, srcA);
    const unsigned int a2 = __shfl((int)u10, srcA), a3 = __shfl((int)u11, srcA);
    const unsigned int b0 = __shfl((int)u00, srcB), b1 = __shfl((int)u01, srcB);
    const unsigned int b2 = __shfl((int)u10, srcB), b3 = __shfl((int)u11, srcB);
    const bool hi = (g >> 1) != 0;
    u32x4 w;
    w[0] = hi ? a2 : a0;  w[1] = hi ? a3 : a1;
    w[2] = hi ? b2 : b0;  w[3] = hi ? b3 : b1;
    const s16x8 pf = __builtin_bit_cast(s16x8, w);
    acc0 = __builtin_amdgcn_mfma_f32_16x16x32_bf16(vf0, pf, acc0, 0, 0, 0);
    acc1 = __builtin_amdgcn_mfma_f32_16x16x32_bf16(vf1, pf, acc1, 0, 0, 0);
}

__launch_bounds__(256)
__global__ void ca_flash(const u16* __restrict__ qb, const u16* __restrict__ xb,
                         const u16* __restrict__ xbT, float* __restrict__ pbuf) {
    const int wid = blockIdx.x * 4 + (threadIdx.x >> 6);   // 0..2047
    const int lane = threadIdx.x & 63;
    const int ks = wid & 7, qt = (wid >> 3) & 15, h = (wid >> 7) & 7, b = wid >> 10;
    const int g = lane >> 4, c = lane & 15;

    s16x8 qf[2];
    #pragma unroll
    for (int nt = 0; nt < 2; ++nt) {
        const int q = qt * 32 + nt * 16 + c;
        qf[nt] = *(const s16x8*)&qb[((size_t)q * 2 + b) * 256 + h * 32 + g * 8];
    }
    const u16* Kb = xb  + (size_t)b * 16384 * 256 + h * 32;
    const u16* Vb = xbT + (size_t)b * 256 * 16384 + (size_t)(h * 32) * 16384;

    float m[2] = {-1e30f, -1e30f}, l[2] = {0.f, 0.f};
    f32x4 acc[2][2];
    #pragma unroll
    for (int i = 0; i < 2; ++i)
        #pragma unroll
        for (int j = 0; j < 2; ++j) acc[i][j] = f32x4{0.f,0.f,0.f,0.f};

    const int base = ks * 2048;
    const f32x4 zero = f32x4{0.f, 0.f, 0.f, 0.f};
    for (int step = 0; step < 64; ++step) {
        const int n0 = base + step * 32;
        const s16x8 kf0 = *(const s16x8*)&Kb[(size_t)(n0 + c) * 256 + g * 8];
        const s16x8 kf1 = *(const s16x8*)&Kb[(size_t)(n0 + 16 + c) * 256 + g * 8];
        const s16x8 vf0 = *(const s16x8*)&Vb[(size_t)c * 16384 + n0 + g * 8];
        const s16x8 vf1 = *(const s16x8*)&Vb[(size_t)(16 + c) * 16384 + n0 + g * 8];
        const f32x4 s00 = __builtin_amdgcn_mfma_f32_16x16x32_bf16(kf0, qf[0], zero, 0, 0, 0);
        const f32x4 s01 = __builtin_amdgcn_mfma_f32_16x16x32_bf16(kf1, qf[0], zero, 0, 0, 0);
        const f32x4 s10 = __builtin_amdgcn_mfma_f32_16x16x32_bf16(kf0, qf[1], zero, 0, 0, 0);
        const f32x4 s11 = __builtin_amdgcn_mfma_f32_16x16x32_bf16(kf1, qf[1], zero, 0, 0, 0);
        ca_step(s00, s01, vf0, vf1, acc[0][0], acc[1][0], m[0], l[0], g, c);
        ca_step(s10, s11, vf0, vf1, acc[0][1], acc[1][1], m[1], l[1], g, c);
    }

    float* P = pbuf + (size_t)wid * 1088;
    if (g == 0) {
        P[c]      = m[0];  P[16 + c] = m[1];
        P[32 + c] = l[0];  P[48 + c] = l[1];
    }
    #pragma unroll
    for (int mi = 0; mi < 2; ++mi)
        #pragma unroll
        for (int nt = 0; nt < 2; ++nt)
            *(f32x4*)&P[64 + (c + 16*nt) * 32 + 16*mi + g*4] = acc[mi][nt];
}

__launch_bounds__(256)
__global__ void ca_merge(const float* __restrict__ pbuf, u16* __restrict__ ctx) {
    const int wave = threadIdx.x >> 6, lane = threadIdx.x & 63;
    const int sub = lane >> 5, d = lane & 31;
    const int rowid = blockIdx.x * 8 + wave * 2 + sub;     // 0..8191
    const int q = rowid & 31, qt = (rowid >> 5) & 15, h = (rowid >> 9) & 7, b = rowid >> 12;
    const size_t w0 = (size_t)((b * 8 + h) * 16 + qt) * 8;
    float mv[8], lv[8];
    float M = -1e30f;
    #pragma unroll
    for (int i = 0; i < 8; ++i) {
        mv[i] = pbuf[(w0 + i) * 1088 + q];
        lv[i] = pbuf[(w0 + i) * 1088 + 32 + q];
        M = fmaxf(M, mv[i]);
    }
    float L = 0.f, o = 0.f;
    #pragma unroll
    for (int i = 0; i < 8; ++i) {
        const float e = __expf(mv[i] - M);
        L += lv[i] * e;
        o += e * pbuf[(w0 + i) * 1088 + 64 + q * 32 + d];
    }
    const int t = qt * 32 + q;
    ctx[((size_t)b * 512 + t) * 256 + h * 32 + d] = f2bf(o / L);
}

// ---------------------------------------------------------------------------
// Final: out = LN(query + ctx^T).
// ---------------------------------------------------------------------------
__launch_bounds__(256)
__global__ void final_ln(const float* __restrict__ query, const u16* __restrict__ ctx4,
                         const float* __restrict__ g, const float* __restrict__ b,
                         float* __restrict__ out) {
    const int wave = threadIdx.x >> 6, lane = threadIdx.x & 63;
    const int row = blockIdx.x * 4 + wave;        // 0..1023 = t*2+bb
    const int t = row >> 1, bb = row & 1;
    const int c = lane * 4;
    float4 rq = *(const float4*)(query + (size_t)row * 256 + c);
    u16x4 rc = *(const u16x4*)(ctx4 + ((size_t)bb * 512 + t) * 256 + c);
    float x0 = rq.x + bf2f(rc[0]);
    float x1 = rq.y + bf2f(rc[1]);
    float x2 = rq.z + bf2f(rc[2]);
    float x3 = rq.w + bf2f(rc[3]);
    float s1 = x0 + x1 + x2 + x3;
    float s2 = x0*x0 + x1*x1 + x2*x2 + x3*x3;
    #pragma unroll
    for (int off = 32; off; off >>= 1) {
        s1 += __shfl_xor(s1, off);
        s2 += __shfl_xor(s2, off);
    }
    const float mean = s1 * (1.f/256.f);
    const float var  = s2 * (1.f/256.f) - mean*mean;
    const float rstd = rsqrtf(var + 1e-5f);
    float4 gg = *(const float4*)(g + c);
    float4 bv = *(const float4*)(b + c);
    float4 og;
    og.x = (x0-mean)*rstd*gg.x + bv.x;
    og.y = (x1-mean)*rstd*gg.y + bv.y;
    og.z = (x2-mean)*rstd*gg.z + bv.z;
    og.w = (x3-mean)*rstd*gg.w + bv.w;
    *(float4*)(out + (size_t)row * 256 + c) = og;
}

// ---------------------------------------------------------------------------

extern "C" void kernel_launch(void* const* d_in, const int* in_sizes, int n_in,
                              void* d_out, int out_size, void* d_ws, size_t ws_size,
                              hipStream_t stream) {
    const float* x_in  = (const float*)d_in[0];
    const float* query = (const float*)d_in[1];
    const float* n1_g  = (const float*)d_in[2];
    const float* n1_b  = (const float*)d_in[3];
    const float* qkv_w = (const float*)d_in[4];
    const float* qkv_b = (const float*)d_in[5];
    const float* out_w = (const float*)d_in[6];
    const float* out_b = (const float*)d_in[7];
    const float* rel   = (const float*)d_in[8];
    const float* n2_g  = (const float*)d_in[9];
    const float* n2_b  = (const float*)d_in[10];
    const float* fc1_w = (const float*)d_in[11];
    const float* fc1_b = (const float*)d_in[12];
    const float* fc2_w = (const float*)d_in[13];
    const float* fc2_b = (const float*)d_in[14];
    const float* can_g = (const float*)d_in[15];
    const float* can_b = (const float*)d_in[16];
    const float* cpq_w = (const float*)d_in[17];
    const float* cfc_w = (const float*)d_in[18];
    const float* cfc_b = (const float*)d_in[19];
    const float* cf1_w = (const float*)d_in[20];
    const float* cf1_b = (const float*)d_in[21];
    const float* cf2_w = (const float*)d_in[22];
    const float* cf2_b = (const float*)d_in[23];

    const int M = 32768;   // 2 * 128 * 128 tokens

    char* w = (char*)d_ws;
    float* xs  = (float*)w;  w += (size_t)M * 256 * 4;        // fp32 residual stream
    u16* hbuf  = (u16*)w;    w += (size_t)M * 256 * 2;        // bf16 LN/attn out
    u16* big   = (u16*)w;    w += (size_t)M * 1024 * 2;       // bf16 qkv / mlp hidden
    u16* arena = (u16*)w;    w += (size_t)2228224 * 2;        // bf16 weights + query
    u16* qbuf  = (u16*)w;    w += 524288;
    u16* ctx1  = (u16*)w;    w += 524288;
    u16* ctx2  = (u16*)w;    w += 524288;
    u16* ctx3  = (u16*)w;    w += 1048576;
    u16* ctx4  = (u16*)w;    w += 524288;
    u16* xb    = (u16*)w;    w += (size_t)M * 256 * 2;        // bf16 copy of final xs
    float* bfragb = (float*)w; w += 65536 * 4;                // bias C-fragments

    // vtbuf aliases the tail of `big` (qkv uses only M*768 of it; dead by fc1)
    u16* vtbuf = big + (size_t)M * 768;                       // 16 MB
    // CA-phase scratch aliases into `big` (free after the block loop):
    u16*   xbT  = big;                                        // (2,256,16384)
    float* pbuf = (float*)(big + 8388608);                    // 2048 * 1088 f32

    u16* wq   = arena;
    u16* wo   = arena + 393216;
    u16* wf1  = arena + 524288;
    u16* wf2  = arena + 1048576;
    u16* wcpq = arena + 1572864;
    u16* wcfc = arena + 1638400;
    u16* wcf1 = arena + 1703936;
    u16* wcf2 = arena + 1835008;
    u16* qcvt = arena + 1966080;

    cvt_weights<<<2176, 256, 0, stream>>>(qkv_w, out_w, fc1_w, fc2_w, cpq_w,
                                          cfc_w, cf1_w, cf2_w, query, arena);
    bias_frag_kernel<<<64, 256, 0, stream>>>(rel, bfragb);
    hipMemcpyAsync(xs, x_in, (size_t)M * 256 * 4, hipMemcpyDeviceToDevice, stream);

    for (int i = 0; i < 2; ++i) {
        ln_kernel<<<M/4, 256, 0, stream>>>(xs, hbuf, n1_g + i*256, n1_b + i*256, M);
        gemm128<7,false><<<dim3(6,256), 256, 0, stream>>>(
            hbuf, wq + (size_t)i*768*256, qkv_b + i*768, nullptr, big, vtbuf, M, 768, 256);
        win_attn<<<1024, 256, 0, stream>>>(big, vtbuf, bfragb, hbuf, i);
        gemm128<3,true><<<dim3(2,256), 256, 0, stream>>>(
            hbuf, wo + (size_t)i*65536, out_b + i*256, xs, xs, nullptr, M, 256, 256);
        ln_kernel<<<M/4, 256, 0, stream>>>(xs, hbuf, n2_g + i*256, n2_b + i*256, M);
        gemm128<2,false><<<dim3(8,256), 256, 0, stream>>>(
            hbuf, wf1 + (size_t)i*262144, fc1_b + i*1024, nullptr, big, nullptr, M, 1024, 256);
        gemm128<3,true><<<dim3(2,256), 256, 0, stream>>>(
            big, wf2 + (size_t)i*262144, fc2_b + i*256, xs, xs, nullptr, M, 256, 1024);
    }

    // ---- cross-attention ----
    cvt_f2b<<<(M*256)/1024, 256, 0, stream>>>(xs, xb, M * 256);
    tr_kernel<<<dim3(256, 4, 2), 256, 0, stream>>>(xb, xbT);
    gemm_bt<6><<<dim3(4, 16), 256, 0, stream>>>(qcvt, wcpq, nullptr, qbuf, 1024, 256, 256);
    ca_flash<<<512, 256, 0, stream>>>(qbuf, xb, xbT, pbuf);
    ca_merge<<<1024, 256, 0, stream>>>(pbuf, ctx1);
    gemm_bt<5><<<dim3(4, 16), 256, 0, stream>>>(ctx1, wcfc, cfc_b, ctx2, 1024, 256, 256);
    gemm_bt<4><<<dim3(8, 16), 256, 0, stream>>>(ctx2, wcf1, cf1_b, ctx3, 1024, 512, 256);
    gemm_bt<1><<<dim3(4, 16), 256, 0, stream>>>(ctx3, wcf2, cf2_b, ctx4, 1024, 256, 512);
    final_ln<<<256, 256, 0, stream>>>(query, ctx4, can_g, can_b, (float*)d_out);

    (void)in_sizes; (void)n_in; (void)out_size; (void)ws_size;
}

// Round 5
// 527.925 us; speedup vs baseline: 3.2608x; 1.0226x over previous
//
#include <hip/hip_runtime.h>
#include <hip/hip_bf16.h>

// ---------------------------------------------------------------------------
// Swin block ×2 + CrossAttnFFN. FP32 in/out, bf16 MFMA everywhere, fp32 accum.
// Round 5: ca_flash v2 — defer-max (T13), lane-local denom, v_cvt_pk_bf16_f32
//          packing (T12), KSPLIT=16 (occupancy 2->4 waves/SIMD);
//          fc2 dual-write epilogue kills the cvt_f2b pass.
// ---------------------------------------------------------------------------

typedef unsigned short u16;
typedef u16  u16x4 __attribute__((ext_vector_type(4)));
typedef u16  u16x8 __attribute__((ext_vector_type(8)));
typedef short s16x8 __attribute__((ext_vector_type(8)));
typedef float f32x4 __attribute__((ext_vector_type(4)));
typedef unsigned int u32x4 __attribute__((ext_vector_type(4)));

static __device__ __forceinline__ float bf2f(u16 u) {
    union { unsigned int i; float f; } v; v.i = ((unsigned int)u) << 16; return v.f;
}
static __device__ __forceinline__ u16 f2bf(float f) {
    unsigned int x = __float_as_uint(f);
    unsigned int r = x + 0x7fffu + ((x >> 16) & 1u);   // RNE
    return (u16)(r >> 16);
}
static __device__ __forceinline__ unsigned int packbf(float a, float b) {
    return (unsigned int)f2bf(a) | ((unsigned int)f2bf(b) << 16);
}
static __device__ __forceinline__ void gld16(const u16* g, u16* l) {
    __builtin_amdgcn_global_load_lds(
        (const __attribute__((address_space(1))) unsigned int*)g,
        (__attribute__((address_space(3))) unsigned int*)l, 16, 0, 0);
}

// ---------------------------------------------------------------------------
// fp32 -> bf16 weight/query conversion (one fused kernel).
// ---------------------------------------------------------------------------
__launch_bounds__(256)
__global__ void cvt_weights(const float* __restrict__ qkvw, const float* __restrict__ outw,
                            const float* __restrict__ f1w,  const float* __restrict__ f2w,
                            const float* __restrict__ cpq,  const float* __restrict__ cfc,
                            const float* __restrict__ cf1,  const float* __restrict__ cf2,
                            const float* __restrict__ qry,  u16* __restrict__ dst) {
    const int q = blockIdx.x * 256 + threadIdx.x;
    const int gid = q * 4;
    const float* s; int off;
    if      (gid <  393216) { s = qkvw; off = 0;       }
    else if (gid <  524288) { s = outw; off = 393216;  }
    else if (gid < 1048576) { s = f1w;  off = 524288;  }
    else if (gid < 1572864) { s = f2w;  off = 1048576; }
    else if (gid < 1638400) { s = cpq;  off = 1572864; }
    else if (gid < 1703936) { s = cfc;  off = 1638400; }
    else if (gid < 1835008) { s = cf1;  off = 1703936; }
    else if (gid < 1966080) { s = cf2;  off = 1835008; }
    else                    { s = qry;  off = 1966080; }
    float4 v = *(const float4*)(s + (gid - off));
    u16x4 o; o[0] = f2bf(v.x); o[1] = f2bf(v.y); o[2] = f2bf(v.z); o[3] = f2bf(v.w);
    *(u16x4*)(dst + gid) = o;
}

// ---------------------------------------------------------------------------
// Relative-position bias in MFMA C-fragment layout.
// ---------------------------------------------------------------------------
__launch_bounds__(256)
__global__ void bias_frag_kernel(const float* __restrict__ rel, float* __restrict__ bfrag) {
    const int idx = blockIdx.x * 256 + threadIdx.x;      // 0..16383
    #pragma unroll
    for (int j = 0; j < 4; ++j) {
        const int i = idx * 4 + j;
        const int layer = i >> 15, h = (i >> 12) & 7, kt = (i >> 10) & 3,
                  qt = (i >> 8) & 3, lane = (i >> 2) & 63, jj = i & 3;
        const int key   = kt * 16 + (lane >> 4) * 4 + jj;
        const int query = qt * 16 + (lane & 15);
        const int dy = (query >> 3) - (key >> 3) + 7;
        const int dx = (query & 7)  - (key & 7)  + 7;
        bfrag[i] = rel[layer * 1800 + (dy * 15 + dx) * 8 + h];
    }
}

// ---------------------------------------------------------------------------
// LayerNorm: one wave per row, C=256. fp32 in -> bf16 out.
// ---------------------------------------------------------------------------
__launch_bounds__(256)
__global__ void ln_kernel(const float* __restrict__ in, u16* __restrict__ out,
                          const float* __restrict__ g, const float* __restrict__ b,
                          int rows) {
    const int wave = threadIdx.x >> 6, lane = threadIdx.x & 63;
    const int row = blockIdx.x * 4 + wave;
    if (row >= rows) return;
    const int c = lane * 4;
    float4 v = *(const float4*)(in + (size_t)row * 256 + c);
    float s1 = v.x + v.y + v.z + v.w;
    float s2 = v.x*v.x + v.y*v.y + v.z*v.z + v.w*v.w;
    #pragma unroll
    for (int off = 32; off; off >>= 1) {
        s1 += __shfl_xor(s1, off);
        s2 += __shfl_xor(s2, off);
    }
    const float mean = s1 * (1.f/256.f);
    const float var  = s2 * (1.f/256.f) - mean*mean;
    const float rstd = rsqrtf(var + 1e-5f);
    float4 gg = *(const float4*)(g + c);
    float4 bb = *(const float4*)(b + c);
    u16x4 og;
    og[0] = f2bf((v.x-mean)*rstd*gg.x + bb.x);
    og[1] = f2bf((v.y-mean)*rstd*gg.y + bb.y);
    og[2] = f2bf((v.z-mean)*rstd*gg.z + bb.z);
    og[3] = f2bf((v.w-mean)*rstd*gg.w + bb.w);
    *(u16x4*)(out + (size_t)row * 256 + c) = og;
}

// ---------------------------------------------------------------------------
// 128x128 GEMM (m97 structure): linear LDS + global_load_lds(16B), BK=64.
// EPI: 2 +bias+gelu, 3 +bias+resid(f32), 7 qkv (+bias, scale q, v->vtbuf),
//      8 +bias+resid dual-write (f32 out + bf16 aux)
// ---------------------------------------------------------------------------
template<int EPI, bool F32O>
__launch_bounds__(256)
__global__ void gemm128(const u16* __restrict__ A, const u16* __restrict__ W,
                        const float* __restrict__ bias, const float* __restrict__ resid,
                        void* __restrict__ outv, u16* __restrict__ aux,
                        int M, int N, int K) {
    __shared__ u16 As[128 * 64];
    __shared__ u16 Bs[128 * 64];
    const int m0 = blockIdx.y * 128, n0 = blockIdx.x * 128;
    const int tid = threadIdx.x, lane = tid & 63, wave = tid >> 6;
    const int g = lane >> 4, c = lane & 15;
    const int wm = (wave >> 1) * 64, wn = (wave & 1) * 64;

    f32x4 acc[4][4];
    #pragma unroll
    for (int i = 0; i < 4; ++i)
        #pragma unroll
        for (int j = 0; j < 4; ++j) acc[i][j] = f32x4{0.f,0.f,0.f,0.f};

    const int srow = (lane >> 3), scol = (lane & 7) * 8;   // within 8-row chunk
    for (int k0 = 0; k0 < K; k0 += 64) {
        #pragma unroll
        for (int i = 0; i < 4; ++i) {
            const int ch = wave * 4 + i;             // chunk 0..15 (8 rows each)
            const int r = ch * 8 + srow;
            gld16(&A[(size_t)(m0 + r) * K + k0 + scol], &As[ch * 512]);
            gld16(&W[(size_t)(n0 + r) * K + k0 + scol], &Bs[ch * 512]);
        }
        __syncthreads();
        #pragma unroll
        for (int kk = 0; kk < 64; kk += 32) {
            s16x8 af[4], bf_[4];
            #pragma unroll
            for (int mi = 0; mi < 4; ++mi)
                af[mi] = *(const s16x8*)&As[(wm + mi*16 + c) * 64 + kk + g * 8];
            #pragma unroll
            for (int ni = 0; ni < 4; ++ni)
                bf_[ni] = *(const s16x8*)&Bs[(wn + ni*16 + c) * 64 + kk + g * 8];
            #pragma unroll
            for (int mi = 0; mi < 4; ++mi)
                #pragma unroll
                for (int ni = 0; ni < 4; ++ni)
                    acc[mi][ni] = __builtin_amdgcn_mfma_f32_16x16x32_bf16(
                        af[mi], bf_[ni], acc[mi][ni], 0, 0, 0);
        }
        __syncthreads();
    }

    #pragma unroll
    for (int mi = 0; mi < 4; ++mi) {
        #pragma unroll
        for (int ni = 0; ni < 4; ++ni) {
            const int col = n0 + wn + ni*16 + c;
            #pragma unroll
            for (int j = 0; j < 4; ++j) {
                const int row = m0 + wm + mi*16 + g*4 + j;
                float v = acc[mi][ni][j];
                v += bias[col];
                if (EPI == 2) v = 0.5f * v * (1.f + erff(v * 0.70710678118654752f));
                if (EPI == 3 || EPI == 8) v += resid[(size_t)row * N + col];
                if (EPI == 8) {
                    ((float*)outv)[(size_t)row * N + col] = v;
                    aux[(size_t)row * N + col] = f2bf(v);
                    continue;
                }
                if (EPI == 7) {
                    if (col < 256) v *= 0.17677669529663687f;
                    if (col >= 512) {
                        const int bidx = row >> 14, y = (row >> 7) & 127, xx = row & 127;
                        const int wini = (bidx*16 + (y>>3))*16 + (xx>>3);
                        const int key  = ((y&7)<<3) | (xx&7);
                        aux[((size_t)wini*256 + (col-512))*64 + key] = f2bf(v);
                        continue;
                    }
                }
                if (F32O) ((float*)outv)[(size_t)row * N + col] = v;
                else      ((u16*)outv)[(size_t)row * N + col]   = f2bf(v);
            }
        }
    }
}

// ---------------------------------------------------------------------------
// 64x64 GEMM (M=1024 CA GEMMs). EPI: 1 bias, 4 bias+relu, 5 bias+clip32,
// 6 softmax-scale (no bias).
// ---------------------------------------------------------------------------
template<int EPI>
__launch_bounds__(256)
__global__ void gemm_bt(const u16* __restrict__ A, const u16* __restrict__ W,
                        const float* __restrict__ bias, u16* __restrict__ out,
                        int M, int N, int K) {
    __shared__ u16 As[64][72];
    __shared__ u16 Bs[64][72];
    const int m0 = blockIdx.y * 64;
    const int n0 = blockIdx.x * 64;
    const int tid = threadIdx.x;
    const int lane = tid & 63, wave = tid >> 6;
    const int wm = (wave >> 1) * 32, wn = (wave & 1) * 32;

    f32x4 acc[2][2];
    #pragma unroll
    for (int i = 0; i < 2; ++i)
        #pragma unroll
        for (int j = 0; j < 2; ++j) acc[i][j] = f32x4{0.f,0.f,0.f,0.f};

    for (int k0 = 0; k0 < K; k0 += 64) {
        #pragma unroll
        for (int rep = 0; rep < 2; ++rep) {
            int i = tid + rep * 256;
            int r = i >> 3, c = (i & 7) * 8;
            *(s16x8*)&As[r][c] = *(const s16x8*)&A[(size_t)(m0 + r) * K + k0 + c];
            *(s16x8*)&Bs[r][c] = *(const s16x8*)&W[(size_t)(n0 + r) * K + k0 + c];
        }
        __syncthreads();
        #pragma unroll
        for (int kk = 0; kk < 64; kk += 32) {
            s16x8 af[2], bfr[2];
            #pragma unroll
            for (int i = 0; i < 2; ++i) {
                af[i]  = *(const s16x8*)&As[wm + i*16 + (lane & 15)][kk + (lane >> 4) * 8];
                bfr[i] = *(const s16x8*)&Bs[wn + i*16 + (lane & 15)][kk + (lane >> 4) * 8];
            }
            #pragma unroll
            for (int mi = 0; mi < 2; ++mi)
                #pragma unroll
                for (int ni = 0; ni < 2; ++ni)
                    acc[mi][ni] = __builtin_amdgcn_mfma_f32_16x16x32_bf16(
                        af[mi], bfr[ni], acc[mi][ni], 0, 0, 0);
        }
        __syncthreads();
    }

    #pragma unroll
    for (int mi = 0; mi < 2; ++mi) {
        #pragma unroll
        for (int ni = 0; ni < 2; ++ni) {
            const int col = n0 + wn + ni*16 + (lane & 15);
            #pragma unroll
            for (int j = 0; j < 4; ++j) {
                const int row = m0 + wm + mi*16 + (lane >> 4)*4 + j;
                float v = acc[mi][ni][j];
                if (EPI >= 1 && EPI <= 5) v += bias[col];
                if (EPI == 4) v = fmaxf(v, 0.f);
                if (EPI == 5) v = fminf(fmaxf(v, -32.f), 32.f);
                if (EPI == 6) v *= 0.17677669529663687f;
                out[(size_t)row * N + col] = f2bf(v);
            }
        }
    }
}

// ---------------------------------------------------------------------------
// MFMA windowed self-attention. 1 wave per (window, head), no LDS.
// ---------------------------------------------------------------------------
__launch_bounds__(256)
__global__ void win_attn(const u16* __restrict__ qkv, const u16* __restrict__ vtbuf,
                         const float* __restrict__ bfrag, u16* __restrict__ o,
                         int layer) {
    const int wid = blockIdx.x * 4 + (threadIdx.x >> 6);   // 0..4095
    const int lane = threadIdx.x & 63;
    const int h = wid & 7, win = wid >> 3;
    const int b = win >> 8, wy = (win >> 4) & 15, wx = win & 15;
    const int g = lane >> 4, c = lane & 15;
    const size_t rowbase = (size_t)b * 16384 + (size_t)wy * 8 * 128 + wx * 8;

    s16x8 qf[4], kf[4];
    #pragma unroll
    for (int qt = 0; qt < 4; ++qt) {
        const int t = qt * 16 + c;
        qf[qt] = *(const s16x8*)&qkv[(rowbase + (size_t)(t >> 3) * 128 + (t & 7)) * 768
                                     + h * 32 + g * 8];
    }
    #pragma unroll
    for (int kt = 0; kt < 4; ++kt) {
        const int t = kt * 16 + c;
        kf[kt] = *(const s16x8*)&qkv[(rowbase + (size_t)(t >> 3) * 128 + (t & 7)) * 768
                                     + 256 + h * 32 + g * 8];
    }

    const float* bb = bfrag + (size_t)((layer * 8 + h) * 16) * 256;
    f32x4 st[4][4];
    #pragma unroll
    for (int kt = 0; kt < 4; ++kt)
        #pragma unroll
        for (int qt = 0; qt < 4; ++qt)
            st[kt][qt] = *(const f32x4*)&bb[(kt * 4 + qt) * 256 + lane * 4];
    #pragma unroll
    for (int kt = 0; kt < 4; ++kt)
        #pragma unroll
        for (int qt = 0; qt < 4; ++qt)
            st[kt][qt] = __builtin_amdgcn_mfma_f32_16x16x32_bf16(
                kf[kt], qf[qt], st[kt][qt], 0, 0, 0);

    float linv[4];
    #pragma unroll
    for (int qt = 0; qt < 4; ++qt) {
        float mx = -1e30f;
        #pragma unroll
        for (int kt = 0; kt < 4; ++kt)
            #pragma unroll
            for (int j = 0; j < 4; ++j) mx = fmaxf(mx, st[kt][qt][j]);
        mx = fmaxf(mx, __shfl_xor(mx, 16));
        mx = fmaxf(mx, __shfl_xor(mx, 32));
        float sum = 0.f;
        #pragma unroll
        for (int kt = 0; kt < 4; ++kt)
            #pragma unroll
            for (int j = 0; j < 4; ++j) {
                const float p = __expf(st[kt][qt][j] - mx);
                st[kt][qt][j] = p;
                sum += p;
            }
        sum += __shfl_xor(sum, 16);
        sum += __shfl_xor(sum, 32);
        linv[qt] = 1.f / sum;
    }

    const u16* vb = vtbuf + ((size_t)win * 256 + h * 32) * 64;
    s16x8 vf[2][2];
    #pragma unroll
    for (int dt = 0; dt < 2; ++dt)
        #pragma unroll
        for (int ks = 0; ks < 2; ++ks)
            vf[dt][ks] = *(const s16x8*)&vb[(size_t)(dt * 16 + c) * 64 + ks * 32 + g * 8];

    f32x4 acc[4][2];
    #pragma unroll
    for (int i = 0; i < 4; ++i)
        #pragma unroll
        for (int j = 0; j < 2; ++j) acc[i][j] = f32x4{0.f,0.f,0.f,0.f};

    const int srcA = ((g & 1) * 2) * 16 + c, srcB = srcA + 16;
    const bool hi = (g >> 1) != 0;
    #pragma unroll
    for (int qt = 0; qt < 4; ++qt) {
        const float li = linv[qt];
        #pragma unroll
        for (int ks = 0; ks < 2; ++ks) {
            const unsigned int u00 = packbf(st[2*ks][qt][0]*li,   st[2*ks][qt][1]*li);
            const unsigned int u01 = packbf(st[2*ks][qt][2]*li,   st[2*ks][qt][3]*li);
            const unsigned int u10 = packbf(st[2*ks+1][qt][0]*li, st[2*ks+1][qt][1]*li);
            const unsigned int u11 = packbf(st[2*ks+1][qt][2]*li, st[2*ks+1][qt][3]*li);
            const unsigned int a0 = __shfl((int)u00, srcA), a1 = __shfl((int)u01, srcA);
            const unsigned int a2 = __shfl((int)u10, srcA), a3 = __shfl((int)u11, srcA);
            const unsigned int b0 = __shfl((int)u00, srcB), b1 = __shfl((int)u01, srcB);
            const unsigned int b2 = __shfl((int)u10, srcB), b3 = __shfl((int)u11, srcB);
            u32x4 w;
            w[0] = hi ? a2 : a0;  w[1] = hi ? a3 : a1;
            w[2] = hi ? b2 : b0;  w[3] = hi ? b3 : b1;
            const s16x8 pfrag = __builtin_bit_cast(s16x8, w);
            acc[qt][0] = __builtin_amdgcn_mfma_f32_16x16x32_bf16(pfrag, vf[0][ks], acc[qt][0], 0,0,0);
            acc[qt][1] = __builtin_amdgcn_mfma_f32_16x16x32_bf16(pfrag, vf[1][ks], acc[qt][1], 0,0,0);
        }
    }

    #pragma unroll
    for (int qt = 0; qt < 4; ++qt)
        #pragma unroll
        for (int dt = 0; dt < 2; ++dt)
            #pragma unroll
            for (int j = 0; j < 4; ++j) {
                const int t = qt * 16 + g * 4 + j;
                o[(rowbase + (size_t)(t >> 3) * 128 + (t & 7)) * 256
                  + h * 32 + dt * 16 + c] = f2bf(acc[qt][dt][j]);
            }
}

// ---------------------------------------------------------------------------
// Transpose: xbT[b][c][n] = xb[b][n][c].
// ---------------------------------------------------------------------------
__launch_bounds__(256)
__global__ void tr_kernel(const u16* __restrict__ src, u16* __restrict__ dst) {
    __shared__ u16 T[64][72];
    const int b = blockIdx.z;
    const int n0 = blockIdx.x * 64, c0 = blockIdx.y * 64;
    const int r = threadIdx.x >> 3, cc = (threadIdx.x & 7) * 8;
    const u16* S = src + (size_t)b * 16384 * 256;
    u16* D = dst + (size_t)b * 256 * 16384;
    #pragma unroll
    for (int rr = 0; rr < 64; rr += 32)
        *(u16x8*)&T[r + rr][cc] = *(const u16x8*)&S[(size_t)(n0 + r + rr) * 256 + c0 + cc];
    __syncthreads();
    #pragma unroll
    for (int rr = 0; rr < 64; rr += 32) {
        u16x8 v;
        #pragma unroll
        for (int k2 = 0; k2 < 8; ++k2) v[k2] = T[cc + k2][r + rr];
        *(u16x8*)&D[(size_t)(c0 + r + rr) * 16384 + n0 + cc] = v;
    }
}

// ---------------------------------------------------------------------------
// MFMA flash cross-attention v2: defer-max, lane-local denom, cvt_pk packing.
// Wave = (b, h, qtile of 32 queries, ks of 16 key-splits): 1024 keys/wave.
// ---------------------------------------------------------------------------
static __device__ __forceinline__ void ca_step(
    const f32x4& sA, const f32x4& sB, const s16x8& vf0, const s16x8& vf1,
    f32x4& acc0, f32x4& acc1, float& m, float& llane,
    int srcA, int srcB, bool hi)
{
    float smax = fmaxf(fmaxf(fmaxf(sA[0],sA[1]), fmaxf(sA[2],sA[3])),
                       fmaxf(fmaxf(sB[0],sB[1]), fmaxf(sB[2],sB[3])));
    if (!__all(smax <= m + 8.f)) {
        smax = fmaxf(smax, __shfl_xor(smax, 16));
        smax = fmaxf(smax, __shfl_xor(smax, 32));
        const float mnew = fmaxf(m, smax);
        const float cc = __expf(m - mnew);
        #pragma unroll
        for (int j = 0; j < 4; ++j) { acc0[j] *= cc; acc1[j] *= cc; }
        llane *= cc;
        m = mnew;
    }
    float p[8];
    #pragma unroll
    for (int j = 0; j < 4; ++j) { p[j] = __expf(sA[j] - m); p[4+j] = __expf(sB[j] - m); }
    llane += ((p[0]+p[1]) + (p[2]+p[3])) + ((p[4]+p[5]) + (p[6]+p[7]));
    unsigned int u00, u01, u10, u11;
    asm("v_cvt_pk_bf16_f32 %0, %1, %2" : "=v"(u00) : "v"(p[0]), "v"(p[1]));
    asm("v_cvt_pk_bf16_f32 %0, %1, %2" : "=v"(u01) : "v"(p[2]), "v"(p[3]));
    asm("v_cvt_pk_bf16_f32 %0, %1, %2" : "=v"(u10) : "v"(p[4]), "v"(p[5]));
    asm("v_cvt_pk_bf16_f32 %0, %1, %2" : "=v"(u11) : "v"(p[6]), "v"(p[7]));
    const unsigned int a0 = __shfl((int)u00, srcA), a1 = __shfl((int)u01, srcA);
    const unsigned int a2 = __shfl((int)u10, srcA), a3 = __shfl((int)u11, srcA);
    const unsigned int b0 = __shfl((int)u00, srcB), b1 = __shfl((int)u01, srcB);
    const unsigned int b2 = __shfl((int)u10, srcB), b3 = __shfl((int)u11, srcB);
    u32x4 w;
    w[0] = hi ? a2 : a0;  w[1] = hi ? a3 : a1;
    w[2] = hi ? b2 : b0;  w[3] = hi ? b3 : b1;
    const s16x8 pf = __builtin_bit_cast(s16x8, w);
    acc0 = __builtin_amdgcn_mfma_f32_16x16x32_bf16(vf0, pf, acc0, 0, 0, 0);
    acc1 = __builtin_amdgcn_mfma_f32_16x16x32_bf16(vf1, pf, acc1, 0, 0, 0);
}

__launch_bounds__(256)
__global__ void ca_flash(const u16* __restrict__ qb, const u16* __restrict__ xb,
                         const u16* __restrict__ xbT, float* __restrict__ pbuf) {
    const int wid = blockIdx.x * 4 + (threadIdx.x >> 6);   // 0..4095
    const int lane = threadIdx.x & 63;
    const int ks = wid & 15, qt = (wid >> 4) & 15, h = (wid >> 8) & 7, b = wid >> 11;
    const int g = lane >> 4, c = lane & 15;
    const int srcA = ((g & 1) * 2) * 16 + c, srcB = srcA + 16;
    const bool hi = (g >> 1) != 0;

    s16x8 qf[2];
    #pragma unroll
    for (int nt = 0; nt < 2; ++nt) {
        const int q = qt * 32 + nt * 16 + c;
        qf[nt] = *(const s16x8*)&qb[((size_t)q * 2 + b) * 256 + h * 32 + g * 8];
    }
    const u16* Kb = xb  + (size_t)b * 16384 * 256 + h * 32;
    const u16* Vb = xbT + (size_t)b * 256 * 16384 + (size_t)(h * 32) * 16384;

    float m[2] = {-1e30f, -1e30f}, llane[2] = {0.f, 0.f};
    f32x4 acc[2][2];   // [d-tile][q-tile]
    #pragma unroll
    for (int i = 0; i < 2; ++i)
        #pragma unroll
        for (int j = 0; j < 2; ++j) acc[i][j] = f32x4{0.f,0.f,0.f,0.f};

    const int base = ks * 1024;
    const f32x4 zero = f32x4{0.f, 0.f, 0.f, 0.f};
    for (int step = 0; step < 32; ++step) {
        const int n0 = base + step * 32;
        const s16x8 kf0 = *(const s16x8*)&Kb[(size_t)(n0 + c) * 256 + g * 8];
        const s16x8 kf1 = *(const s16x8*)&Kb[(size_t)(n0 + 16 + c) * 256 + g * 8];
        const s16x8 vf0 = *(const s16x8*)&Vb[(size_t)c * 16384 + n0 + g * 8];
        const s16x8 vf1 = *(const s16x8*)&Vb[(size_t)(16 + c) * 16384 + n0 + g * 8];
        const f32x4 s00 = __builtin_amdgcn_mfma_f32_16x16x32_bf16(kf0, qf[0], zero, 0, 0, 0);
        const f32x4 s01 = __builtin_amdgcn_mfma_f32_16x16x32_bf16(kf1, qf[0], zero, 0, 0, 0);
        const f32x4 s10 = __builtin_amdgcn_mfma_f32_16x16x32_bf16(kf0, qf[1], zero, 0, 0, 0);
        const f32x4 s11 = __builtin_amdgcn_mfma_f32_16x16x32_bf16(kf1, qf[1], zero, 0, 0, 0);
        ca_step(s00, s01, vf0, vf1, acc[0][0], acc[1][0], m[0], llane[0], srcA, srcB, hi);
        ca_step(s10, s11, vf0, vf1, acc[0][1], acc[1][1], m[1], llane[1], srcA, srcB, hi);
    }

    float l0 = llane[0]; l0 += __shfl_xor(l0, 16); l0 += __shfl_xor(l0, 32);
    float l1 = llane[1]; l1 += __shfl_xor(l1, 16); l1 += __shfl_xor(l1, 32);

    float* P = pbuf + (size_t)wid * 1088;
    if (g == 0) {
        P[c]      = m[0];  P[16 + c] = m[1];
        P[32 + c] = l0;    P[48 + c] = l1;
    }
    #pragma unroll
    for (int mi = 0; mi < 2; ++mi)
        #pragma unroll
        for (int nt = 0; nt < 2; ++nt)
            *(f32x4*)&P[64 + (c + 16*nt) * 32 + 16*mi + g*4] = acc[mi][nt];
}

// ---------------------------------------------------------------------------
// Merge 16 key-split partials -> ctx (b, Tq, C) bf16.
// ---------------------------------------------------------------------------
__launch_bounds__(256)
__global__ void ca_merge(const float* __restrict__ pbuf, u16* __restrict__ ctx) {
    const int wave = threadIdx.x >> 6, lane = threadIdx.x & 63;
    const int sub = lane >> 5, d = lane & 31;
    const int rowid = blockIdx.x * 8 + wave * 2 + sub;     // 0..8191
    const int q = rowid & 31, qt = (rowid >> 5) & 15, h = (rowid >> 9) & 7, b = rowid >> 12;
    const size_t w0 = (size_t)(((b * 8 + h) * 16 + qt)) * 16;
    float mv[16], lv[16];
    float M = -1e30f;
    #pragma unroll
    for (int i = 0; i < 16; ++i) {
        mv[i] = pbuf[(w0 + i) * 1088 + q];
        lv[i] = pbuf[(w0 + i) * 1088 + 32 + q];
        M = fmaxf(M, mv[i]);
    }
    float L = 0.f, o = 0.f;
    #pragma unroll
    for (int i = 0; i < 16; ++i) {
        const float e = __expf(mv[i] - M);
        L += lv[i] * e;
        o += e * pbuf[(w0 + i) * 1088 + 64 + q * 32 + d];
    }
    const int t = qt * 32 + q;
    ctx[((size_t)b * 512 + t) * 256 + h * 32 + d] = f2bf(o / L);
}

// ---------------------------------------------------------------------------
// Final: out = LN(query + ctx^T).
// ---------------------------------------------------------------------------
__launch_bounds__(256)
__global__ void final_ln(const float* __restrict__ query, const u16* __restrict__ ctx4,
                         const float* __restrict__ g, const float* __restrict__ b,
                         float* __restrict__ out) {
    const int wave = threadIdx.x >> 6, lane = threadIdx.x & 63;
    const int row = blockIdx.x * 4 + wave;        // 0..1023 = t*2+bb
    const int t = row >> 1, bb = row & 1;
    const int c = lane * 4;
    float4 rq = *(const float4*)(query + (size_t)row * 256 + c);
    u16x4 rc = *(const u16x4*)(ctx4 + ((size_t)bb * 512 + t) * 256 + c);
    float x0 = rq.x + bf2f(rc[0]);
    float x1 = rq.y + bf2f(rc[1]);
    float x2 = rq.z + bf2f(rc[2]);
    float x3 = rq.w + bf2f(rc[3]);
    float s1 = x0 + x1 + x2 + x3;
    float s2 = x0*x0 + x1*x1 + x2*x2 + x3*x3;
    #pragma unroll
    for (int off = 32; off; off >>= 1) {
        s1 += __shfl_xor(s1, off);
        s2 += __shfl_xor(s2, off);
    }
    const float mean = s1 * (1.f/256.f);
    const float var  = s2 * (1.f/256.f) - mean*mean;
    const float rstd = rsqrtf(var + 1e-5f);
    float4 gg = *(const float4*)(g + c);
    float4 bv = *(const float4*)(b + c);
    float4 og;
    og.x = (x0-mean)*rstd*gg.x + bv.x;
    og.y = (x1-mean)*rstd*gg.y + bv.y;
    og.z = (x2-mean)*rstd*gg.z + bv.z;
    og.w = (x3-mean)*rstd*gg.w + bv.w;
    *(float4*)(out + (size_t)row * 256 + c) = og;
}

// ---------------------------------------------------------------------------

extern "C" void kernel_launch(void* const* d_in, const int* in_sizes, int n_in,
                              void* d_out, int out_size, void* d_ws, size_t ws_size,
                              hipStream_t stream) {
    const float* x_in  = (const float*)d_in[0];
    const float* query = (const float*)d_in[1];
    const float* n1_g  = (const float*)d_in[2];
    const float* n1_b  = (const float*)d_in[3];
    const float* qkv_w = (const float*)d_in[4];
    const float* qkv_b = (const float*)d_in[5];
    const float* out_w = (const float*)d_in[6];
    const float* out_b = (const float*)d_in[7];
    const float* rel   = (const float*)d_in[8];
    const float* n2_g  = (const float*)d_in[9];
    const float* n2_b  = (const float*)d_in[10];
    const float* fc1_w = (const float*)d_in[11];
    const float* fc1_b = (const float*)d_in[12];
    const float* fc2_w = (const float*)d_in[13];
    const float* fc2_b = (const float*)d_in[14];
    const float* can_g = (const float*)d_in[15];
    const float* can_b = (const float*)d_in[16];
    const float* cpq_w = (const float*)d_in[17];
    const float* cfc_w = (const float*)d_in[18];
    const float* cfc_b = (const float*)d_in[19];
    const float* cf1_w = (const float*)d_in[20];
    const float* cf1_b = (const float*)d_in[21];
    const float* cf2_w = (const float*)d_in[22];
    const float* cf2_b = (const float*)d_in[23];

    const int M = 32768;   // 2 * 128 * 128 tokens

    char* w = (char*)d_ws;
    float* xs  = (float*)w;  w += (size_t)M * 256 * 4;        // fp32 residual stream
    u16* hbuf  = (u16*)w;    w += (size_t)M * 256 * 2;        // bf16 LN/attn out
    u16* big   = (u16*)w;    w += (size_t)M * 1024 * 2;       // bf16 qkv / mlp hidden
    u16* arena = (u16*)w;    w += (size_t)2228224 * 2;        // bf16 weights + query
    u16* qbuf  = (u16*)w;    w += 524288;
    u16* ctx1  = (u16*)w;    w += 524288;
    u16* ctx2  = (u16*)w;    w += 524288;
    u16* ctx3  = (u16*)w;    w += 1048576;
    u16* ctx4  = (u16*)w;    w += 524288;
    u16* xb    = (u16*)w;    w += (size_t)M * 256 * 2;        // bf16 copy of final xs
    float* bfragb = (float*)w; w += 65536 * 4;                // bias C-fragments

    // vtbuf aliases the tail of `big` (qkv uses only M*768 of it; dead by fc1)
    u16* vtbuf = big + (size_t)M * 768;                       // 16 MB
    // CA-phase scratch aliases into `big` (free after the block loop):
    u16*   xbT  = big;                                        // (2,256,16384)
    float* pbuf = (float*)(big + 8388608);                    // 4096 * 1088 f32

    u16* wq   = arena;
    u16* wo   = arena + 393216;
    u16* wf1  = arena + 524288;
    u16* wf2  = arena + 1048576;
    u16* wcpq = arena + 1572864;
    u16* wcfc = arena + 1638400;
    u16* wcf1 = arena + 1703936;
    u16* wcf2 = arena + 1835008;
    u16* qcvt = arena + 1966080;

    cvt_weights<<<2176, 256, 0, stream>>>(qkv_w, out_w, fc1_w, fc2_w, cpq_w,
                                          cfc_w, cf1_w, cf2_w, query, arena);
    bias_frag_kernel<<<64, 256, 0, stream>>>(rel, bfragb);
    hipMemcpyAsync(xs, x_in, (size_t)M * 256 * 4, hipMemcpyDeviceToDevice, stream);

    for (int i = 0; i < 2; ++i) {
        ln_kernel<<<M/4, 256, 0, stream>>>(xs, hbuf, n1_g + i*256, n1_b + i*256, M);
        gemm128<7,false><<<dim3(6,256), 256, 0, stream>>>(
            hbuf, wq + (size_t)i*768*256, qkv_b + i*768, nullptr, big, vtbuf, M, 768, 256);
        win_attn<<<1024, 256, 0, stream>>>(big, vtbuf, bfragb, hbuf, i);
        gemm128<3,true><<<dim3(2,256), 256, 0, stream>>>(
            hbuf, wo + (size_t)i*65536, out_b + i*256, xs, xs, nullptr, M, 256, 256);
        ln_kernel<<<M/4, 256, 0, stream>>>(xs, hbuf, n2_g + i*256, n2_b + i*256, M);
        gemm128<2,false><<<dim3(8,256), 256, 0, stream>>>(
            hbuf, wf1 + (size_t)i*262144, fc1_b + i*1024, nullptr, big, nullptr, M, 1024, 256);
        if (i == 0)
            gemm128<3,true><<<dim3(2,256), 256, 0, stream>>>(
                big, wf2, fc2_b, xs, xs, nullptr, M, 256, 1024);
        else
            gemm128<8,true><<<dim3(2,256), 256, 0, stream>>>(
                big, wf2 + 262144, fc2_b + 256, xs, xs, xb, M, 256, 1024);
    }

    // ---- cross-attention ----
    tr_kernel<<<dim3(256, 4, 2), 256, 0, stream>>>(xb, xbT);
    gemm_bt<6><<<dim3(4, 16), 256, 0, stream>>>(qcvt, wcpq, nullptr, qbuf, 1024, 256, 256);
    ca_flash<<<1024, 256, 0, stream>>>(qbuf, xb, xbT, pbuf);
    ca_merge<<<1024, 256, 0, stream>>>(pbuf, ctx1);
    gemm_bt<5><<<dim3(4, 16), 256, 0, stream>>>(ctx1, wcfc, cfc_b, ctx2, 1024, 256, 256);
    gemm_bt<4><<<dim3(8, 16), 256, 0, stream>>>(ctx2, wcf1, cf1_b, ctx3, 1024, 512, 256);
    gemm_bt<1><<<dim3(4, 16), 256, 0, stream>>>(ctx3, wcf2, cf2_b, ctx4, 1024, 256, 512);
    final_ln<<<256, 256, 0, stream>>>(query, ctx4, can_g, can_b, (float*)d_out);

    (void)in_sizes; (void)n_in; (void)out_size; (void)ws_size;
}

// Round 6
// 525.421 us; speedup vs baseline: 3.2764x; 1.0048x over previous
//
#include <hip/hip_runtime.h>
#include <hip/hip_bf16.h>

// ---------------------------------------------------------------------------
// Swin block ×2 + CrossAttnFFN. FP32 in/out, bf16 MFMA everywhere, fp32 accum.
// Round 6: shuffle-free attention — key-permuted QK^T makes the packed P
//          values land directly in the PV B-fragment layout (no ds_bpermute);
//          log2-domain softmax (exp2f, scales pre-folded).
// ---------------------------------------------------------------------------

typedef unsigned short u16;
typedef u16  u16x4 __attribute__((ext_vector_type(4)));
typedef u16  u16x8 __attribute__((ext_vector_type(8)));
typedef short s16x8 __attribute__((ext_vector_type(8)));
typedef float f32x4 __attribute__((ext_vector_type(4)));
typedef unsigned int u32x4 __attribute__((ext_vector_type(4)));

#define LOG2E 1.4426950408889634f
#define SCALE_LOG2 0.25503480f   // (1/sqrt(32)) * log2(e)

static __device__ __forceinline__ float bf2f(u16 u) {
    union { unsigned int i; float f; } v; v.i = ((unsigned int)u) << 16; return v.f;
}
static __device__ __forceinline__ u16 f2bf(float f) {
    unsigned int x = __float_as_uint(f);
    unsigned int r = x + 0x7fffu + ((x >> 16) & 1u);   // RNE
    return (u16)(r >> 16);
}
static __device__ __forceinline__ unsigned int cvtpk(float a, float b) {
    unsigned int u;
    asm("v_cvt_pk_bf16_f32 %0, %1, %2" : "=v"(u) : "v"(a), "v"(b));
    return u;   // lo = bf16(a), hi = bf16(b)  [validated round 5]
}
static __device__ __forceinline__ void gld16(const u16* g, u16* l) {
    __builtin_amdgcn_global_load_lds(
        (const __attribute__((address_space(1))) unsigned int*)g,
        (__attribute__((address_space(3))) unsigned int*)l, 16, 0, 0);
}

// ---------------------------------------------------------------------------
// fp32 -> bf16 weight/query conversion (one fused kernel).
// ---------------------------------------------------------------------------
__launch_bounds__(256)
__global__ void cvt_weights(const float* __restrict__ qkvw, const float* __restrict__ outw,
                            const float* __restrict__ f1w,  const float* __restrict__ f2w,
                            const float* __restrict__ cpq,  const float* __restrict__ cfc,
                            const float* __restrict__ cf1,  const float* __restrict__ cf2,
                            const float* __restrict__ qry,  u16* __restrict__ dst) {
    const int q = blockIdx.x * 256 + threadIdx.x;
    const int gid = q * 4;
    const float* s; int off;
    if      (gid <  393216) { s = qkvw; off = 0;       }
    else if (gid <  524288) { s = outw; off = 393216;  }
    else if (gid < 1048576) { s = f1w;  off = 524288;  }
    else if (gid < 1572864) { s = f2w;  off = 1048576; }
    else if (gid < 1638400) { s = cpq;  off = 1572864; }
    else if (gid < 1703936) { s = cfc;  off = 1638400; }
    else if (gid < 1835008) { s = cf1;  off = 1703936; }
    else if (gid < 1966080) { s = cf2;  off = 1835008; }
    else                    { s = qry;  off = 1966080; }
    float4 v = *(const float4*)(s + (gid - off));
    u16x4 o; o[0] = f2bf(v.x); o[1] = f2bf(v.y); o[2] = f2bf(v.z); o[3] = f2bf(v.w);
    *(u16x4*)(dst + gid) = o;
}

// ---------------------------------------------------------------------------
// Relative-position bias in MFMA C-fragment layout, PERMUTED key map
// (key = (kt>>1)*32 + 4*(kt&1) + 8*g + j), pre-scaled by log2(e).
// ---------------------------------------------------------------------------
__launch_bounds__(256)
__global__ void bias_frag_kernel(const float* __restrict__ rel, float* __restrict__ bfrag) {
    const int idx = blockIdx.x * 256 + threadIdx.x;      // 0..16383
    #pragma unroll
    for (int j = 0; j < 4; ++j) {
        const int i = idx * 4 + j;
        const int layer = i >> 15, h = (i >> 12) & 7, kt = (i >> 10) & 3,
                  qt = (i >> 8) & 3, lane = (i >> 2) & 63, jj = i & 3;
        const int key   = (kt >> 1) * 32 + 4 * (kt & 1) + 8 * (lane >> 4) + jj;
        const int query = qt * 16 + (lane & 15);
        const int dy = (query >> 3) - (key >> 3) + 7;
        const int dx = (query & 7)  - (key & 7)  + 7;
        bfrag[i] = rel[layer * 1800 + (dy * 15 + dx) * 8 + h] * LOG2E;
    }
}

// ---------------------------------------------------------------------------
// LayerNorm: one wave per row, C=256. fp32 in -> bf16 out.
// ---------------------------------------------------------------------------
__launch_bounds__(256)
__global__ void ln_kernel(const float* __restrict__ in, u16* __restrict__ out,
                          const float* __restrict__ g, const float* __restrict__ b,
                          int rows) {
    const int wave = threadIdx.x >> 6, lane = threadIdx.x & 63;
    const int row = blockIdx.x * 4 + wave;
    if (row >= rows) return;
    const int c = lane * 4;
    float4 v = *(const float4*)(in + (size_t)row * 256 + c);
    float s1 = v.x + v.y + v.z + v.w;
    float s2 = v.x*v.x + v.y*v.y + v.z*v.z + v.w*v.w;
    #pragma unroll
    for (int off = 32; off; off >>= 1) {
        s1 += __shfl_xor(s1, off);
        s2 += __shfl_xor(s2, off);
    }
    const float mean = s1 * (1.f/256.f);
    const float var  = s2 * (1.f/256.f) - mean*mean;
    const float rstd = rsqrtf(var + 1e-5f);
    float4 gg = *(const float4*)(g + c);
    float4 bb = *(const float4*)(b + c);
    u16x4 og;
    og[0] = f2bf((v.x-mean)*rstd*gg.x + bb.x);
    og[1] = f2bf((v.y-mean)*rstd*gg.y + bb.y);
    og[2] = f2bf((v.z-mean)*rstd*gg.z + bb.z);
    og[3] = f2bf((v.w-mean)*rstd*gg.w + bb.w);
    *(u16x4*)(out + (size_t)row * 256 + c) = og;
}

// ---------------------------------------------------------------------------
// 128x128 GEMM (m97 structure): linear LDS + global_load_lds(16B), BK=64.
// EPI: 2 +bias+gelu, 3 +bias+resid(f32), 7 qkv (+bias, scale q, v->vtbuf),
//      8 +bias+resid dual-write (f32 out + bf16 aux)
// ---------------------------------------------------------------------------
template<int EPI, bool F32O>
__launch_bounds__(256)
__global__ void gemm128(const u16* __restrict__ A, const u16* __restrict__ W,
                        const float* __restrict__ bias, const float* __restrict__ resid,
                        void* __restrict__ outv, u16* __restrict__ aux,
                        int M, int N, int K) {
    __shared__ u16 As[128 * 64];
    __shared__ u16 Bs[128 * 64];
    const int m0 = blockIdx.y * 128, n0 = blockIdx.x * 128;
    const int tid = threadIdx.x, lane = tid & 63, wave = tid >> 6;
    const int g = lane >> 4, c = lane & 15;
    const int wm = (wave >> 1) * 64, wn = (wave & 1) * 64;

    f32x4 acc[4][4];
    #pragma unroll
    for (int i = 0; i < 4; ++i)
        #pragma unroll
        for (int j = 0; j < 4; ++j) acc[i][j] = f32x4{0.f,0.f,0.f,0.f};

    const int srow = (lane >> 3), scol = (lane & 7) * 8;   // within 8-row chunk
    for (int k0 = 0; k0 < K; k0 += 64) {
        #pragma unroll
        for (int i = 0; i < 4; ++i) {
            const int ch = wave * 4 + i;             // chunk 0..15 (8 rows each)
            const int r = ch * 8 + srow;
            gld16(&A[(size_t)(m0 + r) * K + k0 + scol], &As[ch * 512]);
            gld16(&W[(size_t)(n0 + r) * K + k0 + scol], &Bs[ch * 512]);
        }
        __syncthreads();
        #pragma unroll
        for (int kk = 0; kk < 64; kk += 32) {
            s16x8 af[4], bf_[4];
            #pragma unroll
            for (int mi = 0; mi < 4; ++mi)
                af[mi] = *(const s16x8*)&As[(wm + mi*16 + c) * 64 + kk + g * 8];
            #pragma unroll
            for (int ni = 0; ni < 4; ++ni)
                bf_[ni] = *(const s16x8*)&Bs[(wn + ni*16 + c) * 64 + kk + g * 8];
            #pragma unroll
            for (int mi = 0; mi < 4; ++mi)
                #pragma unroll
                for (int ni = 0; ni < 4; ++ni)
                    acc[mi][ni] = __builtin_amdgcn_mfma_f32_16x16x32_bf16(
                        af[mi], bf_[ni], acc[mi][ni], 0, 0, 0);
        }
        __syncthreads();
    }

    #pragma unroll
    for (int mi = 0; mi < 4; ++mi) {
        #pragma unroll
        for (int ni = 0; ni < 4; ++ni) {
            const int col = n0 + wn + ni*16 + c;
            #pragma unroll
            for (int j = 0; j < 4; ++j) {
                const int row = m0 + wm + mi*16 + g*4 + j;
                float v = acc[mi][ni][j];
                v += bias[col];
                if (EPI == 2) v = 0.5f * v * (1.f + erff(v * 0.70710678118654752f));
                if (EPI == 3 || EPI == 8) v += resid[(size_t)row * N + col];
                if (EPI == 8) {
                    ((float*)outv)[(size_t)row * N + col] = v;
                    aux[(size_t)row * N + col] = f2bf(v);
                    continue;
                }
                if (EPI == 7) {
                    if (col < 256) v *= SCALE_LOG2;
                    if (col >= 512) {
                        const int bidx = row >> 14, y = (row >> 7) & 127, xx = row & 127;
                        const int wini = (bidx*16 + (y>>3))*16 + (xx>>3);
                        const int key  = ((y&7)<<3) | (xx&7);
                        aux[((size_t)wini*256 + (col-512))*64 + key] = f2bf(v);
                        continue;
                    }
                }
                if (F32O) ((float*)outv)[(size_t)row * N + col] = v;
                else      ((u16*)outv)[(size_t)row * N + col]   = f2bf(v);
            }
        }
    }
}

// ---------------------------------------------------------------------------
// 64x64 GEMM (M=1024 CA GEMMs). EPI: 1 bias, 4 bias+relu, 5 bias+clip32,
// 6 softmax-log2-scale (no bias).
// ---------------------------------------------------------------------------
template<int EPI>
__launch_bounds__(256)
__global__ void gemm_bt(const u16* __restrict__ A, const u16* __restrict__ W,
                        const float* __restrict__ bias, u16* __restrict__ out,
                        int M, int N, int K) {
    __shared__ u16 As[64][72];
    __shared__ u16 Bs[64][72];
    const int m0 = blockIdx.y * 64;
    const int n0 = blockIdx.x * 64;
    const int tid = threadIdx.x;
    const int lane = tid & 63, wave = tid >> 6;
    const int wm = (wave >> 1) * 32, wn = (wave & 1) * 32;

    f32x4 acc[2][2];
    #pragma unroll
    for (int i = 0; i < 2; ++i)
        #pragma unroll
        for (int j = 0; j < 2; ++j) acc[i][j] = f32x4{0.f,0.f,0.f,0.f};

    for (int k0 = 0; k0 < K; k0 += 64) {
        #pragma unroll
        for (int rep = 0; rep < 2; ++rep) {
            int i = tid + rep * 256;
            int r = i >> 3, c = (i & 7) * 8;
            *(s16x8*)&As[r][c] = *(const s16x8*)&A[(size_t)(m0 + r) * K + k0 + c];
            *(s16x8*)&Bs[r][c] = *(const s16x8*)&W[(size_t)(n0 + r) * K + k0 + c];
        }
        __syncthreads();
        #pragma unroll
        for (int kk = 0; kk < 64; kk += 32) {
            s16x8 af[2], bfr[2];
            #pragma unroll
            for (int i = 0; i < 2; ++i) {
                af[i]  = *(const s16x8*)&As[wm + i*16 + (lane & 15)][kk + (lane >> 4) * 8];
                bfr[i] = *(const s16x8*)&Bs[wn + i*16 + (lane & 15)][kk + (lane >> 4) * 8];
            }
            #pragma unroll
            for (int mi = 0; mi < 2; ++mi)
                #pragma unroll
                for (int ni = 0; ni < 2; ++ni)
                    acc[mi][ni] = __builtin_amdgcn_mfma_f32_16x16x32_bf16(
                        af[mi], bfr[ni], acc[mi][ni], 0, 0, 0);
        }
        __syncthreads();
    }

    #pragma unroll
    for (int mi = 0; mi < 2; ++mi) {
        #pragma unroll
        for (int ni = 0; ni < 2; ++ni) {
            const int col = n0 + wn + ni*16 + (lane & 15);
            #pragma unroll
            for (int j = 0; j < 4; ++j) {
                const int row = m0 + wm + mi*16 + (lane >> 4)*4 + j;
                float v = acc[mi][ni][j];
                if (EPI >= 1 && EPI <= 5) v += bias[col];
                if (EPI == 4) v = fmaxf(v, 0.f);
                if (EPI == 5) v = fminf(fmaxf(v, -32.f), 32.f);
                if (EPI == 6) v *= SCALE_LOG2;
                out[(size_t)row * N + col] = f2bf(v);
            }
        }
    }
}

// ---------------------------------------------------------------------------
// MFMA windowed self-attention, shuffle-free. 1 wave per (window, head).
// Key-permuted S tiles: tile kt holds keys (kt>>1)*32 + 4*(kt&1) + 8g + j,
// so packed P words ARE the PV operand fragments.
// ---------------------------------------------------------------------------
__launch_bounds__(256)
__global__ void win_attn(const u16* __restrict__ qkv, const u16* __restrict__ vtbuf,
                         const float* __restrict__ bfrag, u16* __restrict__ o,
                         int layer) {
    const int wid = blockIdx.x * 4 + (threadIdx.x >> 6);   // 0..4095
    const int lane = threadIdx.x & 63;
    const int h = wid & 7, win = wid >> 3;
    const int b = win >> 8, wy = (win >> 4) & 15, wx = win & 15;
    const int g = lane >> 4, c = lane & 15;
    const size_t rowbase = (size_t)b * 16384 + (size_t)wy * 8 * 128 + wx * 8;

    s16x8 qf[4], kf[4];
    #pragma unroll
    for (int qt = 0; qt < 4; ++qt) {
        const int t = qt * 16 + c;
        qf[qt] = *(const s16x8*)&qkv[(rowbase + (size_t)(t >> 3) * 128 + (t & 7)) * 768
                                     + h * 32 + g * 8];
    }
    const int kp0 = 8 * (c >> 2) + (c & 3);       // permuted key row for this lane
    #pragma unroll
    for (int kt = 0; kt < 4; ++kt) {
        const int t = (kt >> 1) * 32 + 4 * (kt & 1) + kp0;
        kf[kt] = *(const s16x8*)&qkv[(rowbase + (size_t)(t >> 3) * 128 + (t & 7)) * 768
                                     + 256 + h * 32 + g * 8];
    }

    const float* bb = bfrag + (size_t)((layer * 8 + h) * 16) * 256;
    f32x4 st[4][4];
    #pragma unroll
    for (int kt = 0; kt < 4; ++kt)
        #pragma unroll
        for (int qt = 0; qt < 4; ++qt)
            st[kt][qt] = *(const f32x4*)&bb[(kt * 4 + qt) * 256 + lane * 4];
    #pragma unroll
    for (int kt = 0; kt < 4; ++kt)
        #pragma unroll
        for (int qt = 0; qt < 4; ++qt)
            st[kt][qt] = __builtin_amdgcn_mfma_f32_16x16x32_bf16(
                kf[kt], qf[qt], st[kt][qt], 0, 0, 0);

    // log2-domain softmax per query column; 1/l deferred to output scale
    float linv[4];
    #pragma unroll
    for (int qt = 0; qt < 4; ++qt) {
        float mx = -1e30f;
        #pragma unroll
        for (int kt = 0; kt < 4; ++kt)
            #pragma unroll
            for (int j = 0; j < 4; ++j) mx = fmaxf(mx, st[kt][qt][j]);
        mx = fmaxf(mx, __shfl_xor(mx, 16));
        mx = fmaxf(mx, __shfl_xor(mx, 32));
        float sum = 0.f;
        #pragma unroll
        for (int kt = 0; kt < 4; ++kt)
            #pragma unroll
            for (int j = 0; j < 4; ++j) {
                const float p = exp2f(st[kt][qt][j] - mx);
                st[kt][qt][j] = p;
                sum += p;
            }
        sum += __shfl_xor(sum, 16);
        sum += __shfl_xor(sum, 32);
        linv[qt] = 1.f / sum;
    }

    const u16* vb = vtbuf + ((size_t)win * 256 + h * 32) * 64;
    s16x8 vf[2][2];
    #pragma unroll
    for (int dt = 0; dt < 2; ++dt)
        #pragma unroll
        for (int ks = 0; ks < 2; ++ks)
            vf[dt][ks] = *(const s16x8*)&vb[(size_t)(dt * 16 + c) * 64 + ks * 32 + g * 8];

    f32x4 acc[4][2];
    #pragma unroll
    for (int i = 0; i < 4; ++i)
        #pragma unroll
        for (int j = 0; j < 2; ++j) acc[i][j] = f32x4{0.f,0.f,0.f,0.f};

    #pragma unroll
    for (int qt = 0; qt < 4; ++qt) {
        #pragma unroll
        for (int ks = 0; ks < 2; ++ks) {
            u32x4 w;
            w[0] = cvtpk(st[2*ks][qt][0],   st[2*ks][qt][1]);
            w[1] = cvtpk(st[2*ks][qt][2],   st[2*ks][qt][3]);
            w[2] = cvtpk(st[2*ks+1][qt][0], st[2*ks+1][qt][1]);
            w[3] = cvtpk(st[2*ks+1][qt][2], st[2*ks+1][qt][3]);
            const s16x8 pfrag = __builtin_bit_cast(s16x8, w);
            acc[qt][0] = __builtin_amdgcn_mfma_f32_16x16x32_bf16(pfrag, vf[0][ks], acc[qt][0], 0,0,0);
            acc[qt][1] = __builtin_amdgcn_mfma_f32_16x16x32_bf16(pfrag, vf[1][ks], acc[qt][1], 0,0,0);
        }
    }

    #pragma unroll
    for (int qt = 0; qt < 4; ++qt)
        #pragma unroll
        for (int dt = 0; dt < 2; ++dt)
            #pragma unroll
            for (int j = 0; j < 4; ++j) {
                const int t = qt * 16 + g * 4 + j;
                o[(rowbase + (size_t)(t >> 3) * 128 + (t & 7)) * 256
                  + h * 32 + dt * 16 + c] = f2bf(acc[qt][dt][j] * linv[qt]);
            }
}

// ---------------------------------------------------------------------------
// Transpose: xbT[b][c][n] = xb[b][n][c].
// ---------------------------------------------------------------------------
__launch_bounds__(256)
__global__ void tr_kernel(const u16* __restrict__ src, u16* __restrict__ dst) {
    __shared__ u16 T[64][72];
    const int b = blockIdx.z;
    const int n0 = blockIdx.x * 64, c0 = blockIdx.y * 64;
    const int r = threadIdx.x >> 3, cc = (threadIdx.x & 7) * 8;
    const u16* S = src + (size_t)b * 16384 * 256;
    u16* D = dst + (size_t)b * 256 * 16384;
    #pragma unroll
    for (int rr = 0; rr < 64; rr += 32)
        *(u16x8*)&T[r + rr][cc] = *(const u16x8*)&S[(size_t)(n0 + r + rr) * 256 + c0 + cc];
    __syncthreads();
    #pragma unroll
    for (int rr = 0; rr < 64; rr += 32) {
        u16x8 v;
        #pragma unroll
        for (int k2 = 0; k2 < 8; ++k2) v[k2] = T[cc + k2][r + rr];
        *(u16x8*)&D[(size_t)(c0 + r + rr) * 16384 + n0 + cc] = v;
    }
}

// ---------------------------------------------------------------------------
// MFMA flash cross-attention v3: shuffle-free (permuted QK^T), defer-max,
// lane-local denom, log2 domain. Wave = (b,h,32 queries,16 key-splits).
// ---------------------------------------------------------------------------
static __device__ __forceinline__ void ca_step(
    const f32x4& sA, const f32x4& sB, const s16x8& vf0, const s16x8& vf1,
    f32x4& acc0, f32x4& acc1, float& m, float& llane)
{
    float smax = fmaxf(fmaxf(fmaxf(sA[0],sA[1]), fmaxf(sA[2],sA[3])),
                       fmaxf(fmaxf(sB[0],sB[1]), fmaxf(sB[2],sB[3])));
    if (!__all(smax <= m + 11.5f)) {          // defer-max (T13), log2 domain
        smax = fmaxf(smax, __shfl_xor(smax, 16));
        smax = fmaxf(smax, __shfl_xor(smax, 32));
        const float mnew = fmaxf(m, smax);
        const float cc = exp2f(m - mnew);
        #pragma unroll
        for (int j = 0; j < 4; ++j) { acc0[j] *= cc; acc1[j] *= cc; }
        llane *= cc;
        m = mnew;
    }
    float p[8];
    #pragma unroll
    for (int j = 0; j < 4; ++j) { p[j] = exp2f(sA[j] - m); p[4+j] = exp2f(sB[j] - m); }
    llane += ((p[0]+p[1]) + (p[2]+p[3])) + ((p[4]+p[5]) + (p[6]+p[7]));
    u32x4 w;
    w[0] = cvtpk(p[0], p[1]);
    w[1] = cvtpk(p[2], p[3]);
    w[2] = cvtpk(p[4], p[5]);
    w[3] = cvtpk(p[6], p[7]);
    const s16x8 pf = __builtin_bit_cast(s16x8, w);
    acc0 = __builtin_amdgcn_mfma_f32_16x16x32_bf16(vf0, pf, acc0, 0, 0, 0);
    acc1 = __builtin_amdgcn_mfma_f32_16x16x32_bf16(vf1, pf, acc1, 0, 0, 0);
}

__launch_bounds__(256)
__global__ void ca_flash(const u16* __restrict__ qb, const u16* __restrict__ xb,
                         const u16* __restrict__ xbT, float* __restrict__ pbuf) {
    const int wid = blockIdx.x * 4 + (threadIdx.x >> 6);   // 0..4095
    const int lane = threadIdx.x & 63;
    const int ks = wid & 15, qt = (wid >> 4) & 15, h = (wid >> 8) & 7, b = wid >> 11;
    const int g = lane >> 4, c = lane & 15;
    const int kp0 = 8 * (c >> 2) + (c & 3);    // permuted key row for this lane

    s16x8 qf[2];
    #pragma unroll
    for (int nt = 0; nt < 2; ++nt) {
        const int q = qt * 32 + nt * 16 + c;
        qf[nt] = *(const s16x8*)&qb[((size_t)q * 2 + b) * 256 + h * 32 + g * 8];
    }
    const u16* Kb = xb  + (size_t)b * 16384 * 256 + h * 32;
    const u16* Vb = xbT + (size_t)b * 256 * 16384 + (size_t)(h * 32) * 16384;

    float m[2] = {-1e30f, -1e30f}, llane[2] = {0.f, 0.f};
    f32x4 acc[2][2];   // [d-tile][q-tile]
    #pragma unroll
    for (int i = 0; i < 2; ++i)
        #pragma unroll
        for (int j = 0; j < 2; ++j) acc[i][j] = f32x4{0.f,0.f,0.f,0.f};

    const int base = ks * 1024;
    const f32x4 zero = f32x4{0.f, 0.f, 0.f, 0.f};
    for (int step = 0; step < 32; ++step) {
        const int n0 = base + step * 32;
        const s16x8 kf0 = *(const s16x8*)&Kb[(size_t)(n0 + kp0) * 256 + g * 8];
        const s16x8 kf1 = *(const s16x8*)&Kb[(size_t)(n0 + kp0 + 4) * 256 + g * 8];
        const s16x8 vf0 = *(const s16x8*)&Vb[(size_t)c * 16384 + n0 + g * 8];
        const s16x8 vf1 = *(const s16x8*)&Vb[(size_t)(16 + c) * 16384 + n0 + g * 8];
        const f32x4 s00 = __builtin_amdgcn_mfma_f32_16x16x32_bf16(kf0, qf[0], zero, 0, 0, 0);
        const f32x4 s01 = __builtin_amdgcn_mfma_f32_16x16x32_bf16(kf1, qf[0], zero, 0, 0, 0);
        const f32x4 s10 = __builtin_amdgcn_mfma_f32_16x16x32_bf16(kf0, qf[1], zero, 0, 0, 0);
        const f32x4 s11 = __builtin_amdgcn_mfma_f32_16x16x32_bf16(kf1, qf[1], zero, 0, 0, 0);
        ca_step(s00, s01, vf0, vf1, acc[0][0], acc[1][0], m[0], llane[0]);
        ca_step(s10, s11, vf0, vf1, acc[0][1], acc[1][1], m[1], llane[1]);
    }

    float l0 = llane[0]; l0 += __shfl_xor(l0, 16); l0 += __shfl_xor(l0, 32);
    float l1 = llane[1]; l1 += __shfl_xor(l1, 16); l1 += __shfl_xor(l1, 32);

    float* P = pbuf + (size_t)wid * 1088;
    if (g == 0) {
        P[c]      = m[0];  P[16 + c] = m[1];
        P[32 + c] = l0;    P[48 + c] = l1;
    }
    #pragma unroll
    for (int mi = 0; mi < 2; ++mi)
        #pragma unroll
        for (int nt = 0; nt < 2; ++nt)
            *(f32x4*)&P[64 + (c + 16*nt) * 32 + 16*mi + g*4] = acc[mi][nt];
}

// ---------------------------------------------------------------------------
// Merge 16 key-split partials -> ctx (b, Tq, C) bf16. (log2-domain stats)
// ---------------------------------------------------------------------------
__launch_bounds__(256)
__global__ void ca_merge(const float* __restrict__ pbuf, u16* __restrict__ ctx) {
    const int wave = threadIdx.x >> 6, lane = threadIdx.x & 63;
    const int sub = lane >> 5, d = lane & 31;
    const int rowid = blockIdx.x * 8 + wave * 2 + sub;     // 0..8191
    const int q = rowid & 31, qt = (rowid >> 5) & 15, h = (rowid >> 9) & 7, b = rowid >> 12;
    const size_t w0 = (size_t)(((b * 8 + h) * 16 + qt)) * 16;
    float mv[16], lv[16];
    float M = -1e30f;
    #pragma unroll
    for (int i = 0; i < 16; ++i) {
        mv[i] = pbuf[(w0 + i) * 1088 + q];
        lv[i] = pbuf[(w0 + i) * 1088 + 32 + q];
        M = fmaxf(M, mv[i]);
    }
    float L = 0.f, o = 0.f;
    #pragma unroll
    for (int i = 0; i < 16; ++i) {
        const float e = exp2f(mv[i] - M);
        L += lv[i] * e;
        o += e * pbuf[(w0 + i) * 1088 + 64 + q * 32 + d];
    }
    const int t = qt * 32 + q;
    ctx[((size_t)b * 512 + t) * 256 + h * 32 + d] = f2bf(o / L);
}

// ---------------------------------------------------------------------------
// Final: out = LN(query + ctx^T).
// ---------------------------------------------------------------------------
__launch_bounds__(256)
__global__ void final_ln(const float* __restrict__ query, const u16* __restrict__ ctx4,
                         const float* __restrict__ g, const float* __restrict__ b,
                         float* __restrict__ out) {
    const int wave = threadIdx.x >> 6, lane = threadIdx.x & 63;
    const int row = blockIdx.x * 4 + wave;        // 0..1023 = t*2+bb
    const int t = row >> 1, bb = row & 1;
    const int c = lane * 4;
    float4 rq = *(const float4*)(query + (size_t)row * 256 + c);
    u16x4 rc = *(const u16x4*)(ctx4 + ((size_t)bb * 512 + t) * 256 + c);
    float x0 = rq.x + bf2f(rc[0]);
    float x1 = rq.y + bf2f(rc[1]);
    float x2 = rq.z + bf2f(rc[2]);
    float x3 = rq.w + bf2f(rc[3]);
    float s1 = x0 + x1 + x2 + x3;
    float s2 = x0*x0 + x1*x1 + x2*x2 + x3*x3;
    #pragma unroll
    for (int off = 32; off; off >>= 1) {
        s1 += __shfl_xor(s1, off);
        s2 += __shfl_xor(s2, off);
    }
    const float mean = s1 * (1.f/256.f);
    const float var  = s2 * (1.f/256.f) - mean*mean;
    const float rstd = rsqrtf(var + 1e-5f);
    float4 gg = *(const float4*)(g + c);
    float4 bv = *(const float4*)(b + c);
    float4 og;
    og.x = (x0-mean)*rstd*gg.x + bv.x;
    og.y = (x1-mean)*rstd*gg.y + bv.y;
    og.z = (x2-mean)*rstd*gg.z + bv.z;
    og.w = (x3-mean)*rstd*gg.w + bv.w;
    *(float4*)(out + (size_t)row * 256 + c) = og;
}

// ---------------------------------------------------------------------------

extern "C" void kernel_launch(void* const* d_in, const int* in_sizes, int n_in,
                              void* d_out, int out_size, void* d_ws, size_t ws_size,
                              hipStream_t stream) {
    const float* x_in  = (const float*)d_in[0];
    const float* query = (const float*)d_in[1];
    const float* n1_g  = (const float*)d_in[2];
    const float* n1_b  = (const float*)d_in[3];
    const float* qkv_w = (const float*)d_in[4];
    const float* qkv_b = (const float*)d_in[5];
    const float* out_w = (const float*)d_in[6];
    const float* out_b = (const float*)d_in[7];
    const float* rel   = (const float*)d_in[8];
    const float* n2_g  = (const float*)d_in[9];
    const float* n2_b  = (const float*)d_in[10];
    const float* fc1_w = (const float*)d_in[11];
    const float* fc1_b = (const float*)d_in[12];
    const float* fc2_w = (const float*)d_in[13];
    const float* fc2_b = (const float*)d_in[14];
    const float* can_g = (const float*)d_in[15];
    const float* can_b = (const float*)d_in[16];
    const float* cpq_w = (const float*)d_in[17];
    const float* cfc_w = (const float*)d_in[18];
    const float* cfc_b = (const float*)d_in[19];
    const float* cf1_w = (const float*)d_in[20];
    const float* cf1_b = (const float*)d_in[21];
    const float* cf2_w = (const float*)d_in[22];
    const float* cf2_b = (const float*)d_in[23];

    const int M = 32768;   // 2 * 128 * 128 tokens

    char* w = (char*)d_ws;
    float* xs  = (float*)w;  w += (size_t)M * 256 * 4;        // fp32 residual stream
    u16* hbuf  = (u16*)w;    w += (size_t)M * 256 * 2;        // bf16 LN/attn out
    u16* big   = (u16*)w;    w += (size_t)M * 1024 * 2;       // bf16 qkv / mlp hidden
    u16* arena = (u16*)w;    w += (size_t)2228224 * 2;        // bf16 weights + query
    u16* qbuf  = (u16*)w;    w += 524288;
    u16* ctx1  = (u16*)w;    w += 524288;
    u16* ctx2  = (u16*)w;    w += 524288;
    u16* ctx3  = (u16*)w;    w += 1048576;
    u16* ctx4  = (u16*)w;    w += 524288;
    u16* xb    = (u16*)w;    w += (size_t)M * 256 * 2;        // bf16 copy of final xs
    float* bfragb = (float*)w; w += 65536 * 4;                // bias C-fragments

    // vtbuf aliases the tail of `big` (qkv uses only M*768 of it; dead by fc1)
    u16* vtbuf = big + (size_t)M * 768;                       // 16 MB
    // CA-phase scratch aliases into `big` (free after the block loop):
    u16*   xbT  = big;                                        // (2,256,16384)
    float* pbuf = (float*)(big + 8388608);                    // 4096 * 1088 f32

    u16* wq   = arena;
    u16* wo   = arena + 393216;
    u16* wf1  = arena + 524288;
    u16* wf2  = arena + 1048576;
    u16* wcpq = arena + 1572864;
    u16* wcfc = arena + 1638400;
    u16* wcf1 = arena + 1703936;
    u16* wcf2 = arena + 1835008;
    u16* qcvt = arena + 1966080;

    cvt_weights<<<2176, 256, 0, stream>>>(qkv_w, out_w, fc1_w, fc2_w, cpq_w,
                                          cfc_w, cf1_w, cf2_w, query, arena);
    bias_frag_kernel<<<64, 256, 0, stream>>>(rel, bfragb);
    hipMemcpyAsync(xs, x_in, (size_t)M * 256 * 4, hipMemcpyDeviceToDevice, stream);

    for (int i = 0; i < 2; ++i) {
        ln_kernel<<<M/4, 256, 0, stream>>>(xs, hbuf, n1_g + i*256, n1_b + i*256, M);
        gemm128<7,false><<<dim3(6,256), 256, 0, stream>>>(
            hbuf, wq + (size_t)i*768*256, qkv_b + i*768, nullptr, big, vtbuf, M, 768, 256);
        win_attn<<<1024, 256, 0, stream>>>(big, vtbuf, bfragb, hbuf, i);
        gemm128<3,true><<<dim3(2,256), 256, 0, stream>>>(
            hbuf, wo + (size_t)i*65536, out_b + i*256, xs, xs, nullptr, M, 256, 256);
        ln_kernel<<<M/4, 256, 0, stream>>>(xs, hbuf, n2_g + i*256, n2_b + i*256, M);
        gemm128<2,false><<<dim3(8,256), 256, 0, stream>>>(
            hbuf, wf1 + (size_t)i*262144, fc1_b + i*1024, nullptr, big, nullptr, M, 1024, 256);
        if (i == 0)
            gemm128<3,true><<<dim3(2,256), 256, 0, stream>>>(
                big, wf2, fc2_b, xs, xs, nullptr, M, 256, 1024);
        else
            gemm128<8,true><<<dim3(2,256), 256, 0, stream>>>(
                big, wf2 + 262144, fc2_b + 256, xs, xs, xb, M, 256, 1024);
    }

    // ---- cross-attention ----
    tr_kernel<<<dim3(256, 4, 2), 256, 0, stream>>>(xb, xbT);
    gemm_bt<6><<<dim3(4, 16), 256, 0, stream>>>(qcvt, wcpq, nullptr, qbuf, 1024, 256, 256);
    ca_flash<<<1024, 256, 0, stream>>>(qbuf, xb, xbT, pbuf);
    ca_merge<<<1024, 256, 0, stream>>>(pbuf, ctx1);
    gemm_bt<5><<<dim3(4, 16), 256, 0, stream>>>(ctx1, wcfc, cfc_b, ctx2, 1024, 256, 256);
    gemm_bt<4><<<dim3(8, 16), 256, 0, stream>>>(ctx2, wcf1, cf1_b, ctx3, 1024, 512, 256);
    gemm_bt<1><<<dim3(4, 16), 256, 0, stream>>>(ctx3, wcf2, cf2_b, ctx4, 1024, 256, 512);
    final_ln<<<256, 256, 0, stream>>>(query, ctx4, can_g, can_b, (float*)d_out);

    (void)in_sizes; (void)n_in; (void)out_size; (void)ws_size;
}

// Round 7
// 517.665 us; speedup vs baseline: 3.3255x; 1.0150x over previous
//
#include <hip/hip_runtime.h>
#include <hip/hip_bf16.h>

// ---------------------------------------------------------------------------
// Swin block ×2 + CrossAttnFFN. FP32 in/out, bf16 MFMA everywhere, fp32 accum.
// Round 7: ca_flash KSPLIT=32 (8 waves/SIMD — TLP for the VALU-bound softmax);
//          input memcpy folded into layer-0 LN / out-proj residual.
// ---------------------------------------------------------------------------

typedef unsigned short u16;
typedef u16  u16x4 __attribute__((ext_vector_type(4)));
typedef u16  u16x8 __attribute__((ext_vector_type(8)));
typedef short s16x8 __attribute__((ext_vector_type(8)));
typedef float f32x4 __attribute__((ext_vector_type(4)));
typedef unsigned int u32x4 __attribute__((ext_vector_type(4)));

#define LOG2E 1.4426950408889634f
#define SCALE_LOG2 0.25503480f   // (1/sqrt(32)) * log2(e)

static __device__ __forceinline__ float bf2f(u16 u) {
    union { unsigned int i; float f; } v; v.i = ((unsigned int)u) << 16; return v.f;
}
static __device__ __forceinline__ u16 f2bf(float f) {
    unsigned int x = __float_as_uint(f);
    unsigned int r = x + 0x7fffu + ((x >> 16) & 1u);   // RNE
    return (u16)(r >> 16);
}
static __device__ __forceinline__ unsigned int cvtpk(float a, float b) {
    unsigned int u;
    asm("v_cvt_pk_bf16_f32 %0, %1, %2" : "=v"(u) : "v"(a), "v"(b));
    return u;   // lo = bf16(a), hi = bf16(b)
}
static __device__ __forceinline__ void gld16(const u16* g, u16* l) {
    __builtin_amdgcn_global_load_lds(
        (const __attribute__((address_space(1))) unsigned int*)g,
        (__attribute__((address_space(3))) unsigned int*)l, 16, 0, 0);
}

// ---------------------------------------------------------------------------
// fp32 -> bf16 weight/query conversion (one fused kernel).
// ---------------------------------------------------------------------------
__launch_bounds__(256)
__global__ void cvt_weights(const float* __restrict__ qkvw, const float* __restrict__ outw,
                            const float* __restrict__ f1w,  const float* __restrict__ f2w,
                            const float* __restrict__ cpq,  const float* __restrict__ cfc,
                            const float* __restrict__ cf1,  const float* __restrict__ cf2,
                            const float* __restrict__ qry,  u16* __restrict__ dst) {
    const int q = blockIdx.x * 256 + threadIdx.x;
    const int gid = q * 4;
    const float* s; int off;
    if      (gid <  393216) { s = qkvw; off = 0;       }
    else if (gid <  524288) { s = outw; off = 393216;  }
    else if (gid < 1048576) { s = f1w;  off = 524288;  }
    else if (gid < 1572864) { s = f2w;  off = 1048576; }
    else if (gid < 1638400) { s = cpq;  off = 1572864; }
    else if (gid < 1703936) { s = cfc;  off = 1638400; }
    else if (gid < 1835008) { s = cf1;  off = 1703936; }
    else if (gid < 1966080) { s = cf2;  off = 1835008; }
    else                    { s = qry;  off = 1966080; }
    float4 v = *(const float4*)(s + (gid - off));
    u16x4 o; o[0] = f2bf(v.x); o[1] = f2bf(v.y); o[2] = f2bf(v.z); o[3] = f2bf(v.w);
    *(u16x4*)(dst + gid) = o;
}

// ---------------------------------------------------------------------------
// Relative-position bias in MFMA C-fragment layout, PERMUTED key map,
// pre-scaled by log2(e).
// ---------------------------------------------------------------------------
__launch_bounds__(256)
__global__ void bias_frag_kernel(const float* __restrict__ rel, float* __restrict__ bfrag) {
    const int idx = blockIdx.x * 256 + threadIdx.x;      // 0..16383
    #pragma unroll
    for (int j = 0; j < 4; ++j) {
        const int i = idx * 4 + j;
        const int layer = i >> 15, h = (i >> 12) & 7, kt = (i >> 10) & 3,
                  qt = (i >> 8) & 3, lane = (i >> 2) & 63, jj = i & 3;
        const int key   = (kt >> 1) * 32 + 4 * (kt & 1) + 8 * (lane >> 4) + jj;
        const int query = qt * 16 + (lane & 15);
        const int dy = (query >> 3) - (key >> 3) + 7;
        const int dx = (query & 7)  - (key & 7)  + 7;
        bfrag[i] = rel[layer * 1800 + (dy * 15 + dx) * 8 + h] * LOG2E;
    }
}

// ---------------------------------------------------------------------------
// LayerNorm: one wave per row, C=256. fp32 in -> bf16 out.
// ---------------------------------------------------------------------------
__launch_bounds__(256)
__global__ void ln_kernel(const float* __restrict__ in, u16* __restrict__ out,
                          const float* __restrict__ g, const float* __restrict__ b,
                          int rows) {
    const int wave = threadIdx.x >> 6, lane = threadIdx.x & 63;
    const int row = blockIdx.x * 4 + wave;
    if (row >= rows) return;
    const int c = lane * 4;
    float4 v = *(const float4*)(in + (size_t)row * 256 + c);
    float s1 = v.x + v.y + v.z + v.w;
    float s2 = v.x*v.x + v.y*v.y + v.z*v.z + v.w*v.w;
    #pragma unroll
    for (int off = 32; off; off >>= 1) {
        s1 += __shfl_xor(s1, off);
        s2 += __shfl_xor(s2, off);
    }
    const float mean = s1 * (1.f/256.f);
    const float var  = s2 * (1.f/256.f) - mean*mean;
    const float rstd = rsqrtf(var + 1e-5f);
    float4 gg = *(const float4*)(g + c);
    float4 bb = *(const float4*)(b + c);
    u16x4 og;
    og[0] = f2bf((v.x-mean)*rstd*gg.x + bb.x);
    og[1] = f2bf((v.y-mean)*rstd*gg.y + bb.y);
    og[2] = f2bf((v.z-mean)*rstd*gg.z + bb.z);
    og[3] = f2bf((v.w-mean)*rstd*gg.w + bb.w);
    *(u16x4*)(out + (size_t)row * 256 + c) = og;
}

// ---------------------------------------------------------------------------
// 128x128 GEMM (m97 structure): linear LDS + global_load_lds(16B), BK=64.
// EPI: 2 +bias+gelu, 3 +bias+resid(f32), 7 qkv (+bias, scale q, v->vtbuf),
//      8 +bias+resid dual-write (f32 out + bf16 aux)
// ---------------------------------------------------------------------------
template<int EPI, bool F32O>
__launch_bounds__(256)
__global__ void gemm128(const u16* __restrict__ A, const u16* __restrict__ W,
                        const float* __restrict__ bias, const float* __restrict__ resid,
                        void* __restrict__ outv, u16* __restrict__ aux,
                        int M, int N, int K) {
    __shared__ u16 As[128 * 64];
    __shared__ u16 Bs[128 * 64];
    const int m0 = blockIdx.y * 128, n0 = blockIdx.x * 128;
    const int tid = threadIdx.x, lane = tid & 63, wave = tid >> 6;
    const int g = lane >> 4, c = lane & 15;
    const int wm = (wave >> 1) * 64, wn = (wave & 1) * 64;

    f32x4 acc[4][4];
    #pragma unroll
    for (int i = 0; i < 4; ++i)
        #pragma unroll
        for (int j = 0; j < 4; ++j) acc[i][j] = f32x4{0.f,0.f,0.f,0.f};

    const int srow = (lane >> 3), scol = (lane & 7) * 8;   // within 8-row chunk
    for (int k0 = 0; k0 < K; k0 += 64) {
        #pragma unroll
        for (int i = 0; i < 4; ++i) {
            const int ch = wave * 4 + i;             // chunk 0..15 (8 rows each)
            const int r = ch * 8 + srow;
            gld16(&A[(size_t)(m0 + r) * K + k0 + scol], &As[ch * 512]);
            gld16(&W[(size_t)(n0 + r) * K + k0 + scol], &Bs[ch * 512]);
        }
        __syncthreads();
        #pragma unroll
        for (int kk = 0; kk < 64; kk += 32) {
            s16x8 af[4], bf_[4];
            #pragma unroll
            for (int mi = 0; mi < 4; ++mi)
                af[mi] = *(const s16x8*)&As[(wm + mi*16 + c) * 64 + kk + g * 8];
            #pragma unroll
            for (int ni = 0; ni < 4; ++ni)
                bf_[ni] = *(const s16x8*)&Bs[(wn + ni*16 + c) * 64 + kk + g * 8];
            #pragma unroll
            for (int mi = 0; mi < 4; ++mi)
                #pragma unroll
                for (int ni = 0; ni < 4; ++ni)
                    acc[mi][ni] = __builtin_amdgcn_mfma_f32_16x16x32_bf16(
                        af[mi], bf_[ni], acc[mi][ni], 0, 0, 0);
        }
        __syncthreads();
    }

    #pragma unroll
    for (int mi = 0; mi < 4; ++mi) {
        #pragma unroll
        for (int ni = 0; ni < 4; ++ni) {
            const int col = n0 + wn + ni*16 + c;
            #pragma unroll
            for (int j = 0; j < 4; ++j) {
                const int row = m0 + wm + mi*16 + g*4 + j;
                float v = acc[mi][ni][j];
                v += bias[col];
                if (EPI == 2) v = 0.5f * v * (1.f + erff(v * 0.70710678118654752f));
                if (EPI == 3 || EPI == 8) v += resid[(size_t)row * N + col];
                if (EPI == 8) {
                    ((float*)outv)[(size_t)row * N + col] = v;
                    aux[(size_t)row * N + col] = f2bf(v);
                    continue;
                }
                if (EPI == 7) {
                    if (col < 256) v *= SCALE_LOG2;
                    if (col >= 512) {
                        const int bidx = row >> 14, y = (row >> 7) & 127, xx = row & 127;
                        const int wini = (bidx*16 + (y>>3))*16 + (xx>>3);
                        const int key  = ((y&7)<<3) | (xx&7);
                        aux[((size_t)wini*256 + (col-512))*64 + key] = f2bf(v);
                        continue;
                    }
                }
                if (F32O) ((float*)outv)[(size_t)row * N + col] = v;
                else      ((u16*)outv)[(size_t)row * N + col]   = f2bf(v);
            }
        }
    }
}

// ---------------------------------------------------------------------------
// 64x64 GEMM (M=1024 CA GEMMs). EPI: 1 bias, 4 bias+relu, 5 bias+clip32,
// 6 softmax-log2-scale (no bias).
// ---------------------------------------------------------------------------
template<int EPI>
__launch_bounds__(256)
__global__ void gemm_bt(const u16* __restrict__ A, const u16* __restrict__ W,
                        const float* __restrict__ bias, u16* __restrict__ out,
                        int M, int N, int K) {
    __shared__ u16 As[64][72];
    __shared__ u16 Bs[64][72];
    const int m0 = blockIdx.y * 64;
    const int n0 = blockIdx.x * 64;
    const int tid = threadIdx.x;
    const int lane = tid & 63, wave = tid >> 6;
    const int wm = (wave >> 1) * 32, wn = (wave & 1) * 32;

    f32x4 acc[2][2];
    #pragma unroll
    for (int i = 0; i < 2; ++i)
        #pragma unroll
        for (int j = 0; j < 2; ++j) acc[i][j] = f32x4{0.f,0.f,0.f,0.f};

    for (int k0 = 0; k0 < K; k0 += 64) {
        #pragma unroll
        for (int rep = 0; rep < 2; ++rep) {
            int i = tid + rep * 256;
            int r = i >> 3, c = (i & 7) * 8;
            *(s16x8*)&As[r][c] = *(const s16x8*)&A[(size_t)(m0 + r) * K + k0 + c];
            *(s16x8*)&Bs[r][c] = *(const s16x8*)&W[(size_t)(n0 + r) * K + k0 + c];
        }
        __syncthreads();
        #pragma unroll
        for (int kk = 0; kk < 64; kk += 32) {
            s16x8 af[2], bfr[2];
            #pragma unroll
            for (int i = 0; i < 2; ++i) {
                af[i]  = *(const s16x8*)&As[wm + i*16 + (lane & 15)][kk + (lane >> 4) * 8];
                bfr[i] = *(const s16x8*)&Bs[wn + i*16 + (lane & 15)][kk + (lane >> 4) * 8];
            }
            #pragma unroll
            for (int mi = 0; mi < 2; ++mi)
                #pragma unroll
                for (int ni = 0; ni < 2; ++ni)
                    acc[mi][ni] = __builtin_amdgcn_mfma_f32_16x16x32_bf16(
                        af[mi], bfr[ni], acc[mi][ni], 0, 0, 0);
        }
        __syncthreads();
    }

    #pragma unroll
    for (int mi = 0; mi < 2; ++mi) {
        #pragma unroll
        for (int ni = 0; ni < 2; ++ni) {
            const int col = n0 + wn + ni*16 + (lane & 15);
            #pragma unroll
            for (int j = 0; j < 4; ++j) {
                const int row = m0 + wm + mi*16 + (lane >> 4)*4 + j;
                float v = acc[mi][ni][j];
                if (EPI >= 1 && EPI <= 5) v += bias[col];
                if (EPI == 4) v = fmaxf(v, 0.f);
                if (EPI == 5) v = fminf(fmaxf(v, -32.f), 32.f);
                if (EPI == 6) v *= SCALE_LOG2;
                out[(size_t)row * N + col] = f2bf(v);
            }
        }
    }
}

// ---------------------------------------------------------------------------
// MFMA windowed self-attention, shuffle-free (permuted key map).
// ---------------------------------------------------------------------------
__launch_bounds__(256)
__global__ void win_attn(const u16* __restrict__ qkv, const u16* __restrict__ vtbuf,
                         const float* __restrict__ bfrag, u16* __restrict__ o,
                         int layer) {
    const int wid = blockIdx.x * 4 + (threadIdx.x >> 6);   // 0..4095
    const int lane = threadIdx.x & 63;
    const int h = wid & 7, win = wid >> 3;
    const int b = win >> 8, wy = (win >> 4) & 15, wx = win & 15;
    const int g = lane >> 4, c = lane & 15;
    const size_t rowbase = (size_t)b * 16384 + (size_t)wy * 8 * 128 + wx * 8;

    s16x8 qf[4], kf[4];
    #pragma unroll
    for (int qt = 0; qt < 4; ++qt) {
        const int t = qt * 16 + c;
        qf[qt] = *(const s16x8*)&qkv[(rowbase + (size_t)(t >> 3) * 128 + (t & 7)) * 768
                                     + h * 32 + g * 8];
    }
    const int kp0 = 8 * (c >> 2) + (c & 3);       // permuted key row for this lane
    #pragma unroll
    for (int kt = 0; kt < 4; ++kt) {
        const int t = (kt >> 1) * 32 + 4 * (kt & 1) + kp0;
        kf[kt] = *(const s16x8*)&qkv[(rowbase + (size_t)(t >> 3) * 128 + (t & 7)) * 768
                                     + 256 + h * 32 + g * 8];
    }

    const float* bb = bfrag + (size_t)((layer * 8 + h) * 16) * 256;
    f32x4 st[4][4];
    #pragma unroll
    for (int kt = 0; kt < 4; ++kt)
        #pragma unroll
        for (int qt = 0; qt < 4; ++qt)
            st[kt][qt] = *(const f32x4*)&bb[(kt * 4 + qt) * 256 + lane * 4];
    #pragma unroll
    for (int kt = 0; kt < 4; ++kt)
        #pragma unroll
        for (int qt = 0; qt < 4; ++qt)
            st[kt][qt] = __builtin_amdgcn_mfma_f32_16x16x32_bf16(
                kf[kt], qf[qt], st[kt][qt], 0, 0, 0);

    float linv[4];
    #pragma unroll
    for (int qt = 0; qt < 4; ++qt) {
        float mx = -1e30f;
        #pragma unroll
        for (int kt = 0; kt < 4; ++kt)
            #pragma unroll
            for (int j = 0; j < 4; ++j) mx = fmaxf(mx, st[kt][qt][j]);
        mx = fmaxf(mx, __shfl_xor(mx, 16));
        mx = fmaxf(mx, __shfl_xor(mx, 32));
        float sum = 0.f;
        #pragma unroll
        for (int kt = 0; kt < 4; ++kt)
            #pragma unroll
            for (int j = 0; j < 4; ++j) {
                const float p = exp2f(st[kt][qt][j] - mx);
                st[kt][qt][j] = p;
                sum += p;
            }
        sum += __shfl_xor(sum, 16);
        sum += __shfl_xor(sum, 32);
        linv[qt] = 1.f / sum;
    }

    const u16* vb = vtbuf + ((size_t)win * 256 + h * 32) * 64;
    s16x8 vf[2][2];
    #pragma unroll
    for (int dt = 0; dt < 2; ++dt)
        #pragma unroll
        for (int ks = 0; ks < 2; ++ks)
            vf[dt][ks] = *(const s16x8*)&vb[(size_t)(dt * 16 + c) * 64 + ks * 32 + g * 8];

    f32x4 acc[4][2];
    #pragma unroll
    for (int i = 0; i < 4; ++i)
        #pragma unroll
        for (int j = 0; j < 2; ++j) acc[i][j] = f32x4{0.f,0.f,0.f,0.f};

    #pragma unroll
    for (int qt = 0; qt < 4; ++qt) {
        #pragma unroll
        for (int ks = 0; ks < 2; ++ks) {
            u32x4 w;
            w[0] = cvtpk(st[2*ks][qt][0],   st[2*ks][qt][1]);
            w[1] = cvtpk(st[2*ks][qt][2],   st[2*ks][qt][3]);
            w[2] = cvtpk(st[2*ks+1][qt][0], st[2*ks+1][qt][1]);
            w[3] = cvtpk(st[2*ks+1][qt][2], st[2*ks+1][qt][3]);
            const s16x8 pfrag = __builtin_bit_cast(s16x8, w);
            acc[qt][0] = __builtin_amdgcn_mfma_f32_16x16x32_bf16(pfrag, vf[0][ks], acc[qt][0], 0,0,0);
            acc[qt][1] = __builtin_amdgcn_mfma_f32_16x16x32_bf16(pfrag, vf[1][ks], acc[qt][1], 0,0,0);
        }
    }

    #pragma unroll
    for (int qt = 0; qt < 4; ++qt)
        #pragma unroll
        for (int dt = 0; dt < 2; ++dt)
            #pragma unroll
            for (int j = 0; j < 4; ++j) {
                const int t = qt * 16 + g * 4 + j;
                o[(rowbase + (size_t)(t >> 3) * 128 + (t & 7)) * 256
                  + h * 32 + dt * 16 + c] = f2bf(acc[qt][dt][j] * linv[qt]);
            }
}

// ---------------------------------------------------------------------------
// Transpose: xbT[b][c][n] = xb[b][n][c].
// ---------------------------------------------------------------------------
__launch_bounds__(256)
__global__ void tr_kernel(const u16* __restrict__ src, u16* __restrict__ dst) {
    __shared__ u16 T[64][72];
    const int b = blockIdx.z;
    const int n0 = blockIdx.x * 64, c0 = blockIdx.y * 64;
    const int r = threadIdx.x >> 3, cc = (threadIdx.x & 7) * 8;
    const u16* S = src + (size_t)b * 16384 * 256;
    u16* D = dst + (size_t)b * 256 * 16384;
    #pragma unroll
    for (int rr = 0; rr < 64; rr += 32)
        *(u16x8*)&T[r + rr][cc] = *(const u16x8*)&S[(size_t)(n0 + r + rr) * 256 + c0 + cc];
    __syncthreads();
    #pragma unroll
    for (int rr = 0; rr < 64; rr += 32) {
        u16x8 v;
        #pragma unroll
        for (int k2 = 0; k2 < 8; ++k2) v[k2] = T[cc + k2][r + rr];
        *(u16x8*)&D[(size_t)(c0 + r + rr) * 16384 + n0 + cc] = v;
    }
}

// ---------------------------------------------------------------------------
// MFMA flash cross-attention: shuffle-free, defer-max, lane-local denom,
// log2 domain. KSPLIT=32: wave = (b,h,32 queries, 512-key split).
// ---------------------------------------------------------------------------
static __device__ __forceinline__ void ca_step(
    const f32x4& sA, const f32x4& sB, const s16x8& vf0, const s16x8& vf1,
    f32x4& acc0, f32x4& acc1, float& m, float& llane)
{
    float smax = fmaxf(fmaxf(fmaxf(sA[0],sA[1]), fmaxf(sA[2],sA[3])),
                       fmaxf(fmaxf(sB[0],sB[1]), fmaxf(sB[2],sB[3])));
    if (!__all(smax <= m + 11.5f)) {          // defer-max (T13), log2 domain
        smax = fmaxf(smax, __shfl_xor(smax, 16));
        smax = fmaxf(smax, __shfl_xor(smax, 32));
        const float mnew = fmaxf(m, smax);
        const float cc = exp2f(m - mnew);
        #pragma unroll
        for (int j = 0; j < 4; ++j) { acc0[j] *= cc; acc1[j] *= cc; }
        llane *= cc;
        m = mnew;
    }
    float p[8];
    #pragma unroll
    for (int j = 0; j < 4; ++j) { p[j] = exp2f(sA[j] - m); p[4+j] = exp2f(sB[j] - m); }
    llane += ((p[0]+p[1]) + (p[2]+p[3])) + ((p[4]+p[5]) + (p[6]+p[7]));
    u32x4 w;
    w[0] = cvtpk(p[0], p[1]);
    w[1] = cvtpk(p[2], p[3]);
    w[2] = cvtpk(p[4], p[5]);
    w[3] = cvtpk(p[6], p[7]);
    const s16x8 pf = __builtin_bit_cast(s16x8, w);
    acc0 = __builtin_amdgcn_mfma_f32_16x16x32_bf16(vf0, pf, acc0, 0, 0, 0);
    acc1 = __builtin_amdgcn_mfma_f32_16x16x32_bf16(vf1, pf, acc1, 0, 0, 0);
}

__launch_bounds__(256)
__global__ void ca_flash(const u16* __restrict__ qb, const u16* __restrict__ xb,
                         const u16* __restrict__ xbT, float* __restrict__ pbuf) {
    const int wid = blockIdx.x * 4 + (threadIdx.x >> 6);   // 0..8191
    const int lane = threadIdx.x & 63;
    const int ks = wid & 31, qt = (wid >> 5) & 15, h = (wid >> 9) & 7, b = wid >> 12;
    const int g = lane >> 4, c = lane & 15;
    const int kp0 = 8 * (c >> 2) + (c & 3);    // permuted key row for this lane

    s16x8 qf[2];
    #pragma unroll
    for (int nt = 0; nt < 2; ++nt) {
        const int q = qt * 32 + nt * 16 + c;
        qf[nt] = *(const s16x8*)&qb[((size_t)q * 2 + b) * 256 + h * 32 + g * 8];
    }
    const u16* Kb = xb  + (size_t)b * 16384 * 256 + h * 32;
    const u16* Vb = xbT + (size_t)b * 256 * 16384 + (size_t)(h * 32) * 16384;

    float m[2] = {-1e30f, -1e30f}, llane[2] = {0.f, 0.f};
    f32x4 acc[2][2];   // [d-tile][q-tile]
    #pragma unroll
    for (int i = 0; i < 2; ++i)
        #pragma unroll
        for (int j = 0; j < 2; ++j) acc[i][j] = f32x4{0.f,0.f,0.f,0.f};

    const int base = ks * 512;
    const f32x4 zero = f32x4{0.f, 0.f, 0.f, 0.f};
    for (int step = 0; step < 16; ++step) {
        const int n0 = base + step * 32;
        const s16x8 kf0 = *(const s16x8*)&Kb[(size_t)(n0 + kp0) * 256 + g * 8];
        const s16x8 kf1 = *(const s16x8*)&Kb[(size_t)(n0 + kp0 + 4) * 256 + g * 8];
        const s16x8 vf0 = *(const s16x8*)&Vb[(size_t)c * 16384 + n0 + g * 8];
        const s16x8 vf1 = *(const s16x8*)&Vb[(size_t)(16 + c) * 16384 + n0 + g * 8];
        const f32x4 s00 = __builtin_amdgcn_mfma_f32_16x16x32_bf16(kf0, qf[0], zero, 0, 0, 0);
        const f32x4 s01 = __builtin_amdgcn_mfma_f32_16x16x32_bf16(kf1, qf[0], zero, 0, 0, 0);
        const f32x4 s10 = __builtin_amdgcn_mfma_f32_16x16x32_bf16(kf0, qf[1], zero, 0, 0, 0);
        const f32x4 s11 = __builtin_amdgcn_mfma_f32_16x16x32_bf16(kf1, qf[1], zero, 0, 0, 0);
        ca_step(s00, s01, vf0, vf1, acc[0][0], acc[1][0], m[0], llane[0]);
        ca_step(s10, s11, vf0, vf1, acc[0][1], acc[1][1], m[1], llane[1]);
    }

    float l0 = llane[0]; l0 += __shfl_xor(l0, 16); l0 += __shfl_xor(l0, 32);
    float l1 = llane[1]; l1 += __shfl_xor(l1, 16); l1 += __shfl_xor(l1, 32);

    float* P = pbuf + (size_t)wid * 1088;
    if (g == 0) {
        P[c]      = m[0];  P[16 + c] = m[1];
        P[32 + c] = l0;    P[48 + c] = l1;
    }
    #pragma unroll
    for (int mi = 0; mi < 2; ++mi)
        #pragma unroll
        for (int nt = 0; nt < 2; ++nt)
            *(f32x4*)&P[64 + (c + 16*nt) * 32 + 16*mi + g*4] = acc[mi][nt];
}

// ---------------------------------------------------------------------------
// Merge 32 key-split partials -> ctx (b, Tq, C) bf16. (log2-domain stats)
// ---------------------------------------------------------------------------
__launch_bounds__(256)
__global__ void ca_merge(const float* __restrict__ pbuf, u16* __restrict__ ctx) {
    const int wave = threadIdx.x >> 6, lane = threadIdx.x & 63;
    const int sub = lane >> 5, d = lane & 31;
    const int rowid = blockIdx.x * 8 + wave * 2 + sub;     // 0..8191
    const int q = rowid & 31, qt = (rowid >> 5) & 15, h = (rowid >> 9) & 7, b = rowid >> 12;
    const size_t w0 = (size_t)(((b * 8 + h) * 16 + qt)) * 32;
    float mv[32], lv[32];
    float M = -1e30f;
    #pragma unroll
    for (int i = 0; i < 32; ++i) {
        mv[i] = pbuf[(w0 + i) * 1088 + q];
        lv[i] = pbuf[(w0 + i) * 1088 + 32 + q];
        M = fmaxf(M, mv[i]);
    }
    float L = 0.f, o = 0.f;
    #pragma unroll
    for (int i = 0; i < 32; ++i) {
        const float e = exp2f(mv[i] - M);
        L += lv[i] * e;
        o += e * pbuf[(w0 + i) * 1088 + 64 + q * 32 + d];
    }
    const int t = qt * 32 + q;
    ctx[((size_t)b * 512 + t) * 256 + h * 32 + d] = f2bf(o / L);
}

// ---------------------------------------------------------------------------
// Final: out = LN(query + ctx^T).
// ---------------------------------------------------------------------------
__launch_bounds__(256)
__global__ void final_ln(const float* __restrict__ query, const u16* __restrict__ ctx4,
                         const float* __restrict__ g, const float* __restrict__ b,
                         float* __restrict__ out) {
    const int wave = threadIdx.x >> 6, lane = threadIdx.x & 63;
    const int row = blockIdx.x * 4 + wave;        // 0..1023 = t*2+bb
    const int t = row >> 1, bb = row & 1;
    const int c = lane * 4;
    float4 rq = *(const float4*)(query + (size_t)row * 256 + c);
    u16x4 rc = *(const u16x4*)(ctx4 + ((size_t)bb * 512 + t) * 256 + c);
    float x0 = rq.x + bf2f(rc[0]);
    float x1 = rq.y + bf2f(rc[1]);
    float x2 = rq.z + bf2f(rc[2]);
    float x3 = rq.w + bf2f(rc[3]);
    float s1 = x0 + x1 + x2 + x3;
    float s2 = x0*x0 + x1*x1 + x2*x2 + x3*x3;
    #pragma unroll
    for (int off = 32; off; off >>= 1) {
        s1 += __shfl_xor(s1, off);
        s2 += __shfl_xor(s2, off);
    }
    const float mean = s1 * (1.f/256.f);
    const float var  = s2 * (1.f/256.f) - mean*mean;
    const float rstd = rsqrtf(var + 1e-5f);
    float4 gg = *(const float4*)(g + c);
    float4 bv = *(const float4*)(b + c);
    float4 og;
    og.x = (x0-mean)*rstd*gg.x + bv.x;
    og.y = (x1-mean)*rstd*gg.y + bv.y;
    og.z = (x2-mean)*rstd*gg.z + bv.z;
    og.w = (x3-mean)*rstd*gg.w + bv.w;
    *(float4*)(out + (size_t)row * 256 + c) = og;
}

// ---------------------------------------------------------------------------

extern "C" void kernel_launch(void* const* d_in, const int* in_sizes, int n_in,
                              void* d_out, int out_size, void* d_ws, size_t ws_size,
                              hipStream_t stream) {
    const float* x_in  = (const float*)d_in[0];
    const float* query = (const float*)d_in[1];
    const float* n1_g  = (const float*)d_in[2];
    const float* n1_b  = (const float*)d_in[3];
    const float* qkv_w = (const float*)d_in[4];
    const float* qkv_b = (const float*)d_in[5];
    const float* out_w = (const float*)d_in[6];
    const float* out_b = (const float*)d_in[7];
    const float* rel   = (const float*)d_in[8];
    const float* n2_g  = (const float*)d_in[9];
    const float* n2_b  = (const float*)d_in[10];
    const float* fc1_w = (const float*)d_in[11];
    const float* fc1_b = (const float*)d_in[12];
    const float* fc2_w = (const float*)d_in[13];
    const float* fc2_b = (const float*)d_in[14];
    const float* can_g = (const float*)d_in[15];
    const float* can_b = (const float*)d_in[16];
    const float* cpq_w = (const float*)d_in[17];
    const float* cfc_w = (const float*)d_in[18];
    const float* cfc_b = (const float*)d_in[19];
    const float* cf1_w = (const float*)d_in[20];
    const float* cf1_b = (const float*)d_in[21];
    const float* cf2_w = (const float*)d_in[22];
    const float* cf2_b = (const float*)d_in[23];

    const int M = 32768;   // 2 * 128 * 128 tokens

    char* w = (char*)d_ws;
    float* xs  = (float*)w;  w += (size_t)M * 256 * 4;        // fp32 residual stream
    u16* hbuf  = (u16*)w;    w += (size_t)M * 256 * 2;        // bf16 LN/attn out
    u16* big   = (u16*)w;    w += (size_t)M * 1024 * 2;       // bf16 qkv / mlp hidden
    u16* arena = (u16*)w;    w += (size_t)2228224 * 2;        // bf16 weights + query
    u16* qbuf  = (u16*)w;    w += 524288;
    u16* ctx1  = (u16*)w;    w += 524288;
    u16* ctx2  = (u16*)w;    w += 524288;
    u16* ctx3  = (u16*)w;    w += 1048576;
    u16* ctx4  = (u16*)w;    w += 524288;
    u16* xb    = (u16*)w;    w += (size_t)M * 256 * 2;        // bf16 copy of final xs
    float* bfragb = (float*)w; w += 65536 * 4;                // bias C-fragments

    // vtbuf aliases the tail of `big` (qkv uses only M*768 of it; dead by fc1)
    u16* vtbuf = big + (size_t)M * 768;                       // 16 MB
    // CA-phase scratch aliases into `big` (free after the block loop):
    u16*   xbT  = big;                                        // (2,256,16384) 16 MB
    float* pbuf = (float*)(big + 8388608);                    // 8192 * 1088 f32 = 35.7 MB

    u16* wq   = arena;
    u16* wo   = arena + 393216;
    u16* wf1  = arena + 524288;
    u16* wf2  = arena + 1048576;
    u16* wcpq = arena + 1572864;
    u16* wcfc = arena + 1638400;
    u16* wcf1 = arena + 1703936;
    u16* wcf2 = arena + 1835008;
    u16* qcvt = arena + 1966080;

    cvt_weights<<<2176, 256, 0, stream>>>(qkv_w, out_w, fc1_w, fc2_w, cpq_w,
                                          cfc_w, cf1_w, cf2_w, query, arena);
    bias_frag_kernel<<<64, 256, 0, stream>>>(rel, bfragb);

    for (int i = 0; i < 2; ++i) {
        const float* src = (i == 0) ? x_in : xs;   // layer-0 reads input directly
        ln_kernel<<<M/4, 256, 0, stream>>>(src, hbuf, n1_g + i*256, n1_b + i*256, M);
        gemm128<7,false><<<dim3(6,256), 256, 0, stream>>>(
            hbuf, wq + (size_t)i*768*256, qkv_b + i*768, nullptr, big, vtbuf, M, 768, 256);
        win_attn<<<1024, 256, 0, stream>>>(big, vtbuf, bfragb, hbuf, i);
        gemm128<3,true><<<dim3(2,256), 256, 0, stream>>>(
            hbuf, wo + (size_t)i*65536, out_b + i*256, src, xs, nullptr, M, 256, 256);
        ln_kernel<<<M/4, 256, 0, stream>>>(xs, hbuf, n2_g + i*256, n2_b + i*256, M);
        gemm128<2,false><<<dim3(8,256), 256, 0, stream>>>(
            hbuf, wf1 + (size_t)i*262144, fc1_b + i*1024, nullptr, big, nullptr, M, 1024, 256);
        if (i == 0)
            gemm128<3,true><<<dim3(2,256), 256, 0, stream>>>(
                big, wf2, fc2_b, xs, xs, nullptr, M, 256, 1024);
        else
            gemm128<8,true><<<dim3(2,256), 256, 0, stream>>>(
                big, wf2 + 262144, fc2_b + 256, xs, xs, xb, M, 256, 1024);
    }

    // ---- cross-attention ----
    tr_kernel<<<dim3(256, 4, 2), 256, 0, stream>>>(xb, xbT);
    gemm_bt<6><<<dim3(4, 16), 256, 0, stream>>>(qcvt, wcpq, nullptr, qbuf, 1024, 256, 256);
    ca_flash<<<2048, 256, 0, stream>>>(qbuf, xb, xbT, pbuf);
    ca_merge<<<1024, 256, 0, stream>>>(pbuf, ctx1);
    gemm_bt<5><<<dim3(4, 16), 256, 0, stream>>>(ctx1, wcfc, cfc_b, ctx2, 1024, 256, 256);
    gemm_bt<4><<<dim3(8, 16), 256, 0, stream>>>(ctx2, wcf1, cf1_b, ctx3, 1024, 512, 256);
    gemm_bt<1><<<dim3(4, 16), 256, 0, stream>>>(ctx3, wcf2, cf2_b, ctx4, 1024, 256, 512);
    final_ln<<<256, 256, 0, stream>>>(query, ctx4, can_g, can_b, (float*)d_out);

    (void)in_sizes; (void)n_in; (void)out_size; (void)ws_size;
}

// Round 8
// 488.663 us; speedup vs baseline: 3.5228x; 1.0593x over previous
//
#include <hip/hip_runtime.h>
#include <hip/hip_bf16.h>

// ---------------------------------------------------------------------------
// Swin block ×2 + CrossAttnFFN. FP32 in/out, bf16 MFMA everywhere, fp32 accum.
// Round 8: ca_flash 64 queries/wave (halves K/V cache traffic: 512->256 MB);
//          XCD-aware bijective block swizzle in gemm128 (A-panel L2 locality).
// ---------------------------------------------------------------------------

typedef unsigned short u16;
typedef u16  u16x4 __attribute__((ext_vector_type(4)));
typedef u16  u16x8 __attribute__((ext_vector_type(8)));
typedef short s16x8 __attribute__((ext_vector_type(8)));
typedef float f32x4 __attribute__((ext_vector_type(4)));
typedef unsigned int u32x4 __attribute__((ext_vector_type(4)));

#define LOG2E 1.4426950408889634f
#define SCALE_LOG2 0.25503480f   // (1/sqrt(32)) * log2(e)

static __device__ __forceinline__ float bf2f(u16 u) {
    union { unsigned int i; float f; } v; v.i = ((unsigned int)u) << 16; return v.f;
}
static __device__ __forceinline__ u16 f2bf(float f) {
    unsigned int x = __float_as_uint(f);
    unsigned int r = x + 0x7fffu + ((x >> 16) & 1u);   // RNE
    return (u16)(r >> 16);
}
static __device__ __forceinline__ unsigned int cvtpk(float a, float b) {
    unsigned int u;
    asm("v_cvt_pk_bf16_f32 %0, %1, %2" : "=v"(u) : "v"(a), "v"(b));
    return u;   // lo = bf16(a), hi = bf16(b)
}
static __device__ __forceinline__ void gld16(const u16* g, u16* l) {
    __builtin_amdgcn_global_load_lds(
        (const __attribute__((address_space(1))) unsigned int*)g,
        (__attribute__((address_space(3))) unsigned int*)l, 16, 0, 0);
}

// ---------------------------------------------------------------------------
// fp32 -> bf16 weight/query conversion (one fused kernel).
// ---------------------------------------------------------------------------
__launch_bounds__(256)
__global__ void cvt_weights(const float* __restrict__ qkvw, const float* __restrict__ outw,
                            const float* __restrict__ f1w,  const float* __restrict__ f2w,
                            const float* __restrict__ cpq,  const float* __restrict__ cfc,
                            const float* __restrict__ cf1,  const float* __restrict__ cf2,
                            const float* __restrict__ qry,  u16* __restrict__ dst) {
    const int q = blockIdx.x * 256 + threadIdx.x;
    const int gid = q * 4;
    const float* s; int off;
    if      (gid <  393216) { s = qkvw; off = 0;       }
    else if (gid <  524288) { s = outw; off = 393216;  }
    else if (gid < 1048576) { s = f1w;  off = 524288;  }
    else if (gid < 1572864) { s = f2w;  off = 1048576; }
    else if (gid < 1638400) { s = cpq;  off = 1572864; }
    else if (gid < 1703936) { s = cfc;  off = 1638400; }
    else if (gid < 1835008) { s = cf1;  off = 1703936; }
    else if (gid < 1966080) { s = cf2;  off = 1835008; }
    else                    { s = qry;  off = 1966080; }
    float4 v = *(const float4*)(s + (gid - off));
    u16x4 o; o[0] = f2bf(v.x); o[1] = f2bf(v.y); o[2] = f2bf(v.z); o[3] = f2bf(v.w);
    *(u16x4*)(dst + gid) = o;
}

// ---------------------------------------------------------------------------
// Relative-position bias in MFMA C-fragment layout, PERMUTED key map,
// pre-scaled by log2(e).
// ---------------------------------------------------------------------------
__launch_bounds__(256)
__global__ void bias_frag_kernel(const float* __restrict__ rel, float* __restrict__ bfrag) {
    const int idx = blockIdx.x * 256 + threadIdx.x;      // 0..16383
    #pragma unroll
    for (int j = 0; j < 4; ++j) {
        const int i = idx * 4 + j;
        const int layer = i >> 15, h = (i >> 12) & 7, kt = (i >> 10) & 3,
                  qt = (i >> 8) & 3, lane = (i >> 2) & 63, jj = i & 3;
        const int key   = (kt >> 1) * 32 + 4 * (kt & 1) + 8 * (lane >> 4) + jj;
        const int query = qt * 16 + (lane & 15);
        const int dy = (query >> 3) - (key >> 3) + 7;
        const int dx = (query & 7)  - (key & 7)  + 7;
        bfrag[i] = rel[layer * 1800 + (dy * 15 + dx) * 8 + h] * LOG2E;
    }
}

// ---------------------------------------------------------------------------
// LayerNorm: one wave per row, C=256. fp32 in -> bf16 out.
// ---------------------------------------------------------------------------
__launch_bounds__(256)
__global__ void ln_kernel(const float* __restrict__ in, u16* __restrict__ out,
                          const float* __restrict__ g, const float* __restrict__ b,
                          int rows) {
    const int wave = threadIdx.x >> 6, lane = threadIdx.x & 63;
    const int row = blockIdx.x * 4 + wave;
    if (row >= rows) return;
    const int c = lane * 4;
    float4 v = *(const float4*)(in + (size_t)row * 256 + c);
    float s1 = v.x + v.y + v.z + v.w;
    float s2 = v.x*v.x + v.y*v.y + v.z*v.z + v.w*v.w;
    #pragma unroll
    for (int off = 32; off; off >>= 1) {
        s1 += __shfl_xor(s1, off);
        s2 += __shfl_xor(s2, off);
    }
    const float mean = s1 * (1.f/256.f);
    const float var  = s2 * (1.f/256.f) - mean*mean;
    const float rstd = rsqrtf(var + 1e-5f);
    float4 gg = *(const float4*)(g + c);
    float4 bb = *(const float4*)(b + c);
    u16x4 og;
    og[0] = f2bf((v.x-mean)*rstd*gg.x + bb.x);
    og[1] = f2bf((v.y-mean)*rstd*gg.y + bb.y);
    og[2] = f2bf((v.z-mean)*rstd*gg.z + bb.z);
    og[3] = f2bf((v.w-mean)*rstd*gg.w + bb.w);
    *(u16x4*)(out + (size_t)row * 256 + c) = og;
}

// ---------------------------------------------------------------------------
// 128x128 GEMM (m97 structure): linear LDS + global_load_lds(16B), BK=64,
// XCD-aware bijective block swizzle (all grids have nwg % 8 == 0).
// EPI: 2 +bias+gelu, 3 +bias+resid(f32), 7 qkv (+bias, scale q, v->vtbuf),
//      8 +bias+resid dual-write (f32 out + bf16 aux)
// ---------------------------------------------------------------------------
template<int EPI, bool F32O>
__launch_bounds__(256)
__global__ void gemm128(const u16* __restrict__ A, const u16* __restrict__ W,
                        const float* __restrict__ bias, const float* __restrict__ resid,
                        void* __restrict__ outv, u16* __restrict__ aux,
                        int M, int N, int K) {
    __shared__ u16 As[128 * 64];
    __shared__ u16 Bs[128 * 64];
    const int nx = gridDim.x;
    const int nwg = nx * gridDim.y;
    int bid = blockIdx.y * nx + blockIdx.x;
    bid = (bid & 7) * (nwg >> 3) + (bid >> 3);     // chunked XCD swizzle (T1)
    const int m0 = (bid / nx) * 128, n0 = (bid % nx) * 128;
    const int tid = threadIdx.x, lane = tid & 63, wave = tid >> 6;
    const int g = lane >> 4, c = lane & 15;
    const int wm = (wave >> 1) * 64, wn = (wave & 1) * 64;

    f32x4 acc[4][4];
    #pragma unroll
    for (int i = 0; i < 4; ++i)
        #pragma unroll
        for (int j = 0; j < 4; ++j) acc[i][j] = f32x4{0.f,0.f,0.f,0.f};

    const int srow = (lane >> 3), scol = (lane & 7) * 8;   // within 8-row chunk
    for (int k0 = 0; k0 < K; k0 += 64) {
        #pragma unroll
        for (int i = 0; i < 4; ++i) {
            const int ch = wave * 4 + i;             // chunk 0..15 (8 rows each)
            const int r = ch * 8 + srow;
            gld16(&A[(size_t)(m0 + r) * K + k0 + scol], &As[ch * 512]);
            gld16(&W[(size_t)(n0 + r) * K + k0 + scol], &Bs[ch * 512]);
        }
        __syncthreads();
        #pragma unroll
        for (int kk = 0; kk < 64; kk += 32) {
            s16x8 af[4], bf_[4];
            #pragma unroll
            for (int mi = 0; mi < 4; ++mi)
                af[mi] = *(const s16x8*)&As[(wm + mi*16 + c) * 64 + kk + g * 8];
            #pragma unroll
            for (int ni = 0; ni < 4; ++ni)
                bf_[ni] = *(const s16x8*)&Bs[(wn + ni*16 + c) * 64 + kk + g * 8];
            #pragma unroll
            for (int mi = 0; mi < 4; ++mi)
                #pragma unroll
                for (int ni = 0; ni < 4; ++ni)
                    acc[mi][ni] = __builtin_amdgcn_mfma_f32_16x16x32_bf16(
                        af[mi], bf_[ni], acc[mi][ni], 0, 0, 0);
        }
        __syncthreads();
    }

    #pragma unroll
    for (int mi = 0; mi < 4; ++mi) {
        #pragma unroll
        for (int ni = 0; ni < 4; ++ni) {
            const int col = n0 + wn + ni*16 + c;
            #pragma unroll
            for (int j = 0; j < 4; ++j) {
                const int row = m0 + wm + mi*16 + g*4 + j;
                float v = acc[mi][ni][j];
                v += bias[col];
                if (EPI == 2) v = 0.5f * v * (1.f + erff(v * 0.70710678118654752f));
                if (EPI == 3 || EPI == 8) v += resid[(size_t)row * N + col];
                if (EPI == 8) {
                    ((float*)outv)[(size_t)row * N + col] = v;
                    aux[(size_t)row * N + col] = f2bf(v);
                    continue;
                }
                if (EPI == 7) {
                    if (col < 256) v *= SCALE_LOG2;
                    if (col >= 512) {
                        const int bidx = row >> 14, y = (row >> 7) & 127, xx = row & 127;
                        const int wini = (bidx*16 + (y>>3))*16 + (xx>>3);
                        const int key  = ((y&7)<<3) | (xx&7);
                        aux[((size_t)wini*256 + (col-512))*64 + key] = f2bf(v);
                        continue;
                    }
                }
                if (F32O) ((float*)outv)[(size_t)row * N + col] = v;
                else      ((u16*)outv)[(size_t)row * N + col]   = f2bf(v);
            }
        }
    }
}

// ---------------------------------------------------------------------------
// 64x64 GEMM (M=1024 CA GEMMs). EPI: 1 bias, 4 bias+relu, 5 bias+clip32,
// 6 softmax-log2-scale (no bias).
// ---------------------------------------------------------------------------
template<int EPI>
__launch_bounds__(256)
__global__ void gemm_bt(const u16* __restrict__ A, const u16* __restrict__ W,
                        const float* __restrict__ bias, u16* __restrict__ out,
                        int M, int N, int K) {
    __shared__ u16 As[64][72];
    __shared__ u16 Bs[64][72];
    const int m0 = blockIdx.y * 64;
    const int n0 = blockIdx.x * 64;
    const int tid = threadIdx.x;
    const int lane = tid & 63, wave = tid >> 6;
    const int wm = (wave >> 1) * 32, wn = (wave & 1) * 32;

    f32x4 acc[2][2];
    #pragma unroll
    for (int i = 0; i < 2; ++i)
        #pragma unroll
        for (int j = 0; j < 2; ++j) acc[i][j] = f32x4{0.f,0.f,0.f,0.f};

    for (int k0 = 0; k0 < K; k0 += 64) {
        #pragma unroll
        for (int rep = 0; rep < 2; ++rep) {
            int i = tid + rep * 256;
            int r = i >> 3, c = (i & 7) * 8;
            *(s16x8*)&As[r][c] = *(const s16x8*)&A[(size_t)(m0 + r) * K + k0 + c];
            *(s16x8*)&Bs[r][c] = *(const s16x8*)&W[(size_t)(n0 + r) * K + k0 + c];
        }
        __syncthreads();
        #pragma unroll
        for (int kk = 0; kk < 64; kk += 32) {
            s16x8 af[2], bfr[2];
            #pragma unroll
            for (int i = 0; i < 2; ++i) {
                af[i]  = *(const s16x8*)&As[wm + i*16 + (lane & 15)][kk + (lane >> 4) * 8];
                bfr[i] = *(const s16x8*)&Bs[wn + i*16 + (lane & 15)][kk + (lane >> 4) * 8];
            }
            #pragma unroll
            for (int mi = 0; mi < 2; ++mi)
                #pragma unroll
                for (int ni = 0; ni < 2; ++ni)
                    acc[mi][ni] = __builtin_amdgcn_mfma_f32_16x16x32_bf16(
                        af[mi], bfr[ni], acc[mi][ni], 0, 0, 0);
        }
        __syncthreads();
    }

    #pragma unroll
    for (int mi = 0; mi < 2; ++mi) {
        #pragma unroll
        for (int ni = 0; ni < 2; ++ni) {
            const int col = n0 + wn + ni*16 + (lane & 15);
            #pragma unroll
            for (int j = 0; j < 4; ++j) {
                const int row = m0 + wm + mi*16 + (lane >> 4)*4 + j;
                float v = acc[mi][ni][j];
                if (EPI >= 1 && EPI <= 5) v += bias[col];
                if (EPI == 4) v = fmaxf(v, 0.f);
                if (EPI == 5) v = fminf(fmaxf(v, -32.f), 32.f);
                if (EPI == 6) v *= SCALE_LOG2;
                out[(size_t)row * N + col] = f2bf(v);
            }
        }
    }
}

// ---------------------------------------------------------------------------
// MFMA windowed self-attention, shuffle-free (permuted key map).
// ---------------------------------------------------------------------------
__launch_bounds__(256)
__global__ void win_attn(const u16* __restrict__ qkv, const u16* __restrict__ vtbuf,
                         const float* __restrict__ bfrag, u16* __restrict__ o,
                         int layer) {
    const int wid = blockIdx.x * 4 + (threadIdx.x >> 6);   // 0..4095
    const int lane = threadIdx.x & 63;
    const int h = wid & 7, win = wid >> 3;
    const int b = win >> 8, wy = (win >> 4) & 15, wx = win & 15;
    const int g = lane >> 4, c = lane & 15;
    const size_t rowbase = (size_t)b * 16384 + (size_t)wy * 8 * 128 + wx * 8;

    s16x8 qf[4], kf[4];
    #pragma unroll
    for (int qt = 0; qt < 4; ++qt) {
        const int t = qt * 16 + c;
        qf[qt] = *(const s16x8*)&qkv[(rowbase + (size_t)(t >> 3) * 128 + (t & 7)) * 768
                                     + h * 32 + g * 8];
    }
    const int kp0 = 8 * (c >> 2) + (c & 3);       // permuted key row for this lane
    #pragma unroll
    for (int kt = 0; kt < 4; ++kt) {
        const int t = (kt >> 1) * 32 + 4 * (kt & 1) + kp0;
        kf[kt] = *(const s16x8*)&qkv[(rowbase + (size_t)(t >> 3) * 128 + (t & 7)) * 768
                                     + 256 + h * 32 + g * 8];
    }

    const float* bb = bfrag + (size_t)((layer * 8 + h) * 16) * 256;
    f32x4 st[4][4];
    #pragma unroll
    for (int kt = 0; kt < 4; ++kt)
        #pragma unroll
        for (int qt = 0; qt < 4; ++qt)
            st[kt][qt] = *(const f32x4*)&bb[(kt * 4 + qt) * 256 + lane * 4];
    #pragma unroll
    for (int kt = 0; kt < 4; ++kt)
        #pragma unroll
        for (int qt = 0; qt < 4; ++qt)
            st[kt][qt] = __builtin_amdgcn_mfma_f32_16x16x32_bf16(
                kf[kt], qf[qt], st[kt][qt], 0, 0, 0);

    float linv[4];
    #pragma unroll
    for (int qt = 0; qt < 4; ++qt) {
        float mx = -1e30f;
        #pragma unroll
        for (int kt = 0; kt < 4; ++kt)
            #pragma unroll
            for (int j = 0; j < 4; ++j) mx = fmaxf(mx, st[kt][qt][j]);
        mx = fmaxf(mx, __shfl_xor(mx, 16));
        mx = fmaxf(mx, __shfl_xor(mx, 32));
        float sum = 0.f;
        #pragma unroll
        for (int kt = 0; kt < 4; ++kt)
            #pragma unroll
            for (int j = 0; j < 4; ++j) {
                const float p = exp2f(st[kt][qt][j] - mx);
                st[kt][qt][j] = p;
                sum += p;
            }
        sum += __shfl_xor(sum, 16);
        sum += __shfl_xor(sum, 32);
        linv[qt] = 1.f / sum;
    }

    const u16* vb = vtbuf + ((size_t)win * 256 + h * 32) * 64;
    s16x8 vf[2][2];
    #pragma unroll
    for (int dt = 0; dt < 2; ++dt)
        #pragma unroll
        for (int ks = 0; ks < 2; ++ks)
            vf[dt][ks] = *(const s16x8*)&vb[(size_t)(dt * 16 + c) * 64 + ks * 32 + g * 8];

    f32x4 acc[4][2];
    #pragma unroll
    for (int i = 0; i < 4; ++i)
        #pragma unroll
        for (int j = 0; j < 2; ++j) acc[i][j] = f32x4{0.f,0.f,0.f,0.f};

    #pragma unroll
    for (int qt = 0; qt < 4; ++qt) {
        #pragma unroll
        for (int ks = 0; ks < 2; ++ks) {
            u32x4 w;
            w[0] = cvtpk(st[2*ks][qt][0],   st[2*ks][qt][1]);
            w[1] = cvtpk(st[2*ks][qt][2],   st[2*ks][qt][3]);
            w[2] = cvtpk(st[2*ks+1][qt][0], st[2*ks+1][qt][1]);
            w[3] = cvtpk(st[2*ks+1][qt][2], st[2*ks+1][qt][3]);
            const s16x8 pfrag = __builtin_bit_cast(s16x8, w);
            acc[qt][0] = __builtin_amdgcn_mfma_f32_16x16x32_bf16(pfrag, vf[0][ks], acc[qt][0], 0,0,0);
            acc[qt][1] = __builtin_amdgcn_mfma_f32_16x16x32_bf16(pfrag, vf[1][ks], acc[qt][1], 0,0,0);
        }
    }

    #pragma unroll
    for (int qt = 0; qt < 4; ++qt)
        #pragma unroll
        for (int dt = 0; dt < 2; ++dt)
            #pragma unroll
            for (int j = 0; j < 4; ++j) {
                const int t = qt * 16 + g * 4 + j;
                o[(rowbase + (size_t)(t >> 3) * 128 + (t & 7)) * 256
                  + h * 32 + dt * 16 + c] = f2bf(acc[qt][dt][j] * linv[qt]);
            }
}

// ---------------------------------------------------------------------------
// Transpose: xbT[b][c][n] = xb[b][n][c].
// ---------------------------------------------------------------------------
__launch_bounds__(256)
__global__ void tr_kernel(const u16* __restrict__ src, u16* __restrict__ dst) {
    __shared__ u16 T[64][72];
    const int b = blockIdx.z;
    const int n0 = blockIdx.x * 64, c0 = blockIdx.y * 64;
    const int r = threadIdx.x >> 3, cc = (threadIdx.x & 7) * 8;
    const u16* S = src + (size_t)b * 16384 * 256;
    u16* D = dst + (size_t)b * 256 * 16384;
    #pragma unroll
    for (int rr = 0; rr < 64; rr += 32)
        *(u16x8*)&T[r + rr][cc] = *(const u16x8*)&S[(size_t)(n0 + r + rr) * 256 + c0 + cc];
    __syncthreads();
    #pragma unroll
    for (int rr = 0; rr < 64; rr += 32) {
        u16x8 v;
        #pragma unroll
        for (int k2 = 0; k2 < 8; ++k2) v[k2] = T[cc + k2][r + rr];
        *(u16x8*)&D[(size_t)(c0 + r + rr) * 16384 + n0 + cc] = v;
    }
}

// ---------------------------------------------------------------------------
// MFMA flash cross-attention: 64 queries/wave (4 subtiles share K/V loads),
// shuffle-free, defer-max, lane-local denom, log2 domain. KSPLIT=32.
// ---------------------------------------------------------------------------
static __device__ __forceinline__ void ca_step(
    const f32x4& sA, const f32x4& sB, const s16x8& vf0, const s16x8& vf1,
    f32x4& acc0, f32x4& acc1, float& m, float& llane)
{
    float smax = fmaxf(fmaxf(fmaxf(sA[0],sA[1]), fmaxf(sA[2],sA[3])),
                       fmaxf(fmaxf(sB[0],sB[1]), fmaxf(sB[2],sB[3])));
    if (!__all(smax <= m + 11.5f)) {          // defer-max (T13), log2 domain
        smax = fmaxf(smax, __shfl_xor(smax, 16));
        smax = fmaxf(smax, __shfl_xor(smax, 32));
        const float mnew = fmaxf(m, smax);
        const float cc = exp2f(m - mnew);
        #pragma unroll
        for (int j = 0; j < 4; ++j) { acc0[j] *= cc; acc1[j] *= cc; }
        llane *= cc;
        m = mnew;
    }
    float p[8];
    #pragma unroll
    for (int j = 0; j < 4; ++j) { p[j] = exp2f(sA[j] - m); p[4+j] = exp2f(sB[j] - m); }
    llane += ((p[0]+p[1]) + (p[2]+p[3])) + ((p[4]+p[5]) + (p[6]+p[7]));
    u32x4 w;
    w[0] = cvtpk(p[0], p[1]);
    w[1] = cvtpk(p[2], p[3]);
    w[2] = cvtpk(p[4], p[5]);
    w[3] = cvtpk(p[6], p[7]);
    const s16x8 pf = __builtin_bit_cast(s16x8, w);
    acc0 = __builtin_amdgcn_mfma_f32_16x16x32_bf16(vf0, pf, acc0, 0, 0, 0);
    acc1 = __builtin_amdgcn_mfma_f32_16x16x32_bf16(vf1, pf, acc1, 0, 0, 0);
}

__launch_bounds__(256)
__global__ void ca_flash(const u16* __restrict__ qb, const u16* __restrict__ xb,
                         const u16* __restrict__ xbT, float* __restrict__ pbuf) {
    const int wid = blockIdx.x * 4 + (threadIdx.x >> 6);   // 0..4095
    const int lane = threadIdx.x & 63;
    const int ks = wid & 31, qt = (wid >> 5) & 7, h = (wid >> 8) & 7, b = wid >> 11;
    const int g = lane >> 4, c = lane & 15;
    const int kp0 = 8 * (c >> 2) + (c & 3);    // permuted key row for this lane

    s16x8 qf[4];
    #pragma unroll
    for (int nt = 0; nt < 4; ++nt) {
        const int q = qt * 64 + nt * 16 + c;
        qf[nt] = *(const s16x8*)&qb[((size_t)q * 2 + b) * 256 + h * 32 + g * 8];
    }
    const u16* Kb = xb  + (size_t)b * 16384 * 256 + h * 32;
    const u16* Vb = xbT + (size_t)b * 256 * 16384 + (size_t)(h * 32) * 16384;

    float m[4] = {-1e30f,-1e30f,-1e30f,-1e30f}, llane[4] = {0.f,0.f,0.f,0.f};
    f32x4 acc[2][4];   // [d-tile][q-subtile]
    #pragma unroll
    for (int i = 0; i < 2; ++i)
        #pragma unroll
        for (int j = 0; j < 4; ++j) acc[i][j] = f32x4{0.f,0.f,0.f,0.f};

    const int base = ks * 512;
    const f32x4 zero = f32x4{0.f, 0.f, 0.f, 0.f};
    for (int step = 0; step < 16; ++step) {
        const int n0 = base + step * 32;
        const s16x8 kf0 = *(const s16x8*)&Kb[(size_t)(n0 + kp0) * 256 + g * 8];
        const s16x8 kf1 = *(const s16x8*)&Kb[(size_t)(n0 + kp0 + 4) * 256 + g * 8];
        const s16x8 vf0 = *(const s16x8*)&Vb[(size_t)c * 16384 + n0 + g * 8];
        const s16x8 vf1 = *(const s16x8*)&Vb[(size_t)(16 + c) * 16384 + n0 + g * 8];
        #pragma unroll
        for (int nt = 0; nt < 4; ++nt) {
            const f32x4 sa = __builtin_amdgcn_mfma_f32_16x16x32_bf16(kf0, qf[nt], zero, 0, 0, 0);
            const f32x4 sb = __builtin_amdgcn_mfma_f32_16x16x32_bf16(kf1, qf[nt], zero, 0, 0, 0);
            ca_step(sa, sb, vf0, vf1, acc[0][nt], acc[1][nt], m[nt], llane[nt]);
        }
    }

    #pragma unroll
    for (int nt = 0; nt < 4; ++nt) {
        llane[nt] += __shfl_xor(llane[nt], 16);
        llane[nt] += __shfl_xor(llane[nt], 32);
    }

    float* P = pbuf + (size_t)wid * 2176;
    if (g == 0) {
        #pragma unroll
        for (int nt = 0; nt < 4; ++nt) {
            P[nt * 16 + c]      = m[nt];
            P[64 + nt * 16 + c] = llane[nt];
        }
    }
    #pragma unroll
    for (int mi = 0; mi < 2; ++mi)
        #pragma unroll
        for (int nt = 0; nt < 4; ++nt)
            *(f32x4*)&P[128 + (c + 16*nt) * 32 + 16*mi + g*4] = acc[mi][nt];
}

// ---------------------------------------------------------------------------
// Merge 32 key-split partials -> ctx (b, Tq, C) bf16. (log2-domain stats)
// ---------------------------------------------------------------------------
__launch_bounds__(256)
__global__ void ca_merge(const float* __restrict__ pbuf, u16* __restrict__ ctx) {
    const int wave = threadIdx.x >> 6, lane = threadIdx.x & 63;
    const int sub = lane >> 5, d = lane & 31;
    const int rowid = blockIdx.x * 8 + wave * 2 + sub;     // 0..8191
    const int q = rowid & 63, qt = (rowid >> 6) & 7, h = (rowid >> 9) & 7, b = rowid >> 12;
    const size_t w0 = (size_t)((b * 8 + h) * 8 + qt) * 32;
    float mv[32], lv[32];
    float M = -1e30f;
    #pragma unroll
    for (int i = 0; i < 32; ++i) {
        mv[i] = pbuf[(w0 + i) * 2176 + q];
        lv[i] = pbuf[(w0 + i) * 2176 + 64 + q];
        M = fmaxf(M, mv[i]);
    }
    float L = 0.f, o = 0.f;
    #pragma unroll
    for (int i = 0; i < 32; ++i) {
        const float e = exp2f(mv[i] - M);
        L += lv[i] * e;
        o += e * pbuf[(w0 + i) * 2176 + 128 + q * 32 + d];
    }
    const int t = qt * 64 + q;
    ctx[((size_t)b * 512 + t) * 256 + h * 32 + d] = f2bf(o / L);
}

// ---------------------------------------------------------------------------
// Final: out = LN(query + ctx^T).
// ---------------------------------------------------------------------------
__launch_bounds__(256)
__global__ void final_ln(const float* __restrict__ query, const u16* __restrict__ ctx4,
                         const float* __restrict__ g, const float* __restrict__ b,
                         float* __restrict__ out) {
    const int wave = threadIdx.x >> 6, lane = threadIdx.x & 63;
    const int row = blockIdx.x * 4 + wave;        // 0..1023 = t*2+bb
    const int t = row >> 1, bb = row & 1;
    const int c = lane * 4;
    float4 rq = *(const float4*)(query + (size_t)row * 256 + c);
    u16x4 rc = *(const u16x4*)(ctx4 + ((size_t)bb * 512 + t) * 256 + c);
    float x0 = rq.x + bf2f(rc[0]);
    float x1 = rq.y + bf2f(rc[1]);
    float x2 = rq.z + bf2f(rc[2]);
    float x3 = rq.w + bf2f(rc[3]);
    float s1 = x0 + x1 + x2 + x3;
    float s2 = x0*x0 + x1*x1 + x2*x2 + x3*x3;
    #pragma unroll
    for (int off = 32; off; off >>= 1) {
        s1 += __shfl_xor(s1, off);
        s2 += __shfl_xor(s2, off);
    }
    const float mean = s1 * (1.f/256.f);
    const float var  = s2 * (1.f/256.f) - mean*mean;
    const float rstd = rsqrtf(var + 1e-5f);
    float4 gg = *(const float4*)(g + c);
    float4 bv = *(const float4*)(b + c);
    float4 og;
    og.x = (x0-mean)*rstd*gg.x + bv.x;
    og.y = (x1-mean)*rstd*gg.y + bv.y;
    og.z = (x2-mean)*rstd*gg.z + bv.z;
    og.w = (x3-mean)*rstd*gg.w + bv.w;
    *(float4*)(out + (size_t)row * 256 + c) = og;
}

// ---------------------------------------------------------------------------

extern "C" void kernel_launch(void* const* d_in, const int* in_sizes, int n_in,
                              void* d_out, int out_size, void* d_ws, size_t ws_size,
                              hipStream_t stream) {
    const float* x_in  = (const float*)d_in[0];
    const float* query = (const float*)d_in[1];
    const float* n1_g  = (const float*)d_in[2];
    const float* n1_b  = (const float*)d_in[3];
    const float* qkv_w = (const float*)d_in[4];
    const float* qkv_b = (const float*)d_in[5];
    const float* out_w = (const float*)d_in[6];
    const float* out_b = (const float*)d_in[7];
    const float* rel   = (const float*)d_in[8];
    const float* n2_g  = (const float*)d_in[9];
    const float* n2_b  = (const float*)d_in[10];
    const float* fc1_w = (const float*)d_in[11];
    const float* fc1_b = (const float*)d_in[12];
    const float* fc2_w = (const float*)d_in[13];
    const float* fc2_b = (const float*)d_in[14];
    const float* can_g = (const float*)d_in[15];
    const float* can_b = (const float*)d_in[16];
    const float* cpq_w = (const float*)d_in[17];
    const float* cfc_w = (const float*)d_in[18];
    const float* cfc_b = (const float*)d_in[19];
    const float* cf1_w = (const float*)d_in[20];
    const float* cf1_b = (const float*)d_in[21];
    const float* cf2_w = (const float*)d_in[22];
    const float* cf2_b = (const float*)d_in[23];

    const int M = 32768;   // 2 * 128 * 128 tokens

    char* w = (char*)d_ws;
    float* xs  = (float*)w;  w += (size_t)M * 256 * 4;        // fp32 residual stream
    u16* hbuf  = (u16*)w;    w += (size_t)M * 256 * 2;        // bf16 LN/attn out
    u16* big   = (u16*)w;    w += (size_t)M * 1024 * 2;       // bf16 qkv / mlp hidden
    u16* arena = (u16*)w;    w += (size_t)2228224 * 2;        // bf16 weights + query
    u16* qbuf  = (u16*)w;    w += 524288;
    u16* ctx1  = (u16*)w;    w += 524288;
    u16* ctx2  = (u16*)w;    w += 524288;
    u16* ctx3  = (u16*)w;    w += 1048576;
    u16* ctx4  = (u16*)w;    w += 524288;
    u16* xb    = (u16*)w;    w += (size_t)M * 256 * 2;        // bf16 copy of final xs
    float* bfragb = (float*)w; w += 65536 * 4;                // bias C-fragments

    // vtbuf aliases the tail of `big` (qkv uses only M*768 of it; dead by fc1)
    u16* vtbuf = big + (size_t)M * 768;                       // 16 MB
    // CA-phase scratch aliases into `big` (free after the block loop):
    u16*   xbT  = big;                                        // (2,256,16384) 16 MB
    float* pbuf = (float*)(big + 8388608);                    // 4096 * 2176 f32 = 35.7 MB

    u16* wq   = arena;
    u16* wo   = arena + 393216;
    u16* wf1  = arena + 524288;
    u16* wf2  = arena + 1048576;
    u16* wcpq = arena + 1572864;
    u16* wcfc = arena + 1638400;
    u16* wcf1 = arena + 1703936;
    u16* wcf2 = arena + 1835008;
    u16* qcvt = arena + 1966080;

    cvt_weights<<<2176, 256, 0, stream>>>(qkv_w, out_w, fc1_w, fc2_w, cpq_w,
                                          cfc_w, cf1_w, cf2_w, query, arena);
    bias_frag_kernel<<<64, 256, 0, stream>>>(rel, bfragb);

    for (int i = 0; i < 2; ++i) {
        const float* src = (i == 0) ? x_in : xs;   // layer-0 reads input directly
        ln_kernel<<<M/4, 256, 0, stream>>>(src, hbuf, n1_g + i*256, n1_b + i*256, M);
        gemm128<7,false><<<dim3(6,256), 256, 0, stream>>>(
            hbuf, wq + (size_t)i*768*256, qkv_b + i*768, nullptr, big, vtbuf, M, 768, 256);
        win_attn<<<1024, 256, 0, stream>>>(big, vtbuf, bfragb, hbuf, i);
        gemm128<3,true><<<dim3(2,256), 256, 0, stream>>>(
            hbuf, wo + (size_t)i*65536, out_b + i*256, src, xs, nullptr, M, 256, 256);
        ln_kernel<<<M/4, 256, 0, stream>>>(xs, hbuf, n2_g + i*256, n2_b + i*256, M);
        gemm128<2,false><<<dim3(8,256), 256, 0, stream>>>(
            hbuf, wf1 + (size_t)i*262144, fc1_b + i*1024, nullptr, big, nullptr, M, 1024, 256);
        if (i == 0)
            gemm128<3,true><<<dim3(2,256), 256, 0, stream>>>(
                big, wf2, fc2_b, xs, xs, nullptr, M, 256, 1024);
        else
            gemm128<8,true><<<dim3(2,256), 256, 0, stream>>>(
                big, wf2 + 262144, fc2_b + 256, xs, xs, xb, M, 256, 1024);
    }

    // ---- cross-attention ----
    tr_kernel<<<dim3(256, 4, 2), 256, 0, stream>>>(xb, xbT);
    gemm_bt<6><<<dim3(4, 16), 256, 0, stream>>>(qcvt, wcpq, nullptr, qbuf, 1024, 256, 256);
    ca_flash<<<1024, 256, 0, stream>>>(qbuf, xb, xbT, pbuf);
    ca_merge<<<1024, 256, 0, stream>>>(pbuf, ctx1);
    gemm_bt<5><<<dim3(4, 16), 256, 0, stream>>>(ctx1, wcfc, cfc_b, ctx2, 1024, 256, 256);
    gemm_bt<4><<<dim3(8, 16), 256, 0, stream>>>(ctx2, wcf1, cf1_b, ctx3, 1024, 512, 256);
    gemm_bt<1><<<dim3(4, 16), 256, 0, stream>>>(ctx3, wcf2, cf2_b, ctx4, 1024, 256, 512);
    final_ln<<<256, 256, 0, stream>>>(query, ctx4, can_g, can_b, (float*)d_out);

    (void)in_sizes; (void)n_in; (void)out_size; (void)ws_size;
}

// Round 9
// 473.116 us; speedup vs baseline: 3.6386x; 1.0329x over previous
//
#include <hip/hip_runtime.h>
#include <hip/hip_bf16.h>

// ---------------------------------------------------------------------------
// Swin block ×2 + CrossAttnFFN. FP32 in/out, bf16 MFMA everywhere, fp32 accum.
// Round 9: statically-shifted softmax (no max tracking — exact shift-invariance,
//          fp32 range verified); denominator accumulated via ones-MFMA on the
//          idle matrix pipe; merge is plain sum-of-partials.
// ---------------------------------------------------------------------------

typedef unsigned short u16;
typedef u16  u16x4 __attribute__((ext_vector_type(4)));
typedef u16  u16x8 __attribute__((ext_vector_type(8)));
typedef short s16x8 __attribute__((ext_vector_type(8)));
typedef float f32x4 __attribute__((ext_vector_type(4)));
typedef unsigned int u32x4 __attribute__((ext_vector_type(4)));

#define LOG2E 1.4426950408889634f
#define SCALE_LOG2 0.25503480f   // (1/sqrt(32)) * log2(e)

static __device__ __forceinline__ float bf2f(u16 u) {
    union { unsigned int i; float f; } v; v.i = ((unsigned int)u) << 16; return v.f;
}
static __device__ __forceinline__ u16 f2bf(float f) {
    unsigned int x = __float_as_uint(f);
    unsigned int r = x + 0x7fffu + ((x >> 16) & 1u);   // RNE
    return (u16)(r >> 16);
}
static __device__ __forceinline__ unsigned int cvtpk(float a, float b) {
    unsigned int u;
    asm("v_cvt_pk_bf16_f32 %0, %1, %2" : "=v"(u) : "v"(a), "v"(b));
    return u;   // lo = bf16(a), hi = bf16(b)
}
static __device__ __forceinline__ void gld16(const u16* g, u16* l) {
    __builtin_amdgcn_global_load_lds(
        (const __attribute__((address_space(1))) unsigned int*)g,
        (__attribute__((address_space(3))) unsigned int*)l, 16, 0, 0);
}
#define EXP2F __builtin_amdgcn_exp2f

// ---------------------------------------------------------------------------
// fp32 -> bf16 weight/query conversion (one fused kernel).
// ---------------------------------------------------------------------------
__launch_bounds__(256)
__global__ void cvt_weights(const float* __restrict__ qkvw, const float* __restrict__ outw,
                            const float* __restrict__ f1w,  const float* __restrict__ f2w,
                            const float* __restrict__ cpq,  const float* __restrict__ cfc,
                            const float* __restrict__ cf1,  const float* __restrict__ cf2,
                            const float* __restrict__ qry,  u16* __restrict__ dst) {
    const int q = blockIdx.x * 256 + threadIdx.x;
    const int gid = q * 4;
    const float* s; int off;
    if      (gid <  393216) { s = qkvw; off = 0;       }
    else if (gid <  524288) { s = outw; off = 393216;  }
    else if (gid < 1048576) { s = f1w;  off = 524288;  }
    else if (gid < 1572864) { s = f2w;  off = 1048576; }
    else if (gid < 1638400) { s = cpq;  off = 1572864; }
    else if (gid < 1703936) { s = cfc;  off = 1638400; }
    else if (gid < 1835008) { s = cf1;  off = 1703936; }
    else if (gid < 1966080) { s = cf2;  off = 1835008; }
    else                    { s = qry;  off = 1966080; }
    float4 v = *(const float4*)(s + (gid - off));
    u16x4 o; o[0] = f2bf(v.x); o[1] = f2bf(v.y); o[2] = f2bf(v.z); o[3] = f2bf(v.w);
    *(u16x4*)(dst + gid) = o;
}

// ---------------------------------------------------------------------------
// Relative-position bias in MFMA C-fragment layout, PERMUTED key map,
// pre-scaled by log2(e).
// ---------------------------------------------------------------------------
__launch_bounds__(256)
__global__ void bias_frag_kernel(const float* __restrict__ rel, float* __restrict__ bfrag) {
    const int idx = blockIdx.x * 256 + threadIdx.x;      // 0..16383
    #pragma unroll
    for (int j = 0; j < 4; ++j) {
        const int i = idx * 4 + j;
        const int layer = i >> 15, h = (i >> 12) & 7, kt = (i >> 10) & 3,
                  qt = (i >> 8) & 3, lane = (i >> 2) & 63, jj = i & 3;
        const int key   = (kt >> 1) * 32 + 4 * (kt & 1) + 8 * (lane >> 4) + jj;
        const int query = qt * 16 + (lane & 15);
        const int dy = (query >> 3) - (key >> 3) + 7;
        const int dx = (query & 7)  - (key & 7)  + 7;
        bfrag[i] = rel[layer * 1800 + (dy * 15 + dx) * 8 + h] * LOG2E;
    }
}

// ---------------------------------------------------------------------------
// LayerNorm: one wave per row, C=256. fp32 in -> bf16 out.
// ---------------------------------------------------------------------------
__launch_bounds__(256)
__global__ void ln_kernel(const float* __restrict__ in, u16* __restrict__ out,
                          const float* __restrict__ g, const float* __restrict__ b,
                          int rows) {
    const int wave = threadIdx.x >> 6, lane = threadIdx.x & 63;
    const int row = blockIdx.x * 4 + wave;
    if (row >= rows) return;
    const int c = lane * 4;
    float4 v = *(const float4*)(in + (size_t)row * 256 + c);
    float s1 = v.x + v.y + v.z + v.w;
    float s2 = v.x*v.x + v.y*v.y + v.z*v.z + v.w*v.w;
    #pragma unroll
    for (int off = 32; off; off >>= 1) {
        s1 += __shfl_xor(s1, off);
        s2 += __shfl_xor(s2, off);
    }
    const float mean = s1 * (1.f/256.f);
    const float var  = s2 * (1.f/256.f) - mean*mean;
    const float rstd = rsqrtf(var + 1e-5f);
    float4 gg = *(const float4*)(g + c);
    float4 bb = *(const float4*)(b + c);
    u16x4 og;
    og[0] = f2bf((v.x-mean)*rstd*gg.x + bb.x);
    og[1] = f2bf((v.y-mean)*rstd*gg.y + bb.y);
    og[2] = f2bf((v.z-mean)*rstd*gg.z + bb.z);
    og[3] = f2bf((v.w-mean)*rstd*gg.w + bb.w);
    *(u16x4*)(out + (size_t)row * 256 + c) = og;
}

// ---------------------------------------------------------------------------
// 128x128 GEMM (m97 structure): linear LDS + global_load_lds(16B), BK=64,
// XCD-aware block swizzle.
// EPI: 2 +bias+gelu, 3 +bias+resid(f32), 7 qkv (+bias, scale q, v->vtbuf),
//      8 +bias+resid dual-write (f32 out + bf16 aux)
// ---------------------------------------------------------------------------
template<int EPI, bool F32O>
__launch_bounds__(256)
__global__ void gemm128(const u16* __restrict__ A, const u16* __restrict__ W,
                        const float* __restrict__ bias, const float* __restrict__ resid,
                        void* __restrict__ outv, u16* __restrict__ aux,
                        int M, int N, int K) {
    __shared__ u16 As[128 * 64];
    __shared__ u16 Bs[128 * 64];
    const int nx = gridDim.x;
    const int nwg = nx * gridDim.y;
    int bid = blockIdx.y * nx + blockIdx.x;
    bid = (bid & 7) * (nwg >> 3) + (bid >> 3);     // chunked XCD swizzle (T1)
    const int m0 = (bid / nx) * 128, n0 = (bid % nx) * 128;
    const int tid = threadIdx.x, lane = tid & 63, wave = tid >> 6;
    const int g = lane >> 4, c = lane & 15;
    const int wm = (wave >> 1) * 64, wn = (wave & 1) * 64;

    f32x4 acc[4][4];
    #pragma unroll
    for (int i = 0; i < 4; ++i)
        #pragma unroll
        for (int j = 0; j < 4; ++j) acc[i][j] = f32x4{0.f,0.f,0.f,0.f};

    const int srow = (lane >> 3), scol = (lane & 7) * 8;   // within 8-row chunk
    for (int k0 = 0; k0 < K; k0 += 64) {
        #pragma unroll
        for (int i = 0; i < 4; ++i) {
            const int ch = wave * 4 + i;             // chunk 0..15 (8 rows each)
            const int r = ch * 8 + srow;
            gld16(&A[(size_t)(m0 + r) * K + k0 + scol], &As[ch * 512]);
            gld16(&W[(size_t)(n0 + r) * K + k0 + scol], &Bs[ch * 512]);
        }
        __syncthreads();
        #pragma unroll
        for (int kk = 0; kk < 64; kk += 32) {
            s16x8 af[4], bf_[4];
            #pragma unroll
            for (int mi = 0; mi < 4; ++mi)
                af[mi] = *(const s16x8*)&As[(wm + mi*16 + c) * 64 + kk + g * 8];
            #pragma unroll
            for (int ni = 0; ni < 4; ++ni)
                bf_[ni] = *(const s16x8*)&Bs[(wn + ni*16 + c) * 64 + kk + g * 8];
            #pragma unroll
            for (int mi = 0; mi < 4; ++mi)
                #pragma unroll
                for (int ni = 0; ni < 4; ++ni)
                    acc[mi][ni] = __builtin_amdgcn_mfma_f32_16x16x32_bf16(
                        af[mi], bf_[ni], acc[mi][ni], 0, 0, 0);
        }
        __syncthreads();
    }

    #pragma unroll
    for (int mi = 0; mi < 4; ++mi) {
        #pragma unroll
        for (int ni = 0; ni < 4; ++ni) {
            const int col = n0 + wn + ni*16 + c;
            #pragma unroll
            for (int j = 0; j < 4; ++j) {
                const int row = m0 + wm + mi*16 + g*4 + j;
                float v = acc[mi][ni][j];
                v += bias[col];
                if (EPI == 2) v = 0.5f * v * (1.f + erff(v * 0.70710678118654752f));
                if (EPI == 3 || EPI == 8) v += resid[(size_t)row * N + col];
                if (EPI == 8) {
                    ((float*)outv)[(size_t)row * N + col] = v;
                    aux[(size_t)row * N + col] = f2bf(v);
                    continue;
                }
                if (EPI == 7) {
                    if (col < 256) v *= SCALE_LOG2;
                    if (col >= 512) {
                        const int bidx = row >> 14, y = (row >> 7) & 127, xx = row & 127;
                        const int wini = (bidx*16 + (y>>3))*16 + (xx>>3);
                        const int key  = ((y&7)<<3) | (xx&7);
                        aux[((size_t)wini*256 + (col-512))*64 + key] = f2bf(v);
                        continue;
                    }
                }
                if (F32O) ((float*)outv)[(size_t)row * N + col] = v;
                else      ((u16*)outv)[(size_t)row * N + col]   = f2bf(v);
            }
        }
    }
}

// ---------------------------------------------------------------------------
// 64x64 GEMM (M=1024 CA GEMMs). EPI: 1 bias, 4 bias+relu, 5 bias+clip32,
// 6 softmax-log2-scale (no bias).
// ---------------------------------------------------------------------------
template<int EPI>
__launch_bounds__(256)
__global__ void gemm_bt(const u16* __restrict__ A, const u16* __restrict__ W,
                        const float* __restrict__ bias, u16* __restrict__ out,
                        int M, int N, int K) {
    __shared__ u16 As[64][72];
    __shared__ u16 Bs[64][72];
    const int m0 = blockIdx.y * 64;
    const int n0 = blockIdx.x * 64;
    const int tid = threadIdx.x;
    const int lane = tid & 63, wave = tid >> 6;
    const int wm = (wave >> 1) * 32, wn = (wave & 1) * 32;

    f32x4 acc[2][2];
    #pragma unroll
    for (int i = 0; i < 2; ++i)
        #pragma unroll
        for (int j = 0; j < 2; ++j) acc[i][j] = f32x4{0.f,0.f,0.f,0.f};

    for (int k0 = 0; k0 < K; k0 += 64) {
        #pragma unroll
        for (int rep = 0; rep < 2; ++rep) {
            int i = tid + rep * 256;
            int r = i >> 3, c = (i & 7) * 8;
            *(s16x8*)&As[r][c] = *(const s16x8*)&A[(size_t)(m0 + r) * K + k0 + c];
            *(s16x8*)&Bs[r][c] = *(const s16x8*)&W[(size_t)(n0 + r) * K + k0 + c];
        }
        __syncthreads();
        #pragma unroll
        for (int kk = 0; kk < 64; kk += 32) {
            s16x8 af[2], bfr[2];
            #pragma unroll
            for (int i = 0; i < 2; ++i) {
                af[i]  = *(const s16x8*)&As[wm + i*16 + (lane & 15)][kk + (lane >> 4) * 8];
                bfr[i] = *(const s16x8*)&Bs[wn + i*16 + (lane & 15)][kk + (lane >> 4) * 8];
            }
            #pragma unroll
            for (int mi = 0; mi < 2; ++mi)
                #pragma unroll
                for (int ni = 0; ni < 2; ++ni)
                    acc[mi][ni] = __builtin_amdgcn_mfma_f32_16x16x32_bf16(
                        af[mi], bfr[ni], acc[mi][ni], 0, 0, 0);
        }
        __syncthreads();
    }

    #pragma unroll
    for (int mi = 0; mi < 2; ++mi) {
        #pragma unroll
        for (int ni = 0; ni < 2; ++ni) {
            const int col = n0 + wn + ni*16 + (lane & 15);
            #pragma unroll
            for (int j = 0; j < 4; ++j) {
                const int row = m0 + wm + mi*16 + (lane >> 4)*4 + j;
                float v = acc[mi][ni][j];
                if (EPI >= 1 && EPI <= 5) v += bias[col];
                if (EPI == 4) v = fmaxf(v, 0.f);
                if (EPI == 5) v = fminf(fmaxf(v, -32.f), 32.f);
                if (EPI == 6) v *= SCALE_LOG2;
                out[(size_t)row * N + col] = f2bf(v);
            }
        }
    }
}

// ---------------------------------------------------------------------------
// MFMA windowed self-attention, shuffle-free, max-free softmax (scores
// bounded; softmax shift-invariance is exact).
// ---------------------------------------------------------------------------
__launch_bounds__(256)
__global__ void win_attn(const u16* __restrict__ qkv, const u16* __restrict__ vtbuf,
                         const float* __restrict__ bfrag, u16* __restrict__ o,
                         int layer) {
    const int wid = blockIdx.x * 4 + (threadIdx.x >> 6);   // 0..4095
    const int lane = threadIdx.x & 63;
    const int h = wid & 7, win = wid >> 3;
    const int b = win >> 8, wy = (win >> 4) & 15, wx = win & 15;
    const int g = lane >> 4, c = lane & 15;
    const size_t rowbase = (size_t)b * 16384 + (size_t)wy * 8 * 128 + wx * 8;

    s16x8 qf[4], kf[4];
    #pragma unroll
    for (int qt = 0; qt < 4; ++qt) {
        const int t = qt * 16 + c;
        qf[qt] = *(const s16x8*)&qkv[(rowbase + (size_t)(t >> 3) * 128 + (t & 7)) * 768
                                     + h * 32 + g * 8];
    }
    const int kp0 = 8 * (c >> 2) + (c & 3);       // permuted key row for this lane
    #pragma unroll
    for (int kt = 0; kt < 4; ++kt) {
        const int t = (kt >> 1) * 32 + 4 * (kt & 1) + kp0;
        kf[kt] = *(const s16x8*)&qkv[(rowbase + (size_t)(t >> 3) * 128 + (t & 7)) * 768
                                     + 256 + h * 32 + g * 8];
    }

    const float* bb = bfrag + (size_t)((layer * 8 + h) * 16) * 256;
    f32x4 st[4][4];
    #pragma unroll
    for (int kt = 0; kt < 4; ++kt)
        #pragma unroll
        for (int qt = 0; qt < 4; ++qt)
            st[kt][qt] = *(const f32x4*)&bb[(kt * 4 + qt) * 256 + lane * 4];
    #pragma unroll
    for (int kt = 0; kt < 4; ++kt)
        #pragma unroll
        for (int qt = 0; qt < 4; ++qt)
            st[kt][qt] = __builtin_amdgcn_mfma_f32_16x16x32_bf16(
                kf[kt], qf[qt], st[kt][qt], 0, 0, 0);

    // max-free log2-domain softmax; 1/l deferred to output scale
    float linv[4];
    #pragma unroll
    for (int qt = 0; qt < 4; ++qt) {
        float sum = 0.f;
        #pragma unroll
        for (int kt = 0; kt < 4; ++kt)
            #pragma unroll
            for (int j = 0; j < 4; ++j) {
                const float p = EXP2F(st[kt][qt][j]);
                st[kt][qt][j] = p;
                sum += p;
            }
        sum += __shfl_xor(sum, 16);
        sum += __shfl_xor(sum, 32);
        linv[qt] = 1.f / sum;
    }

    const u16* vb = vtbuf + ((size_t)win * 256 + h * 32) * 64;
    s16x8 vf[2][2];
    #pragma unroll
    for (int dt = 0; dt < 2; ++dt)
        #pragma unroll
        for (int ks = 0; ks < 2; ++ks)
            vf[dt][ks] = *(const s16x8*)&vb[(size_t)(dt * 16 + c) * 64 + ks * 32 + g * 8];

    f32x4 acc[4][2];
    #pragma unroll
    for (int i = 0; i < 4; ++i)
        #pragma unroll
        for (int j = 0; j < 2; ++j) acc[i][j] = f32x4{0.f,0.f,0.f,0.f};

    #pragma unroll
    for (int qt = 0; qt < 4; ++qt) {
        #pragma unroll
        for (int ks = 0; ks < 2; ++ks) {
            u32x4 w;
            w[0] = cvtpk(st[2*ks][qt][0],   st[2*ks][qt][1]);
            w[1] = cvtpk(st[2*ks][qt][2],   st[2*ks][qt][3]);
            w[2] = cvtpk(st[2*ks+1][qt][0], st[2*ks+1][qt][1]);
            w[3] = cvtpk(st[2*ks+1][qt][2], st[2*ks+1][qt][3]);
            const s16x8 pfrag = __builtin_bit_cast(s16x8, w);
            acc[qt][0] = __builtin_amdgcn_mfma_f32_16x16x32_bf16(pfrag, vf[0][ks], acc[qt][0], 0,0,0);
            acc[qt][1] = __builtin_amdgcn_mfma_f32_16x16x32_bf16(pfrag, vf[1][ks], acc[qt][1], 0,0,0);
        }
    }

    #pragma unroll
    for (int qt = 0; qt < 4; ++qt)
        #pragma unroll
        for (int dt = 0; dt < 2; ++dt)
            #pragma unroll
            for (int j = 0; j < 4; ++j) {
                const int t = qt * 16 + g * 4 + j;
                o[(rowbase + (size_t)(t >> 3) * 128 + (t & 7)) * 256
                  + h * 32 + dt * 16 + c] = f2bf(acc[qt][dt][j] * linv[qt]);
            }
}

// ---------------------------------------------------------------------------
// Transpose: xbT[b][c][n] = xb[b][n][c].
// ---------------------------------------------------------------------------
__launch_bounds__(256)
__global__ void tr_kernel(const u16* __restrict__ src, u16* __restrict__ dst) {
    __shared__ u16 T[64][72];
    const int b = blockIdx.z;
    const int n0 = blockIdx.x * 64, c0 = blockIdx.y * 64;
    const int r = threadIdx.x >> 3, cc = (threadIdx.x & 7) * 8;
    const u16* S = src + (size_t)b * 16384 * 256;
    u16* D = dst + (size_t)b * 256 * 16384;
    #pragma unroll
    for (int rr = 0; rr < 64; rr += 32)
        *(u16x8*)&T[r + rr][cc] = *(const u16x8*)&S[(size_t)(n0 + r + rr) * 256 + c0 + cc];
    __syncthreads();
    #pragma unroll
    for (int rr = 0; rr < 64; rr += 32) {
        u16x8 v;
        #pragma unroll
        for (int k2 = 0; k2 < 8; ++k2) v[k2] = T[cc + k2][r + rr];
        *(u16x8*)&D[(size_t)(c0 + r + rr) * 16384 + n0 + cc] = v;
    }
}

// ---------------------------------------------------------------------------
// MFMA flash cross-attention: max-free softmax, denominator via ones-MFMA,
// 64 queries/wave, KSPLIT=32. Per step: 8 exp2 + 4 cvtpk per q-subtile,
// zero cross-lane ops, zero branches.
// ---------------------------------------------------------------------------
__launch_bounds__(256)
__global__ void ca_flash(const u16* __restrict__ qb, const u16* __restrict__ xb,
                         const u16* __restrict__ xbT, float* __restrict__ pbuf) {
    const int wid = blockIdx.x * 4 + (threadIdx.x >> 6);   // 0..4095
    const int lane = threadIdx.x & 63;
    const int ks = wid & 31, qt = (wid >> 5) & 7, h = (wid >> 8) & 7, b = wid >> 11;
    const int g = lane >> 4, c = lane & 15;
    const int kp0 = 8 * (c >> 2) + (c & 3);    // permuted key row for this lane

    s16x8 qf[4];
    #pragma unroll
    for (int nt = 0; nt < 4; ++nt) {
        const int q = qt * 64 + nt * 16 + c;
        qf[nt] = *(const s16x8*)&qb[((size_t)q * 2 + b) * 256 + h * 32 + g * 8];
    }
    const u16* Kb = xb  + (size_t)b * 16384 * 256 + h * 32;
    const u16* Vb = xbT + (size_t)b * 256 * 16384 + (size_t)(h * 32) * 16384;

    s16x8 ones;
    #pragma unroll
    for (int j = 0; j < 8; ++j) ones[j] = (short)0x3F80;   // bf16 1.0

    f32x4 acc[2][4];    // [d-tile][q-subtile]
    f32x4 accl[4];      // denominator rows (all identical) per q-subtile
    #pragma unroll
    for (int j = 0; j < 4; ++j) {
        acc[0][j] = f32x4{0.f,0.f,0.f,0.f};
        acc[1][j] = f32x4{0.f,0.f,0.f,0.f};
        accl[j]   = f32x4{0.f,0.f,0.f,0.f};
    }

    const int base = ks * 512;
    const f32x4 zero = f32x4{0.f, 0.f, 0.f, 0.f};
    for (int step = 0; step < 16; ++step) {
        const int n0 = base + step * 32;
        const s16x8 kf0 = *(const s16x8*)&Kb[(size_t)(n0 + kp0) * 256 + g * 8];
        const s16x8 kf1 = *(const s16x8*)&Kb[(size_t)(n0 + kp0 + 4) * 256 + g * 8];
        const s16x8 vf0 = *(const s16x8*)&Vb[(size_t)c * 16384 + n0 + g * 8];
        const s16x8 vf1 = *(const s16x8*)&Vb[(size_t)(16 + c) * 16384 + n0 + g * 8];
        #pragma unroll
        for (int nt = 0; nt < 4; ++nt) {
            const f32x4 sa = __builtin_amdgcn_mfma_f32_16x16x32_bf16(kf0, qf[nt], zero, 0, 0, 0);
            const f32x4 sb = __builtin_amdgcn_mfma_f32_16x16x32_bf16(kf1, qf[nt], zero, 0, 0, 0);
            u32x4 w;
            w[0] = cvtpk(EXP2F(sa[0]), EXP2F(sa[1]));
            w[1] = cvtpk(EXP2F(sa[2]), EXP2F(sa[3]));
            w[2] = cvtpk(EXP2F(sb[0]), EXP2F(sb[1]));
            w[3] = cvtpk(EXP2F(sb[2]), EXP2F(sb[3]));
            const s16x8 pf = __builtin_bit_cast(s16x8, w);
            acc[0][nt] = __builtin_amdgcn_mfma_f32_16x16x32_bf16(vf0, pf, acc[0][nt], 0, 0, 0);
            acc[1][nt] = __builtin_amdgcn_mfma_f32_16x16x32_bf16(vf1, pf, acc[1][nt], 0, 0, 0);
            accl[nt]   = __builtin_amdgcn_mfma_f32_16x16x32_bf16(ones, pf, accl[nt], 0, 0, 0);
        }
    }

    // pbuf wave record: [0..63] = l per query, [64..2111] = O^T partial
    float* P = pbuf + (size_t)wid * 2112;
    if (g == 0) {
        #pragma unroll
        for (int nt = 0; nt < 4; ++nt)
            P[nt * 16 + c] = accl[nt][0];
    }
    #pragma unroll
    for (int mi = 0; mi < 2; ++mi)
        #pragma unroll
        for (int nt = 0; nt < 4; ++nt)
            *(f32x4*)&P[64 + (c + 16*nt) * 32 + 16*mi + g*4] = acc[mi][nt];
}

// ---------------------------------------------------------------------------
// Merge 32 key-split partials: plain sums (no exp, no max).
// ---------------------------------------------------------------------------
__launch_bounds__(256)
__global__ void ca_merge(const float* __restrict__ pbuf, u16* __restrict__ ctx) {
    const int wave = threadIdx.x >> 6, lane = threadIdx.x & 63;
    const int sub = lane >> 5, d = lane & 31;
    const int rowid = blockIdx.x * 8 + wave * 2 + sub;     // 0..8191
    const int q = rowid & 63, qt = (rowid >> 6) & 7, h = (rowid >> 9) & 7, b = rowid >> 12;
    const size_t w0 = (size_t)((b * 8 + h) * 8 + qt) * 32;
    float L = 0.f, o = 0.f;
    #pragma unroll
    for (int i = 0; i < 32; ++i) {
        L += pbuf[(w0 + i) * 2112 + q];
        o += pbuf[(w0 + i) * 2112 + 64 + q * 32 + d];
    }
    const int t = qt * 64 + q;
    ctx[((size_t)b * 512 + t) * 256 + h * 32 + d] = f2bf(o / L);
}

// ---------------------------------------------------------------------------
// Final: out = LN(query + ctx^T).
// ---------------------------------------------------------------------------
__launch_bounds__(256)
__global__ void final_ln(const float* __restrict__ query, const u16* __restrict__ ctx4,
                         const float* __restrict__ g, const float* __restrict__ b,
                         float* __restrict__ out) {
    const int wave = threadIdx.x >> 6, lane = threadIdx.x & 63;
    const int row = blockIdx.x * 4 + wave;        // 0..1023 = t*2+bb
    const int t = row >> 1, bb = row & 1;
    const int c = lane * 4;
    float4 rq = *(const float4*)(query + (size_t)row * 256 + c);
    u16x4 rc = *(const u16x4*)(ctx4 + ((size_t)bb * 512 + t) * 256 + c);
    float x0 = rq.x + bf2f(rc[0]);
    float x1 = rq.y + bf2f(rc[1]);
    float x2 = rq.z + bf2f(rc[2]);
    float x3 = rq.w + bf2f(rc[3]);
    float s1 = x0 + x1 + x2 + x3;
    float s2 = x0*x0 + x1*x1 + x2*x2 + x3*x3;
    #pragma unroll
    for (int off = 32; off; off >>= 1) {
        s1 += __shfl_xor(s1, off);
        s2 += __shfl_xor(s2, off);
    }
    const float mean = s1 * (1.f/256.f);
    const float var  = s2 * (1.f/256.f) - mean*mean;
    const float rstd = rsqrtf(var + 1e-5f);
    float4 gg = *(const float4*)(g + c);
    float4 bv = *(const float4*)(b + c);
    float4 og;
    og.x = (x0-mean)*rstd*gg.x + bv.x;
    og.y = (x1-mean)*rstd*gg.y + bv.y;
    og.z = (x2-mean)*rstd*gg.z + bv.z;
    og.w = (x3-mean)*rstd*gg.w + bv.w;
    *(float4*)(out + (size_t)row * 256 + c) = og;
}

// ---------------------------------------------------------------------------

extern "C" void kernel_launch(void* const* d_in, const int* in_sizes, int n_in,
                              void* d_out, int out_size, void* d_ws, size_t ws_size,
                              hipStream_t stream) {
    const float* x_in  = (const float*)d_in[0];
    const float* query = (const float*)d_in[1];
    const float* n1_g  = (const float*)d_in[2];
    const float* n1_b  = (const float*)d_in[3];
    const float* qkv_w = (const float*)d_in[4];
    const float* qkv_b = (const float*)d_in[5];
    const float* out_w = (const float*)d_in[6];
    const float* out_b = (const float*)d_in[7];
    const float* rel   = (const float*)d_in[8];
    const float* n2_g  = (const float*)d_in[9];
    const float* n2_b  = (const float*)d_in[10];
    const float* fc1_w = (const float*)d_in[11];
    const float* fc1_b = (const float*)d_in[12];
    const float* fc2_w = (const float*)d_in[13];
    const float* fc2_b = (const float*)d_in[14];
    const float* can_g = (const float*)d_in[15];
    const float* can_b = (const float*)d_in[16];
    const float* cpq_w = (const float*)d_in[17];
    const float* cfc_w = (const float*)d_in[18];
    const float* cfc_b = (const float*)d_in[19];
    const float* cf1_w = (const float*)d_in[20];
    const float* cf1_b = (const float*)d_in[21];
    const float* cf2_w = (const float*)d_in[22];
    const float* cf2_b = (const float*)d_in[23];

    const int M = 32768;   // 2 * 128 * 128 tokens

    char* w = (char*)d_ws;
    float* xs  = (float*)w;  w += (size_t)M * 256 * 4;        // fp32 residual stream
    u16* hbuf  = (u16*)w;    w += (size_t)M * 256 * 2;        // bf16 LN/attn out
    u16* big   = (u16*)w;    w += (size_t)M * 1024 * 2;       // bf16 qkv / mlp hidden
    u16* arena = (u16*)w;    w += (size_t)2228224 * 2;        // bf16 weights + query
    u16* qbuf  = (u16*)w;    w += 524288;
    u16* ctx1  = (u16*)w;    w += 524288;
    u16* ctx2  = (u16*)w;    w += 524288;
    u16* ctx3  = (u16*)w;    w += 1048576;
    u16* ctx4  = (u16*)w;    w += 524288;
    u16* xb    = (u16*)w;    w += (size_t)M * 256 * 2;        // bf16 copy of final xs
    float* bfragb = (float*)w; w += 65536 * 4;                // bias C-fragments

    // vtbuf aliases the tail of `big` (qkv uses only M*768 of it; dead by fc1)
    u16* vtbuf = big + (size_t)M * 768;                       // 16 MB
    // CA-phase scratch aliases into `big` (free after the block loop):
    u16*   xbT  = big;                                        // (2,256,16384) 16 MB
    float* pbuf = (float*)(big + 8388608);                    // 4096 * 2112 f32 = 34.6 MB

    u16* wq   = arena;
    u16* wo   = arena + 393216;
    u16* wf1  = arena + 524288;
    u16* wf2  = arena + 1048576;
    u16* wcpq = arena + 1572864;
    u16* wcfc = arena + 1638400;
    u16* wcf1 = arena + 1703936;
    u16* wcf2 = arena + 1835008;
    u16* qcvt = arena + 1966080;

    cvt_weights<<<2176, 256, 0, stream>>>(qkv_w, out_w, fc1_w, fc2_w, cpq_w,
                                          cfc_w, cf1_w, cf2_w, query, arena);
    bias_frag_kernel<<<64, 256, 0, stream>>>(rel, bfragb);

    for (int i = 0; i < 2; ++i) {
        const float* src = (i == 0) ? x_in : xs;   // layer-0 reads input directly
        ln_kernel<<<M/4, 256, 0, stream>>>(src, hbuf, n1_g + i*256, n1_b + i*256, M);
        gemm128<7,false><<<dim3(6,256), 256, 0, stream>>>(
            hbuf, wq + (size_t)i*768*256, qkv_b + i*768, nullptr, big, vtbuf, M, 768, 256);
        win_attn<<<1024, 256, 0, stream>>>(big, vtbuf, bfragb, hbuf, i);
        gemm128<3,true><<<dim3(2,256), 256, 0, stream>>>(
            hbuf, wo + (size_t)i*65536, out_b + i*256, src, xs, nullptr, M, 256, 256);
        ln_kernel<<<M/4, 256, 0, stream>>>(xs, hbuf, n2_g + i*256, n2_b + i*256, M);
        gemm128<2,false><<<dim3(8,256), 256, 0, stream>>>(
            hbuf, wf1 + (size_t)i*262144, fc1_b + i*1024, nullptr, big, nullptr, M, 1024, 256);
        if (i == 0)
            gemm128<3,true><<<dim3(2,256), 256, 0, stream>>>(
                big, wf2, fc2_b, xs, xs, nullptr, M, 256, 1024);
        else
            gemm128<8,true><<<dim3(2,256), 256, 0, stream>>>(
                big, wf2 + 262144, fc2_b + 256, xs, xs, xb, M, 256, 1024);
    }

    // ---- cross-attention ----
    tr_kernel<<<dim3(256, 4, 2), 256, 0, stream>>>(xb, xbT);
    gemm_bt<6><<<dim3(4, 16), 256, 0, stream>>>(qcvt, wcpq, nullptr, qbuf, 1024, 256, 256);
    ca_flash<<<1024, 256, 0, stream>>>(qbuf, xb, xbT, pbuf);
    ca_merge<<<1024, 256, 0, stream>>>(pbuf, ctx1);
    gemm_bt<5><<<dim3(4, 16), 256, 0, stream>>>(ctx1, wcfc, cfc_b, ctx2, 1024, 256, 256);
    gemm_bt<4><<<dim3(8, 16), 256, 0, stream>>>(ctx2, wcf1, cf1_b, ctx3, 1024, 512, 256);
    gemm_bt<1><<<dim3(4, 16), 256, 0, stream>>>(ctx3, wcf2, cf2_b, ctx4, 1024, 256, 512);
    final_ln<<<256, 256, 0, stream>>>(query, ctx4, can_g, can_b, (float*)d_out);

    (void)in_sizes; (void)n_in; (void)out_size; (void)ws_size;
}

// Round 11
// 406.098 us; speedup vs baseline: 4.2391x; 1.1650x over previous
//
#include <hip/hip_runtime.h>
#include <hip/hip_bf16.h>

// ---------------------------------------------------------------------------
// Swin block ×2 + CrossAttnFFN. FP32 in/out, bf16 MFMA everywhere, fp32 accum.
// Round 11 (= round 10 + compile fix): gemm128 LDS both-sides XOR swizzle,
//           fast tanh-gelu, packed vtbuf stores in the qkv epilogue.
// ---------------------------------------------------------------------------

typedef unsigned short u16;
typedef u16  u16x4 __attribute__((ext_vector_type(4)));
typedef u16  u16x8 __attribute__((ext_vector_type(8)));
typedef short s16x8 __attribute__((ext_vector_type(8)));
typedef float f32x4 __attribute__((ext_vector_type(4)));
typedef unsigned int u32x4 __attribute__((ext_vector_type(4)));

#define LOG2E 1.4426950408889634f
#define SCALE_LOG2 0.25503480f   // (1/sqrt(32)) * log2(e)

static __device__ __forceinline__ float bf2f(u16 u) {
    union { unsigned int i; float f; } v; v.i = ((unsigned int)u) << 16; return v.f;
}
static __device__ __forceinline__ u16 f2bf(float f) {
    unsigned int x = __float_as_uint(f);
    unsigned int r = x + 0x7fffu + ((x >> 16) & 1u);   // RNE
    return (u16)(r >> 16);
}
static __device__ __forceinline__ unsigned int cvtpk(float a, float b) {
    unsigned int u;
    asm("v_cvt_pk_bf16_f32 %0, %1, %2" : "=v"(u) : "v"(a), "v"(b));
    return u;   // lo = bf16(a), hi = bf16(b)
}
static __device__ __forceinline__ void gld16(const u16* g, u16* l) {
    __builtin_amdgcn_global_load_lds(
        (const __attribute__((address_space(1))) unsigned int*)g,
        (__attribute__((address_space(3))) unsigned int*)l, 16, 0, 0);
}
#define EXP2F __builtin_amdgcn_exp2f

// ---------------------------------------------------------------------------
// fp32 -> bf16 weight/query conversion (one fused kernel).
// ---------------------------------------------------------------------------
__launch_bounds__(256)
__global__ void cvt_weights(const float* __restrict__ qkvw, const float* __restrict__ outw,
                            const float* __restrict__ f1w,  const float* __restrict__ f2w,
                            const float* __restrict__ cpq,  const float* __restrict__ cfc,
                            const float* __restrict__ cf1,  const float* __restrict__ cf2,
                            const float* __restrict__ qry,  u16* __restrict__ dst) {
    const int q = blockIdx.x * 256 + threadIdx.x;
    const int gid = q * 4;
    const float* s; int off;
    if      (gid <  393216) { s = qkvw; off = 0;       }
    else if (gid <  524288) { s = outw; off = 393216;  }
    else if (gid < 1048576) { s = f1w;  off = 524288;  }
    else if (gid < 1572864) { s = f2w;  off = 1048576; }
    else if (gid < 1638400) { s = cpq;  off = 1572864; }
    else if (gid < 1703936) { s = cfc;  off = 1638400; }
    else if (gid < 1835008) { s = cf1;  off = 1703936; }
    else if (gid < 1966080) { s = cf2;  off = 1835008; }
    else                    { s = qry;  off = 1966080; }
    float4 v = *(const float4*)(s + (gid - off));
    u16x4 o; o[0] = f2bf(v.x); o[1] = f2bf(v.y); o[2] = f2bf(v.z); o[3] = f2bf(v.w);
    *(u16x4*)(dst + gid) = o;
}

// ---------------------------------------------------------------------------
// Relative-position bias in MFMA C-fragment layout, PERMUTED key map,
// pre-scaled by log2(e).
// ---------------------------------------------------------------------------
__launch_bounds__(256)
__global__ void bias_frag_kernel(const float* __restrict__ rel, float* __restrict__ bfrag) {
    const int idx = blockIdx.x * 256 + threadIdx.x;      // 0..16383
    #pragma unroll
    for (int j = 0; j < 4; ++j) {
        const int i = idx * 4 + j;
        const int layer = i >> 15, h = (i >> 12) & 7, kt = (i >> 10) & 3,
                  qt = (i >> 8) & 3, lane = (i >> 2) & 63, jj = i & 3;
        const int key   = (kt >> 1) * 32 + 4 * (kt & 1) + 8 * (lane >> 4) + jj;
        const int query = qt * 16 + (lane & 15);
        const int dy = (query >> 3) - (key >> 3) + 7;
        const int dx = (query & 7)  - (key & 7)  + 7;
        bfrag[i] = rel[layer * 1800 + (dy * 15 + dx) * 8 + h] * LOG2E;
    }
}

// ---------------------------------------------------------------------------
// LayerNorm: one wave per row, C=256. fp32 in -> bf16 out.
// ---------------------------------------------------------------------------
__launch_bounds__(256)
__global__ void ln_kernel(const float* __restrict__ in, u16* __restrict__ out,
                          const float* __restrict__ g, const float* __restrict__ b,
                          int rows) {
    const int wave = threadIdx.x >> 6, lane = threadIdx.x & 63;
    const int row = blockIdx.x * 4 + wave;
    if (row >= rows) return;
    const int c = lane * 4;
    float4 v = *(const float4*)(in + (size_t)row * 256 + c);
    float s1 = v.x + v.y + v.z + v.w;
    float s2 = v.x*v.x + v.y*v.y + v.z*v.z + v.w*v.w;
    #pragma unroll
    for (int off = 32; off; off >>= 1) {
        s1 += __shfl_xor(s1, off);
        s2 += __shfl_xor(s2, off);
    }
    const float mean = s1 * (1.f/256.f);
    const float var  = s2 * (1.f/256.f) - mean*mean;
    const float rstd = rsqrtf(var + 1e-5f);
    float4 gg = *(const float4*)(g + c);
    float4 bb = *(const float4*)(b + c);
    u16x4 og;
    og[0] = f2bf((v.x-mean)*rstd*gg.x + bb.x);
    og[1] = f2bf((v.y-mean)*rstd*gg.y + bb.y);
    og[2] = f2bf((v.z-mean)*rstd*gg.z + bb.z);
    og[3] = f2bf((v.w-mean)*rstd*gg.w + bb.w);
    *(u16x4*)(out + (size_t)row * 256 + c) = og;
}

// ---------------------------------------------------------------------------
// 128x128 GEMM: linear LDS dest + global_load_lds(16B) with pre-swizzled
// global source slot, XOR-swizzled ds_read (both-sides involution, rule #21).
// XCD-aware block swizzle. BK=64.
// EPI: 2 +bias+fastgelu, 3 +bias+resid(f32), 7 qkv (+bias, scale q, v->vtbuf),
//      8 +bias+resid dual-write (f32 out + bf16 aux)
// ---------------------------------------------------------------------------
template<int EPI, bool F32O>
__launch_bounds__(256)
__global__ void gemm128(const u16* __restrict__ A, const u16* __restrict__ W,
                        const float* __restrict__ bias, const float* __restrict__ resid,
                        void* __restrict__ outv, u16* __restrict__ aux,
                        int M, int N, int K) {
    __shared__ u16 As[128 * 64];
    __shared__ u16 Bs[128 * 64];
    const int nx = gridDim.x;
    const int nwg = nx * gridDim.y;
    int bid = blockIdx.y * nx + blockIdx.x;
    bid = (bid & 7) * (nwg >> 3) + (bid >> 3);     // chunked XCD swizzle (T1)
    const int m0 = (bid / nx) * 128, n0 = (bid % nx) * 128;
    const int tid = threadIdx.x, lane = tid & 63, wave = tid >> 6;
    const int g = lane >> 4, c = lane & 15;
    const int wm = (wave >> 1) * 64, wn = (wave & 1) * 64;

    f32x4 acc[4][4];
    #pragma unroll
    for (int i = 0; i < 4; ++i)
        #pragma unroll
        for (int j = 0; j < 4; ++j) acc[i][j] = f32x4{0.f,0.f,0.f,0.f};

    // staging: lane l -> LDS row ch*8 + (l>>3), slot l&7 (linear, DMA order);
    // global source slot is (l&7)^(l>>3) so LDS (row,slot) holds global slot
    // slot^(row&7) — the read-side applies the same XOR.
    const int srow = (lane >> 3);
    const int scol = ((lane & 7) ^ srow) * 8;      // pre-swizzled source slot
    const int cx = c & 7;                          // read-side XOR key
    for (int k0 = 0; k0 < K; k0 += 64) {
        #pragma unroll
        for (int i = 0; i < 4; ++i) {
            const int ch = wave * 4 + i;             // chunk 0..15 (8 rows each)
            const int r = ch * 8 + srow;
            gld16(&A[(size_t)(m0 + r) * K + k0 + scol], &As[ch * 512]);
            gld16(&W[(size_t)(n0 + r) * K + k0 + scol], &Bs[ch * 512]);
        }
        __syncthreads();
        #pragma unroll
        for (int kk = 0; kk < 64; kk += 32) {
            const int slot = (kk >> 3) + g;          // 0..7 across kk,g
            s16x8 af[4], bf_[4];
            #pragma unroll
            for (int mi = 0; mi < 4; ++mi)
                af[mi] = *(const s16x8*)&As[(wm + mi*16 + c) * 64 + (slot ^ cx) * 8];
            #pragma unroll
            for (int ni = 0; ni < 4; ++ni)
                bf_[ni] = *(const s16x8*)&Bs[(wn + ni*16 + c) * 64 + (slot ^ cx) * 8];
            #pragma unroll
            for (int mi = 0; mi < 4; ++mi)
                #pragma unroll
                for (int ni = 0; ni < 4; ++ni)
                    acc[mi][ni] = __builtin_amdgcn_mfma_f32_16x16x32_bf16(
                        af[mi], bf_[ni], acc[mi][ni], 0, 0, 0);
        }
        __syncthreads();
    }

    #pragma unroll
    for (int mi = 0; mi < 4; ++mi) {
        #pragma unroll
        for (int ni = 0; ni < 4; ++ni) {
            const int col = n0 + wn + ni*16 + c;
            if (EPI == 7 && col >= 512) {
                // v-columns: packed u16x4 store (keys g*4..g*4+3 consecutive)
                const int row0 = m0 + wm + mi*16 + g*4;
                const int bidx = row0 >> 14, y = (row0 >> 7) & 127, xx0 = row0 & 127;
                const int wini = (bidx*16 + (y>>3))*16 + (xx0>>3);
                const int key0 = ((y&7)<<3) | (xx0&7);
                const float bb2 = bias[col];
                u16x4 pv;
                #pragma unroll
                for (int j = 0; j < 4; ++j) pv[j] = f2bf(acc[mi][ni][j] + bb2);
                *(u16x4*)&aux[((size_t)wini*256 + (col-512))*64 + key0] = pv;
                continue;
            }
            #pragma unroll
            for (int j = 0; j < 4; ++j) {
                const int row = m0 + wm + mi*16 + g*4 + j;
                float v = acc[mi][ni][j];
                v += bias[col];
                if (EPI == 2) {
                    // fast gelu: v * t/(t+1), t = exp2(C*(v + 0.044715 v^3))
                    const float t = EXP2F(2.3022082f * fmaf(0.044715f * v, v * v, v));
                    v = v * t * __builtin_amdgcn_rcpf(t + 1.f);
                }
                if (EPI == 3 || EPI == 8) v += resid[(size_t)row * N + col];
                if (EPI == 8) {
                    ((float*)outv)[(size_t)row * N + col] = v;
                    aux[(size_t)row * N + col] = f2bf(v);
                    continue;
                }
                if (EPI == 7 && col < 256) v *= SCALE_LOG2;
                if (F32O) ((float*)outv)[(size_t)row * N + col] = v;
                else      ((u16*)outv)[(size_t)row * N + col]   = f2bf(v);
            }
        }
    }
}

// ---------------------------------------------------------------------------
// 64x64 GEMM (M=1024 CA GEMMs). EPI: 1 bias, 4 bias+relu, 5 bias+clip32,
// 6 softmax-log2-scale (no bias).
// ---------------------------------------------------------------------------
template<int EPI>
__launch_bounds__(256)
__global__ void gemm_bt(const u16* __restrict__ A, const u16* __restrict__ W,
                        const float* __restrict__ bias, u16* __restrict__ out,
                        int M, int N, int K) {
    __shared__ u16 As[64][72];
    __shared__ u16 Bs[64][72];
    const int m0 = blockIdx.y * 64;
    const int n0 = blockIdx.x * 64;
    const int tid = threadIdx.x;
    const int lane = tid & 63, wave = tid >> 6;
    const int wm = (wave >> 1) * 32, wn = (wave & 1) * 32;

    f32x4 acc[2][2];
    #pragma unroll
    for (int i = 0; i < 2; ++i)
        #pragma unroll
        for (int j = 0; j < 2; ++j) acc[i][j] = f32x4{0.f,0.f,0.f,0.f};

    for (int k0 = 0; k0 < K; k0 += 64) {
        #pragma unroll
        for (int rep = 0; rep < 2; ++rep) {
            int i = tid + rep * 256;
            int r = i >> 3, c = (i & 7) * 8;
            *(s16x8*)&As[r][c] = *(const s16x8*)&A[(size_t)(m0 + r) * K + k0 + c];
            *(s16x8*)&Bs[r][c] = *(const s16x8*)&W[(size_t)(n0 + r) * K + k0 + c];
        }
        __syncthreads();
        #pragma unroll
        for (int kk = 0; kk < 64; kk += 32) {
            s16x8 af[2], bfr[2];
            #pragma unroll
            for (int i = 0; i < 2; ++i) {
                af[i]  = *(const s16x8*)&As[wm + i*16 + (lane & 15)][kk + (lane >> 4) * 8];
                bfr[i] = *(const s16x8*)&Bs[wn + i*16 + (lane & 15)][kk + (lane >> 4) * 8];
            }
            #pragma unroll
            for (int mi = 0; mi < 2; ++mi)
                #pragma unroll
                for (int ni = 0; ni < 2; ++ni)
                    acc[mi][ni] = __builtin_amdgcn_mfma_f32_16x16x32_bf16(
                        af[mi], bfr[ni], acc[mi][ni], 0, 0, 0);
        }
        __syncthreads();
    }

    #pragma unroll
    for (int mi = 0; mi < 2; ++mi) {
        #pragma unroll
        for (int ni = 0; ni < 2; ++ni) {
            const int col = n0 + wn + ni*16 + (lane & 15);
            #pragma unroll
            for (int j = 0; j < 4; ++j) {
                const int row = m0 + wm + mi*16 + (lane >> 4)*4 + j;
                float v = acc[mi][ni][j];
                if (EPI >= 1 && EPI <= 5) v += bias[col];
                if (EPI == 4) v = fmaxf(v, 0.f);
                if (EPI == 5) v = fminf(fmaxf(v, -32.f), 32.f);
                if (EPI == 6) v *= SCALE_LOG2;
                out[(size_t)row * N + col] = f2bf(v);
            }
        }
    }
}

// ---------------------------------------------------------------------------
// MFMA windowed self-attention, shuffle-free, max-free softmax.
// ---------------------------------------------------------------------------
__launch_bounds__(256)
__global__ void win_attn(const u16* __restrict__ qkv, const u16* __restrict__ vtbuf,
                         const float* __restrict__ bfrag, u16* __restrict__ o,
                         int layer) {
    const int wid = blockIdx.x * 4 + (threadIdx.x >> 6);   // 0..4095
    const int lane = threadIdx.x & 63;
    const int h = wid & 7, win = wid >> 3;
    const int b = win >> 8, wy = (win >> 4) & 15, wx = win & 15;
    const int g = lane >> 4, c = lane & 15;
    const size_t rowbase = (size_t)b * 16384 + (size_t)wy * 8 * 128 + wx * 8;

    s16x8 qf[4], kf[4];
    #pragma unroll
    for (int qt = 0; qt < 4; ++qt) {
        const int t = qt * 16 + c;
        qf[qt] = *(const s16x8*)&qkv[(rowbase + (size_t)(t >> 3) * 128 + (t & 7)) * 768
                                     + h * 32 + g * 8];
    }
    const int kp0 = 8 * (c >> 2) + (c & 3);       // permuted key row for this lane
    #pragma unroll
    for (int kt = 0; kt < 4; ++kt) {
        const int t = (kt >> 1) * 32 + 4 * (kt & 1) + kp0;
        kf[kt] = *(const s16x8*)&qkv[(rowbase + (size_t)(t >> 3) * 128 + (t & 7)) * 768
                                     + 256 + h * 32 + g * 8];
    }

    const float* bb = bfrag + (size_t)((layer * 8 + h) * 16) * 256;
    f32x4 st[4][4];
    #pragma unroll
    for (int kt = 0; kt < 4; ++kt)
        #pragma unroll
        for (int qt = 0; qt < 4; ++qt)
            st[kt][qt] = *(const f32x4*)&bb[(kt * 4 + qt) * 256 + lane * 4];
    #pragma unroll
    for (int kt = 0; kt < 4; ++kt)
        #pragma unroll
        for (int qt = 0; qt < 4; ++qt)
            st[kt][qt] = __builtin_amdgcn_mfma_f32_16x16x32_bf16(
                kf[kt], qf[qt], st[kt][qt], 0, 0, 0);

    // max-free log2-domain softmax; 1/l deferred to output scale
    float linv[4];
    #pragma unroll
    for (int qt = 0; qt < 4; ++qt) {
        float sum = 0.f;
        #pragma unroll
        for (int kt = 0; kt < 4; ++kt)
            #pragma unroll
            for (int j = 0; j < 4; ++j) {
                const float p = EXP2F(st[kt][qt][j]);
                st[kt][qt][j] = p;
                sum += p;
            }
        sum += __shfl_xor(sum, 16);
        sum += __shfl_xor(sum, 32);
        linv[qt] = 1.f / sum;
    }

    const u16* vb = vtbuf + ((size_t)win * 256 + h * 32) * 64;
    s16x8 vf[2][2];
    #pragma unroll
    for (int dt = 0; dt < 2; ++dt)
        #pragma unroll
        for (int ks = 0; ks < 2; ++ks)
            vf[dt][ks] = *(const s16x8*)&vb[(size_t)(dt * 16 + c) * 64 + ks * 32 + g * 8];

    f32x4 acc[4][2];
    #pragma unroll
    for (int i = 0; i < 4; ++i)
        #pragma unroll
        for (int j = 0; j < 2; ++j) acc[i][j] = f32x4{0.f,0.f,0.f,0.f};

    #pragma unroll
    for (int qt = 0; qt < 4; ++qt) {
        #pragma unroll
        for (int ks = 0; ks < 2; ++ks) {
            u32x4 w;
            w[0] = cvtpk(st[2*ks][qt][0],   st[2*ks][qt][1]);
            w[1] = cvtpk(st[2*ks][qt][2],   st[2*ks][qt][3]);
            w[2] = cvtpk(st[2*ks+1][qt][0], st[2*ks+1][qt][1]);
            w[3] = cvtpk(st[2*ks+1][qt][2], st[2*ks+1][qt][3]);
            const s16x8 pfrag = __builtin_bit_cast(s16x8, w);
            acc[qt][0] = __builtin_amdgcn_mfma_f32_16x16x32_bf16(pfrag, vf[0][ks], acc[qt][0], 0,0,0);
            acc[qt][1] = __builtin_amdgcn_mfma_f32_16x16x32_bf16(pfrag, vf[1][ks], acc[qt][1], 0,0,0);
        }
    }

    #pragma unroll
    for (int qt = 0; qt < 4; ++qt)
        #pragma unroll
        for (int dt = 0; dt < 2; ++dt)
            #pragma unroll
            for (int j = 0; j < 4; ++j) {
                const int t = qt * 16 + g * 4 + j;
                o[(rowbase + (size_t)(t >> 3) * 128 + (t & 7)) * 256
                  + h * 32 + dt * 16 + c] = f2bf(acc[qt][dt][j] * linv[qt]);
            }
}

// ---------------------------------------------------------------------------
// Transpose: xbT[b][c][n] = xb[b][n][c].
// ---------------------------------------------------------------------------
__launch_bounds__(256)
__global__ void tr_kernel(const u16* __restrict__ src, u16* __restrict__ dst) {
    __shared__ u16 T[64][72];
    const int b = blockIdx.z;
    const int n0 = blockIdx.x * 64, c0 = blockIdx.y * 64;
    const int r = threadIdx.x >> 3, cc = (threadIdx.x & 7) * 8;
    const u16* S = src + (size_t)b * 16384 * 256;
    u16* D = dst + (size_t)b * 256 * 16384;
    #pragma unroll
    for (int rr = 0; rr < 64; rr += 32)
        *(u16x8*)&T[r + rr][cc] = *(const u16x8*)&S[(size_t)(n0 + r + rr) * 256 + c0 + cc];
    __syncthreads();
    #pragma unroll
    for (int rr = 0; rr < 64; rr += 32) {
        u16x8 v;
        #pragma unroll
        for (int k2 = 0; k2 < 8; ++k2) v[k2] = T[cc + k2][r + rr];
        *(u16x8*)&D[(size_t)(c0 + r + rr) * 16384 + n0 + cc] = v;
    }
}

// ---------------------------------------------------------------------------
// MFMA flash cross-attention: max-free softmax, denominator via ones-MFMA,
// 64 queries/wave, KSPLIT=32.
// ---------------------------------------------------------------------------
__launch_bounds__(256)
__global__ void ca_flash(const u16* __restrict__ qb, const u16* __restrict__ xb,
                         const u16* __restrict__ xbT, float* __restrict__ pbuf) {
    const int wid = blockIdx.x * 4 + (threadIdx.x >> 6);   // 0..4095
    const int lane = threadIdx.x & 63;
    const int ks = wid & 31, qt = (wid >> 5) & 7, h = (wid >> 8) & 7, b = wid >> 11;
    const int g = lane >> 4, c = lane & 15;
    const int kp0 = 8 * (c >> 2) + (c & 3);    // permuted key row for this lane

    s16x8 qf[4];
    #pragma unroll
    for (int nt = 0; nt < 4; ++nt) {
        const int q = qt * 64 + nt * 16 + c;
        qf[nt] = *(const s16x8*)&qb[((size_t)q * 2 + b) * 256 + h * 32 + g * 8];
    }
    const u16* Kb = xb  + (size_t)b * 16384 * 256 + h * 32;
    const u16* Vb = xbT + (size_t)b * 256 * 16384 + (size_t)(h * 32) * 16384;

    s16x8 ones;
    #pragma unroll
    for (int j = 0; j < 8; ++j) ones[j] = (short)0x3F80;   // bf16 1.0

    f32x4 acc[2][4];    // [d-tile][q-subtile]
    f32x4 accl[4];      // denominator rows per q-subtile
    #pragma unroll
    for (int j = 0; j < 4; ++j) {
        acc[0][j] = f32x4{0.f,0.f,0.f,0.f};
        acc[1][j] = f32x4{0.f,0.f,0.f,0.f};
        accl[j]   = f32x4{0.f,0.f,0.f,0.f};
    }

    const int base = ks * 512;
    const f32x4 zero = f32x4{0.f, 0.f, 0.f, 0.f};
    for (int step = 0; step < 16; ++step) {
        const int n0 = base + step * 32;
        const s16x8 kf0 = *(const s16x8*)&Kb[(size_t)(n0 + kp0) * 256 + g * 8];
        const s16x8 kf1 = *(const s16x8*)&Kb[(size_t)(n0 + kp0 + 4) * 256 + g * 8];
        const s16x8 vf0 = *(const s16x8*)&Vb[(size_t)c * 16384 + n0 + g * 8];
        const s16x8 vf1 = *(const s16x8*)&Vb[(size_t)(16 + c) * 16384 + n0 + g * 8];
        #pragma unroll
        for (int nt = 0; nt < 4; ++nt) {
            const f32x4 sa = __builtin_amdgcn_mfma_f32_16x16x32_bf16(kf0, qf[nt], zero, 0, 0, 0);
            const f32x4 sb = __builtin_amdgcn_mfma_f32_16x16x32_bf16(kf1, qf[nt], zero, 0, 0, 0);
            u32x4 w;
            w[0] = cvtpk(EXP2F(sa[0]), EXP2F(sa[1]));
            w[1] = cvtpk(EXP2F(sa[2]), EXP2F(sa[3]));
            w[2] = cvtpk(EXP2F(sb[0]), EXP2F(sb[1]));
            w[3] = cvtpk(EXP2F(sb[2]), EXP2F(sb[3]));
            const s16x8 pf = __builtin_bit_cast(s16x8, w);
            acc[0][nt] = __builtin_amdgcn_mfma_f32_16x16x32_bf16(vf0, pf, acc[0][nt], 0, 0, 0);
            acc[1][nt] = __builtin_amdgcn_mfma_f32_16x16x32_bf16(vf1, pf, acc[1][nt], 0, 0, 0);
            accl[nt]   = __builtin_amdgcn_mfma_f32_16x16x32_bf16(ones, pf, accl[nt], 0, 0, 0);
        }
    }

    float* P = pbuf + (size_t)wid * 2112;
    if (g == 0) {
        #pragma unroll
        for (int nt = 0; nt < 4; ++nt)
            P[nt * 16 + c] = accl[nt][0];
    }
    #pragma unroll
    for (int mi = 0; mi < 2; ++mi)
        #pragma unroll
        for (int nt = 0; nt < 4; ++nt)
            *(f32x4*)&P[64 + (c + 16*nt) * 32 + 16*mi + g*4] = acc[mi][nt];
}

// ---------------------------------------------------------------------------
// Merge 32 key-split partials: plain sums (no exp, no max).
// ---------------------------------------------------------------------------
__launch_bounds__(256)
__global__ void ca_merge(const float* __restrict__ pbuf, u16* __restrict__ ctx) {
    const int wave = threadIdx.x >> 6, lane = threadIdx.x & 63;
    const int sub = lane >> 5, d = lane & 31;
    const int rowid = blockIdx.x * 8 + wave * 2 + sub;     // 0..8191
    const int q = rowid & 63, qt = (rowid >> 6) & 7, h = (rowid >> 9) & 7, b = rowid >> 12;
    const size_t w0 = (size_t)((b * 8 + h) * 8 + qt) * 32;
    float L = 0.f, o = 0.f;
    #pragma unroll
    for (int i = 0; i < 32; ++i) {
        L += pbuf[(w0 + i) * 2112 + q];
        o += pbuf[(w0 + i) * 2112 + 64 + q * 32 + d];
    }
    const int t = qt * 64 + q;
    ctx[((size_t)b * 512 + t) * 256 + h * 32 + d] = f2bf(o / L);
}

// ---------------------------------------------------------------------------
// Final: out = LN(query + ctx^T).
// ---------------------------------------------------------------------------
__launch_bounds__(256)
__global__ void final_ln(const float* __restrict__ query, const u16* __restrict__ ctx4,
                         const float* __restrict__ g, const float* __restrict__ b,
                         float* __restrict__ out) {
    const int wave = threadIdx.x >> 6, lane = threadIdx.x & 63;
    const int row = blockIdx.x * 4 + wave;        // 0..1023 = t*2+bb
    const int t = row >> 1, bb = row & 1;
    const int c = lane * 4;
    float4 rq = *(const float4*)(query + (size_t)row * 256 + c);
    u16x4 rc = *(const u16x4*)(ctx4 + ((size_t)bb * 512 + t) * 256 + c);
    float x0 = rq.x + bf2f(rc[0]);
    float x1 = rq.y + bf2f(rc[1]);
    float x2 = rq.z + bf2f(rc[2]);
    float x3 = rq.w + bf2f(rc[3]);
    float s1 = x0 + x1 + x2 + x3;
    float s2 = x0*x0 + x1*x1 + x2*x2 + x3*x3;
    #pragma unroll
    for (int off = 32; off; off >>= 1) {
        s1 += __shfl_xor(s1, off);
        s2 += __shfl_xor(s2, off);
    }
    const float mean = s1 * (1.f/256.f);
    const float var  = s2 * (1.f/256.f) - mean*mean;
    const float rstd = rsqrtf(var + 1e-5f);
    float4 gg = *(const float4*)(g + c);
    float4 bv = *(const float4*)(b + c);
    float4 og;
    og.x = (x0-mean)*rstd*gg.x + bv.x;
    og.y = (x1-mean)*rstd*gg.y + bv.y;
    og.z = (x2-mean)*rstd*gg.z + bv.z;
    og.w = (x3-mean)*rstd*gg.w + bv.w;
    *(float4*)(out + (size_t)row * 256 + c) = og;
}

// ---------------------------------------------------------------------------

extern "C" void kernel_launch(void* const* d_in, const int* in_sizes, int n_in,
                              void* d_out, int out_size, void* d_ws, size_t ws_size,
                              hipStream_t stream) {
    const float* x_in  = (const float*)d_in[0];
    const float* query = (const float*)d_in[1];
    const float* n1_g  = (const float*)d_in[2];
    const float* n1_b  = (const float*)d_in[3];
    const float* qkv_w = (const float*)d_in[4];
    const float* qkv_b = (const float*)d_in[5];
    const float* out_w = (const float*)d_in[6];
    const float* out_b = (const float*)d_in[7];
    const float* rel   = (const float*)d_in[8];
    const float* n2_g  = (const float*)d_in[9];
    const float* n2_b  = (const float*)d_in[10];
    const float* fc1_w = (const float*)d_in[11];
    const float* fc1_b = (const float*)d_in[12];
    const float* fc2_w = (const float*)d_in[13];
    const float* fc2_b = (const float*)d_in[14];
    const float* can_g = (const float*)d_in[15];
    const float* can_b = (const float*)d_in[16];
    const float* cpq_w = (const float*)d_in[17];
    const float* cfc_w = (const float*)d_in[18];
    const float* cfc_b = (const float*)d_in[19];
    const float* cf1_w = (const float*)d_in[20];
    const float* cf1_b = (const float*)d_in[21];
    const float* cf2_w = (const float*)d_in[22];
    const float* cf2_b = (const float*)d_in[23];

    const int M = 32768;   // 2 * 128 * 128 tokens

    char* w = (char*)d_ws;
    float* xs  = (float*)w;  w += (size_t)M * 256 * 4;        // fp32 residual stream
    u16* hbuf  = (u16*)w;    w += (size_t)M * 256 * 2;        // bf16 LN/attn out
    u16* big   = (u16*)w;    w += (size_t)M * 1024 * 2;       // bf16 qkv / mlp hidden
    u16* arena = (u16*)w;    w += (size_t)2228224 * 2;        // bf16 weights + query
    u16* qbuf  = (u16*)w;    w += 524288;
    u16* ctx1  = (u16*)w;    w += 524288;
    u16* ctx2  = (u16*)w;    w += 524288;
    u16* ctx3  = (u16*)w;    w += 1048576;
    u16* ctx4  = (u16*)w;    w += 524288;
    u16* xb    = (u16*)w;    w += (size_t)M * 256 * 2;        // bf16 copy of final xs
    float* bfragb = (float*)w; w += 65536 * 4;                // bias C-fragments

    u16* vtbuf = big + (size_t)M * 768;                       // 16 MB (qkv tail)
    u16*   xbT  = big;                                        // (2,256,16384) 16 MB
    float* pbuf = (float*)(big + 8388608);                    // 4096 * 2112 f32

    u16* wq   = arena;
    u16* wo   = arena + 393216;
    u16* wf1  = arena + 524288;
    u16* wf2  = arena + 1048576;
    u16* wcpq = arena + 1572864;
    u16* wcfc = arena + 1638400;
    u16* wcf1 = arena + 1703936;
    u16* wcf2 = arena + 1835008;
    u16* qcvt = arena + 1966080;

    cvt_weights<<<2176, 256, 0, stream>>>(qkv_w, out_w, fc1_w, fc2_w, cpq_w,
                                          cfc_w, cf1_w, cf2_w, query, arena);
    bias_frag_kernel<<<64, 256, 0, stream>>>(rel, bfragb);

    for (int i = 0; i < 2; ++i) {
        const float* src = (i == 0) ? x_in : xs;   // layer-0 reads input directly
        ln_kernel<<<M/4, 256, 0, stream>>>(src, hbuf, n1_g + i*256, n1_b + i*256, M);
        gemm128<7,false><<<dim3(6,256), 256, 0, stream>>>(
            hbuf, wq + (size_t)i*768*256, qkv_b + i*768, nullptr, big, vtbuf, M, 768, 256);
        win_attn<<<1024, 256, 0, stream>>>(big, vtbuf, bfragb, hbuf, i);
        gemm128<3,true><<<dim3(2,256), 256, 0, stream>>>(
            hbuf, wo + (size_t)i*65536, out_b + i*256, src, xs, nullptr, M, 256, 256);
        ln_kernel<<<M/4, 256, 0, stream>>>(xs, hbuf, n2_g + i*256, n2_b + i*256, M);
        gemm128<2,false><<<dim3(8,256), 256, 0, stream>>>(
            hbuf, wf1 + (size_t)i*262144, fc1_b + i*1024, nullptr, big, nullptr, M, 1024, 256);
        if (i == 0)
            gemm128<3,true><<<dim3(2,256), 256, 0, stream>>>(
                big, wf2, fc2_b, xs, xs, nullptr, M, 256, 1024);
        else
            gemm128<8,true><<<dim3(2,256), 256, 0, stream>>>(
                big, wf2 + 262144, fc2_b + 256, xs, xs, xb, M, 256, 1024);
    }

    // ---- cross-attention ----
    tr_kernel<<<dim3(256, 4, 2), 256, 0, stream>>>(xb, xbT);
    gemm_bt<6><<<dim3(4, 16), 256, 0, stream>>>(qcvt, wcpq, nullptr, qbuf, 1024, 256, 256);
    ca_flash<<<1024, 256, 0, stream>>>(qbuf, xb, xbT, pbuf);
    ca_merge<<<1024, 256, 0, stream>>>(pbuf, ctx1);
    gemm_bt<5><<<dim3(4, 16), 256, 0, stream>>>(ctx1, wcfc, cfc_b, ctx2, 1024, 256, 256);
    gemm_bt<4><<<dim3(8, 16), 256, 0, stream>>>(ctx2, wcf1, cf1_b, ctx3, 1024, 512, 256);
    gemm_bt<1><<<dim3(4, 16), 256, 0, stream>>>(ctx3, wcf2, cf2_b, ctx4, 1024, 256, 512);
    final_ln<<<256, 256, 0, stream>>>(query, ctx4, can_g, can_b, (float*)d_out);

    (void)in_sizes; (void)n_in; (void)out_size; (void)ws_size;
}

// Round 12
// 401.275 us; speedup vs baseline: 4.2900x; 1.0120x over previous
//
#include <hip/hip_runtime.h>
#include <hip/hip_bf16.h>

// ---------------------------------------------------------------------------
// Swin block ×2 + CrossAttnFFN. FP32 in/out, bf16 MFMA everywhere, fp32 accum.
// Round 12: ca_flash 128 queries/wave (K/V cache traffic 256 -> 128 MB).
// ---------------------------------------------------------------------------

typedef unsigned short u16;
typedef u16  u16x4 __attribute__((ext_vector_type(4)));
typedef u16  u16x8 __attribute__((ext_vector_type(8)));
typedef short s16x8 __attribute__((ext_vector_type(8)));
typedef float f32x4 __attribute__((ext_vector_type(4)));
typedef unsigned int u32x4 __attribute__((ext_vector_type(4)));

#define LOG2E 1.4426950408889634f
#define SCALE_LOG2 0.25503480f   // (1/sqrt(32)) * log2(e)

static __device__ __forceinline__ float bf2f(u16 u) {
    union { unsigned int i; float f; } v; v.i = ((unsigned int)u) << 16; return v.f;
}
static __device__ __forceinline__ u16 f2bf(float f) {
    unsigned int x = __float_as_uint(f);
    unsigned int r = x + 0x7fffu + ((x >> 16) & 1u);   // RNE
    return (u16)(r >> 16);
}
static __device__ __forceinline__ unsigned int cvtpk(float a, float b) {
    unsigned int u;
    asm("v_cvt_pk_bf16_f32 %0, %1, %2" : "=v"(u) : "v"(a), "v"(b));
    return u;   // lo = bf16(a), hi = bf16(b)
}
static __device__ __forceinline__ void gld16(const u16* g, u16* l) {
    __builtin_amdgcn_global_load_lds(
        (const __attribute__((address_space(1))) unsigned int*)g,
        (__attribute__((address_space(3))) unsigned int*)l, 16, 0, 0);
}
#define EXP2F __builtin_amdgcn_exp2f

// ---------------------------------------------------------------------------
// fp32 -> bf16 weight/query conversion (one fused kernel).
// ---------------------------------------------------------------------------
__launch_bounds__(256)
__global__ void cvt_weights(const float* __restrict__ qkvw, const float* __restrict__ outw,
                            const float* __restrict__ f1w,  const float* __restrict__ f2w,
                            const float* __restrict__ cpq,  const float* __restrict__ cfc,
                            const float* __restrict__ cf1,  const float* __restrict__ cf2,
                            const float* __restrict__ qry,  u16* __restrict__ dst) {
    const int q = blockIdx.x * 256 + threadIdx.x;
    const int gid = q * 4;
    const float* s; int off;
    if      (gid <  393216) { s = qkvw; off = 0;       }
    else if (gid <  524288) { s = outw; off = 393216;  }
    else if (gid < 1048576) { s = f1w;  off = 524288;  }
    else if (gid < 1572864) { s = f2w;  off = 1048576; }
    else if (gid < 1638400) { s = cpq;  off = 1572864; }
    else if (gid < 1703936) { s = cfc;  off = 1638400; }
    else if (gid < 1835008) { s = cf1;  off = 1703936; }
    else if (gid < 1966080) { s = cf2;  off = 1835008; }
    else                    { s = qry;  off = 1966080; }
    float4 v = *(const float4*)(s + (gid - off));
    u16x4 o; o[0] = f2bf(v.x); o[1] = f2bf(v.y); o[2] = f2bf(v.z); o[3] = f2bf(v.w);
    *(u16x4*)(dst + gid) = o;
}

// ---------------------------------------------------------------------------
// Relative-position bias in MFMA C-fragment layout, PERMUTED key map,
// pre-scaled by log2(e).
// ---------------------------------------------------------------------------
__launch_bounds__(256)
__global__ void bias_frag_kernel(const float* __restrict__ rel, float* __restrict__ bfrag) {
    const int idx = blockIdx.x * 256 + threadIdx.x;      // 0..16383
    #pragma unroll
    for (int j = 0; j < 4; ++j) {
        const int i = idx * 4 + j;
        const int layer = i >> 15, h = (i >> 12) & 7, kt = (i >> 10) & 3,
                  qt = (i >> 8) & 3, lane = (i >> 2) & 63, jj = i & 3;
        const int key   = (kt >> 1) * 32 + 4 * (kt & 1) + 8 * (lane >> 4) + jj;
        const int query = qt * 16 + (lane & 15);
        const int dy = (query >> 3) - (key >> 3) + 7;
        const int dx = (query & 7)  - (key & 7)  + 7;
        bfrag[i] = rel[layer * 1800 + (dy * 15 + dx) * 8 + h] * LOG2E;
    }
}

// ---------------------------------------------------------------------------
// LayerNorm: one wave per row, C=256. fp32 in -> bf16 out.
// ---------------------------------------------------------------------------
__launch_bounds__(256)
__global__ void ln_kernel(const float* __restrict__ in, u16* __restrict__ out,
                          const float* __restrict__ g, const float* __restrict__ b,
                          int rows) {
    const int wave = threadIdx.x >> 6, lane = threadIdx.x & 63;
    const int row = blockIdx.x * 4 + wave;
    if (row >= rows) return;
    const int c = lane * 4;
    float4 v = *(const float4*)(in + (size_t)row * 256 + c);
    float s1 = v.x + v.y + v.z + v.w;
    float s2 = v.x*v.x + v.y*v.y + v.z*v.z + v.w*v.w;
    #pragma unroll
    for (int off = 32; off; off >>= 1) {
        s1 += __shfl_xor(s1, off);
        s2 += __shfl_xor(s2, off);
    }
    const float mean = s1 * (1.f/256.f);
    const float var  = s2 * (1.f/256.f) - mean*mean;
    const float rstd = rsqrtf(var + 1e-5f);
    float4 gg = *(const float4*)(g + c);
    float4 bb = *(const float4*)(b + c);
    u16x4 og;
    og[0] = f2bf((v.x-mean)*rstd*gg.x + bb.x);
    og[1] = f2bf((v.y-mean)*rstd*gg.y + bb.y);
    og[2] = f2bf((v.z-mean)*rstd*gg.z + bb.z);
    og[3] = f2bf((v.w-mean)*rstd*gg.w + bb.w);
    *(u16x4*)(out + (size_t)row * 256 + c) = og;
}

// ---------------------------------------------------------------------------
// 128x128 GEMM: linear LDS dest + global_load_lds(16B) with pre-swizzled
// global source slot, XOR-swizzled ds_read. XCD-aware block swizzle. BK=64.
// EPI: 2 +bias+fastgelu, 3 +bias+resid(f32), 7 qkv (+bias, scale q, v->vtbuf),
//      8 +bias+resid dual-write (f32 out + bf16 aux)
// ---------------------------------------------------------------------------
template<int EPI, bool F32O>
__launch_bounds__(256)
__global__ void gemm128(const u16* __restrict__ A, const u16* __restrict__ W,
                        const float* __restrict__ bias, const float* __restrict__ resid,
                        void* __restrict__ outv, u16* __restrict__ aux,
                        int M, int N, int K) {
    __shared__ u16 As[128 * 64];
    __shared__ u16 Bs[128 * 64];
    const int nx = gridDim.x;
    const int nwg = nx * gridDim.y;
    int bid = blockIdx.y * nx + blockIdx.x;
    bid = (bid & 7) * (nwg >> 3) + (bid >> 3);     // chunked XCD swizzle (T1)
    const int m0 = (bid / nx) * 128, n0 = (bid % nx) * 128;
    const int tid = threadIdx.x, lane = tid & 63, wave = tid >> 6;
    const int g = lane >> 4, c = lane & 15;
    const int wm = (wave >> 1) * 64, wn = (wave & 1) * 64;

    f32x4 acc[4][4];
    #pragma unroll
    for (int i = 0; i < 4; ++i)
        #pragma unroll
        for (int j = 0; j < 4; ++j) acc[i][j] = f32x4{0.f,0.f,0.f,0.f};

    const int srow = (lane >> 3);
    const int scol = ((lane & 7) ^ srow) * 8;      // pre-swizzled source slot
    const int cx = c & 7;                          // read-side XOR key
    for (int k0 = 0; k0 < K; k0 += 64) {
        #pragma unroll
        for (int i = 0; i < 4; ++i) {
            const int ch = wave * 4 + i;             // chunk 0..15 (8 rows each)
            const int r = ch * 8 + srow;
            gld16(&A[(size_t)(m0 + r) * K + k0 + scol], &As[ch * 512]);
            gld16(&W[(size_t)(n0 + r) * K + k0 + scol], &Bs[ch * 512]);
        }
        __syncthreads();
        #pragma unroll
        for (int kk = 0; kk < 64; kk += 32) {
            const int slot = (kk >> 3) + g;          // 0..7 across kk,g
            s16x8 af[4], bf_[4];
            #pragma unroll
            for (int mi = 0; mi < 4; ++mi)
                af[mi] = *(const s16x8*)&As[(wm + mi*16 + c) * 64 + (slot ^ cx) * 8];
            #pragma unroll
            for (int ni = 0; ni < 4; ++ni)
                bf_[ni] = *(const s16x8*)&Bs[(wn + ni*16 + c) * 64 + (slot ^ cx) * 8];
            #pragma unroll
            for (int mi = 0; mi < 4; ++mi)
                #pragma unroll
                for (int ni = 0; ni < 4; ++ni)
                    acc[mi][ni] = __builtin_amdgcn_mfma_f32_16x16x32_bf16(
                        af[mi], bf_[ni], acc[mi][ni], 0, 0, 0);
        }
        __syncthreads();
    }

    #pragma unroll
    for (int mi = 0; mi < 4; ++mi) {
        #pragma unroll
        for (int ni = 0; ni < 4; ++ni) {
            const int col = n0 + wn + ni*16 + c;
            if (EPI == 7 && col >= 512) {
                const int row0 = m0 + wm + mi*16 + g*4;
                const int bidx = row0 >> 14, y = (row0 >> 7) & 127, xx0 = row0 & 127;
                const int wini = (bidx*16 + (y>>3))*16 + (xx0>>3);
                const int key0 = ((y&7)<<3) | (xx0&7);
                const float bb2 = bias[col];
                u16x4 pv;
                #pragma unroll
                for (int j = 0; j < 4; ++j) pv[j] = f2bf(acc[mi][ni][j] + bb2);
                *(u16x4*)&aux[((size_t)wini*256 + (col-512))*64 + key0] = pv;
                continue;
            }
            #pragma unroll
            for (int j = 0; j < 4; ++j) {
                const int row = m0 + wm + mi*16 + g*4 + j;
                float v = acc[mi][ni][j];
                v += bias[col];
                if (EPI == 2) {
                    const float t = EXP2F(2.3022082f * fmaf(0.044715f * v, v * v, v));
                    v = v * t * __builtin_amdgcn_rcpf(t + 1.f);
                }
                if (EPI == 3 || EPI == 8) v += resid[(size_t)row * N + col];
                if (EPI == 8) {
                    ((float*)outv)[(size_t)row * N + col] = v;
                    aux[(size_t)row * N + col] = f2bf(v);
                    continue;
                }
                if (EPI == 7 && col < 256) v *= SCALE_LOG2;
                if (F32O) ((float*)outv)[(size_t)row * N + col] = v;
                else      ((u16*)outv)[(size_t)row * N + col]   = f2bf(v);
            }
        }
    }
}

// ---------------------------------------------------------------------------
// 64x64 GEMM (M=1024 CA GEMMs). EPI: 1 bias, 4 bias+relu, 5 bias+clip32,
// 6 softmax-log2-scale (no bias).
// ---------------------------------------------------------------------------
template<int EPI>
__launch_bounds__(256)
__global__ void gemm_bt(const u16* __restrict__ A, const u16* __restrict__ W,
                        const float* __restrict__ bias, u16* __restrict__ out,
                        int M, int N, int K) {
    __shared__ u16 As[64][72];
    __shared__ u16 Bs[64][72];
    const int m0 = blockIdx.y * 64;
    const int n0 = blockIdx.x * 64;
    const int tid = threadIdx.x;
    const int lane = tid & 63, wave = tid >> 6;
    const int wm = (wave >> 1) * 32, wn = (wave & 1) * 32;

    f32x4 acc[2][2];
    #pragma unroll
    for (int i = 0; i < 2; ++i)
        #pragma unroll
        for (int j = 0; j < 2; ++j) acc[i][j] = f32x4{0.f,0.f,0.f,0.f};

    for (int k0 = 0; k0 < K; k0 += 64) {
        #pragma unroll
        for (int rep = 0; rep < 2; ++rep) {
            int i = tid + rep * 256;
            int r = i >> 3, c = (i & 7) * 8;
            *(s16x8*)&As[r][c] = *(const s16x8*)&A[(size_t)(m0 + r) * K + k0 + c];
            *(s16x8*)&Bs[r][c] = *(const s16x8*)&W[(size_t)(n0 + r) * K + k0 + c];
        }
        __syncthreads();
        #pragma unroll
        for (int kk = 0; kk < 64; kk += 32) {
            s16x8 af[2], bfr[2];
            #pragma unroll
            for (int i = 0; i < 2; ++i) {
                af[i]  = *(const s16x8*)&As[wm + i*16 + (lane & 15)][kk + (lane >> 4) * 8];
                bfr[i] = *(const s16x8*)&Bs[wn + i*16 + (lane & 15)][kk + (lane >> 4) * 8];
            }
            #pragma unroll
            for (int mi = 0; mi < 2; ++mi)
                #pragma unroll
                for (int ni = 0; ni < 2; ++ni)
                    acc[mi][ni] = __builtin_amdgcn_mfma_f32_16x16x32_bf16(
                        af[mi], bfr[ni], acc[mi][ni], 0, 0, 0);
        }
        __syncthreads();
    }

    #pragma unroll
    for (int mi = 0; mi < 2; ++mi) {
        #pragma unroll
        for (int ni = 0; ni < 2; ++ni) {
            const int col = n0 + wn + ni*16 + (lane & 15);
            #pragma unroll
            for (int j = 0; j < 4; ++j) {
                const int row = m0 + wm + mi*16 + (lane >> 4)*4 + j;
                float v = acc[mi][ni][j];
                if (EPI >= 1 && EPI <= 5) v += bias[col];
                if (EPI == 4) v = fmaxf(v, 0.f);
                if (EPI == 5) v = fminf(fmaxf(v, -32.f), 32.f);
                if (EPI == 6) v *= SCALE_LOG2;
                out[(size_t)row * N + col] = f2bf(v);
            }
        }
    }
}

// ---------------------------------------------------------------------------
// MFMA windowed self-attention, shuffle-free, max-free softmax.
// ---------------------------------------------------------------------------
__launch_bounds__(256)
__global__ void win_attn(const u16* __restrict__ qkv, const u16* __restrict__ vtbuf,
                         const float* __restrict__ bfrag, u16* __restrict__ o,
                         int layer) {
    const int wid = blockIdx.x * 4 + (threadIdx.x >> 6);   // 0..4095
    const int lane = threadIdx.x & 63;
    const int h = wid & 7, win = wid >> 3;
    const int b = win >> 8, wy = (win >> 4) & 15, wx = win & 15;
    const int g = lane >> 4, c = lane & 15;
    const size_t rowbase = (size_t)b * 16384 + (size_t)wy * 8 * 128 + wx * 8;

    s16x8 qf[4], kf[4];
    #pragma unroll
    for (int qt = 0; qt < 4; ++qt) {
        const int t = qt * 16 + c;
        qf[qt] = *(const s16x8*)&qkv[(rowbase + (size_t)(t >> 3) * 128 + (t & 7)) * 768
                                     + h * 32 + g * 8];
    }
    const int kp0 = 8 * (c >> 2) + (c & 3);       // permuted key row for this lane
    #pragma unroll
    for (int kt = 0; kt < 4; ++kt) {
        const int t = (kt >> 1) * 32 + 4 * (kt & 1) + kp0;
        kf[kt] = *(const s16x8*)&qkv[(rowbase + (size_t)(t >> 3) * 128 + (t & 7)) * 768
                                     + 256 + h * 32 + g * 8];
    }

    const float* bb = bfrag + (size_t)((layer * 8 + h) * 16) * 256;
    f32x4 st[4][4];
    #pragma unroll
    for (int kt = 0; kt < 4; ++kt)
        #pragma unroll
        for (int qt = 0; qt < 4; ++qt)
            st[kt][qt] = *(const f32x4*)&bb[(kt * 4 + qt) * 256 + lane * 4];
    #pragma unroll
    for (int kt = 0; kt < 4; ++kt)
        #pragma unroll
        for (int qt = 0; qt < 4; ++qt)
            st[kt][qt] = __builtin_amdgcn_mfma_f32_16x16x32_bf16(
                kf[kt], qf[qt], st[kt][qt], 0, 0, 0);

    float linv[4];
    #pragma unroll
    for (int qt = 0; qt < 4; ++qt) {
        float sum = 0.f;
        #pragma unroll
        for (int kt = 0; kt < 4; ++kt)
            #pragma unroll
            for (int j = 0; j < 4; ++j) {
                const float p = EXP2F(st[kt][qt][j]);
                st[kt][qt][j] = p;
                sum += p;
            }
        sum += __shfl_xor(sum, 16);
        sum += __shfl_xor(sum, 32);
        linv[qt] = 1.f / sum;
    }

    const u16* vb = vtbuf + ((size_t)win * 256 + h * 32) * 64;
    s16x8 vf[2][2];
    #pragma unroll
    for (int dt = 0; dt < 2; ++dt)
        #pragma unroll
        for (int ks = 0; ks < 2; ++ks)
            vf[dt][ks] = *(const s16x8*)&vb[(size_t)(dt * 16 + c) * 64 + ks * 32 + g * 8];

    f32x4 acc[4][2];
    #pragma unroll
    for (int i = 0; i < 4; ++i)
        #pragma unroll
        for (int j = 0; j < 2; ++j) acc[i][j] = f32x4{0.f,0.f,0.f,0.f};

    #pragma unroll
    for (int qt = 0; qt < 4; ++qt) {
        #pragma unroll
        for (int ks = 0; ks < 2; ++ks) {
            u32x4 w;
            w[0] = cvtpk(st[2*ks][qt][0],   st[2*ks][qt][1]);
            w[1] = cvtpk(st[2*ks][qt][2],   st[2*ks][qt][3]);
            w[2] = cvtpk(st[2*ks+1][qt][0], st[2*ks+1][qt][1]);
            w[3] = cvtpk(st[2*ks+1][qt][2], st[2*ks+1][qt][3]);
            const s16x8 pfrag = __builtin_bit_cast(s16x8, w);
            acc[qt][0] = __builtin_amdgcn_mfma_f32_16x16x32_bf16(pfrag, vf[0][ks], acc[qt][0], 0,0,0);
            acc[qt][1] = __builtin_amdgcn_mfma_f32_16x16x32_bf16(pfrag, vf[1][ks], acc[qt][1], 0,0,0);
        }
    }

    #pragma unroll
    for (int qt = 0; qt < 4; ++qt)
        #pragma unroll
        for (int dt = 0; dt < 2; ++dt)
            #pragma unroll
            for (int j = 0; j < 4; ++j) {
                const int t = qt * 16 + g * 4 + j;
                o[(rowbase + (size_t)(t >> 3) * 128 + (t & 7)) * 256
                  + h * 32 + dt * 16 + c] = f2bf(acc[qt][dt][j] * linv[qt]);
            }
}

// ---------------------------------------------------------------------------
// Transpose: xbT[b][c][n] = xb[b][n][c].
// ---------------------------------------------------------------------------
__launch_bounds__(256)
__global__ void tr_kernel(const u16* __restrict__ src, u16* __restrict__ dst) {
    __shared__ u16 T[64][72];
    const int b = blockIdx.z;
    const int n0 = blockIdx.x * 64, c0 = blockIdx.y * 64;
    const int r = threadIdx.x >> 3, cc = (threadIdx.x & 7) * 8;
    const u16* S = src + (size_t)b * 16384 * 256;
    u16* D = dst + (size_t)b * 256 * 16384;
    #pragma unroll
    for (int rr = 0; rr < 64; rr += 32)
        *(u16x8*)&T[r + rr][cc] = *(const u16x8*)&S[(size_t)(n0 + r + rr) * 256 + c0 + cc];
    __syncthreads();
    #pragma unroll
    for (int rr = 0; rr < 64; rr += 32) {
        u16x8 v;
        #pragma unroll
        for (int k2 = 0; k2 < 8; ++k2) v[k2] = T[cc + k2][r + rr];
        *(u16x8*)&D[(size_t)(c0 + r + rr) * 16384 + n0 + cc] = v;
    }
}

// ---------------------------------------------------------------------------
// MFMA flash cross-attention: max-free softmax, denominator via ones-MFMA,
// 128 queries/wave (8 q-subtiles share each K/V load), KSPLIT=32.
// ---------------------------------------------------------------------------
__launch_bounds__(256)
__global__ void ca_flash(const u16* __restrict__ qb, const u16* __restrict__ xb,
                         const u16* __restrict__ xbT, float* __restrict__ pbuf) {
    const int wid = blockIdx.x * 4 + (threadIdx.x >> 6);   // 0..2047
    const int lane = threadIdx.x & 63;
    const int ks = wid & 31, qt = (wid >> 5) & 3, h = (wid >> 7) & 7, b = wid >> 10;
    const int g = lane >> 4, c = lane & 15;
    const int kp0 = 8 * (c >> 2) + (c & 3);    // permuted key row for this lane

    s16x8 qf[8];
    #pragma unroll
    for (int nt = 0; nt < 8; ++nt) {
        const int q = qt * 128 + nt * 16 + c;
        qf[nt] = *(const s16x8*)&qb[((size_t)q * 2 + b) * 256 + h * 32 + g * 8];
    }
    const u16* Kb = xb  + (size_t)b * 16384 * 256 + h * 32;
    const u16* Vb = xbT + (size_t)b * 256 * 16384 + (size_t)(h * 32) * 16384;

    s16x8 ones;
    #pragma unroll
    for (int j = 0; j < 8; ++j) ones[j] = (short)0x3F80;   // bf16 1.0

    f32x4 acc[2][8];    // [d-tile][q-subtile]
    f32x4 accl[8];      // denominator rows per q-subtile
    #pragma unroll
    for (int j = 0; j < 8; ++j) {
        acc[0][j] = f32x4{0.f,0.f,0.f,0.f};
        acc[1][j] = f32x4{0.f,0.f,0.f,0.f};
        accl[j]   = f32x4{0.f,0.f,0.f,0.f};
    }

    const int base = ks * 512;
    const f32x4 zero = f32x4{0.f, 0.f, 0.f, 0.f};
    for (int step = 0; step < 16; ++step) {
        const int n0 = base + step * 32;
        const s16x8 kf0 = *(const s16x8*)&Kb[(size_t)(n0 + kp0) * 256 + g * 8];
        const s16x8 kf1 = *(const s16x8*)&Kb[(size_t)(n0 + kp0 + 4) * 256 + g * 8];
        const s16x8 vf0 = *(const s16x8*)&Vb[(size_t)c * 16384 + n0 + g * 8];
        const s16x8 vf1 = *(const s16x8*)&Vb[(size_t)(16 + c) * 16384 + n0 + g * 8];
        #pragma unroll
        for (int nt = 0; nt < 8; ++nt) {
            const f32x4 sa = __builtin_amdgcn_mfma_f32_16x16x32_bf16(kf0, qf[nt], zero, 0, 0, 0);
            const f32x4 sb = __builtin_amdgcn_mfma_f32_16x16x32_bf16(kf1, qf[nt], zero, 0, 0, 0);
            u32x4 w;
            w[0] = cvtpk(EXP2F(sa[0]), EXP2F(sa[1]));
            w[1] = cvtpk(EXP2F(sa[2]), EXP2F(sa[3]));
            w[2] = cvtpk(EXP2F(sb[0]), EXP2F(sb[1]));
            w[3] = cvtpk(EXP2F(sb[2]), EXP2F(sb[3]));
            const s16x8 pf = __builtin_bit_cast(s16x8, w);
            acc[0][nt] = __builtin_amdgcn_mfma_f32_16x16x32_bf16(vf0, pf, acc[0][nt], 0, 0, 0);
            acc[1][nt] = __builtin_amdgcn_mfma_f32_16x16x32_bf16(vf1, pf, acc[1][nt], 0, 0, 0);
            accl[nt]   = __builtin_amdgcn_mfma_f32_16x16x32_bf16(ones, pf, accl[nt], 0, 0, 0);
        }
    }

    // pbuf wave record (4224 f32): [0..127] = l per query, [128..4223] = O^T
    float* P = pbuf + (size_t)wid * 4224;
    if (g == 0) {
        #pragma unroll
        for (int nt = 0; nt < 8; ++nt)
            P[nt * 16 + c] = accl[nt][0];
    }
    #pragma unroll
    for (int mi = 0; mi < 2; ++mi)
        #pragma unroll
        for (int nt = 0; nt < 8; ++nt)
            *(f32x4*)&P[128 + (c + 16*nt) * 32 + 16*mi + g*4] = acc[mi][nt];
}

// ---------------------------------------------------------------------------
// Merge 32 key-split partials: plain sums (no exp, no max).
// ---------------------------------------------------------------------------
__launch_bounds__(256)
__global__ void ca_merge(const float* __restrict__ pbuf, u16* __restrict__ ctx) {
    const int wave = threadIdx.x >> 6, lane = threadIdx.x & 63;
    const int sub = lane >> 5, d = lane & 31;
    const int rowid = blockIdx.x * 8 + wave * 2 + sub;     // 0..8191
    const int t = rowid & 511, h = (rowid >> 9) & 7, b = rowid >> 12;
    const int qt = t >> 7, qq = t & 127;
    const size_t w0 = (size_t)((b * 8 + h) * 4 + qt) * 32;
    float L = 0.f, o = 0.f;
    #pragma unroll
    for (int i = 0; i < 32; ++i) {
        L += pbuf[(w0 + i) * 4224 + qq];
        o += pbuf[(w0 + i) * 4224 + 128 + qq * 32 + d];
    }
    ctx[((size_t)b * 512 + t) * 256 + h * 32 + d] = f2bf(o / L);
}

// ---------------------------------------------------------------------------
// Final: out = LN(query + ctx^T).
// ---------------------------------------------------------------------------
__launch_bounds__(256)
__global__ void final_ln(const float* __restrict__ query, const u16* __restrict__ ctx4,
                         const float* __restrict__ g, const float* __restrict__ b,
                         float* __restrict__ out) {
    const int wave = threadIdx.x >> 6, lane = threadIdx.x & 63;
    const int row = blockIdx.x * 4 + wave;        // 0..1023 = t*2+bb
    const int t = row >> 1, bb = row & 1;
    const int c = lane * 4;
    float4 rq = *(const float4*)(query + (size_t)row * 256 + c);
    u16x4 rc = *(const u16x4*)(ctx4 + ((size_t)bb * 512 + t) * 256 + c);
    float x0 = rq.x + bf2f(rc[0]);
    float x1 = rq.y + bf2f(rc[1]);
    float x2 = rq.z + bf2f(rc[2]);
    float x3 = rq.w + bf2f(rc[3]);
    float s1 = x0 + x1 + x2 + x3;
    float s2 = x0*x0 + x1*x1 + x2*x2 + x3*x3;
    #pragma unroll
    for (int off = 32; off; off >>= 1) {
        s1 += __shfl_xor(s1, off);
        s2 += __shfl_xor(s2, off);
    }
    const float mean = s1 * (1.f/256.f);
    const float var  = s2 * (1.f/256.f) - mean*mean;
    const float rstd = rsqrtf(var + 1e-5f);
    float4 gg = *(const float4*)(g + c);
    float4 bv = *(const float4*)(b + c);
    float4 og;
    og.x = (x0-mean)*rstd*gg.x + bv.x;
    og.y = (x1-mean)*rstd*gg.y + bv.y;
    og.z = (x2-mean)*rstd*gg.z + bv.z;
    og.w = (x3-mean)*rstd*gg.w + bv.w;
    *(float4*)(out + (size_t)row * 256 + c) = og;
}

// ---------------------------------------------------------------------------

extern "C" void kernel_launch(void* const* d_in, const int* in_sizes, int n_in,
                              void* d_out, int out_size, void* d_ws, size_t ws_size,
                              hipStream_t stream) {
    const float* x_in  = (const float*)d_in[0];
    const float* query = (const float*)d_in[1];
    const float* n1_g  = (const float*)d_in[2];
    const float* n1_b  = (const float*)d_in[3];
    const float* qkv_w = (const float*)d_in[4];
    const float* qkv_b = (const float*)d_in[5];
    const float* out_w = (const float*)d_in[6];
    const float* out_b = (const float*)d_in[7];
    const float* rel   = (const float*)d_in[8];
    const float* n2_g  = (const float*)d_in[9];
    const float* n2_b  = (const float*)d_in[10];
    const float* fc1_w = (const float*)d_in[11];
    const float* fc1_b = (const float*)d_in[12];
    const float* fc2_w = (const float*)d_in[13];
    const float* fc2_b = (const float*)d_in[14];
    const float* can_g = (const float*)d_in[15];
    const float* can_b = (const float*)d_in[16];
    const float* cpq_w = (const float*)d_in[17];
    const float* cfc_w = (const float*)d_in[18];
    const float* cfc_b = (const float*)d_in[19];
    const float* cf1_w = (const float*)d_in[20];
    const float* cf1_b = (const float*)d_in[21];
    const float* cf2_w = (const float*)d_in[22];
    const float* cf2_b = (const float*)d_in[23];

    const int M = 32768;   // 2 * 128 * 128 tokens

    char* w = (char*)d_ws;
    float* xs  = (float*)w;  w += (size_t)M * 256 * 4;        // fp32 residual stream
    u16* hbuf  = (u16*)w;    w += (size_t)M * 256 * 2;        // bf16 LN/attn out
    u16* big   = (u16*)w;    w += (size_t)M * 1024 * 2;       // bf16 qkv / mlp hidden
    u16* arena = (u16*)w;    w += (size_t)2228224 * 2;        // bf16 weights + query
    u16* qbuf  = (u16*)w;    w += 524288;
    u16* ctx1  = (u16*)w;    w += 524288;
    u16* ctx2  = (u16*)w;    w += 524288;
    u16* ctx3  = (u16*)w;    w += 1048576;
    u16* ctx4  = (u16*)w;    w += 524288;
    u16* xb    = (u16*)w;    w += (size_t)M * 256 * 2;        // bf16 copy of final xs
    float* bfragb = (float*)w; w += 65536 * 4;                // bias C-fragments

    u16* vtbuf = big + (size_t)M * 768;                       // 16 MB (qkv tail)
    u16*   xbT  = big;                                        // (2,256,16384) 16 MB
    float* pbuf = (float*)(big + 8388608);                    // 2048 * 4224 f32 = 34.6 MB

    u16* wq   = arena;
    u16* wo   = arena + 393216;
    u16* wf1  = arena + 524288;
    u16* wf2  = arena + 1048576;
    u16* wcpq = arena + 1572864;
    u16* wcfc = arena + 1638400;
    u16* wcf1 = arena + 1703936;
    u16* wcf2 = arena + 1835008;
    u16* qcvt = arena + 1966080;

    cvt_weights<<<2176, 256, 0, stream>>>(qkv_w, out_w, fc1_w, fc2_w, cpq_w,
                                          cfc_w, cf1_w, cf2_w, query, arena);
    bias_frag_kernel<<<64, 256, 0, stream>>>(rel, bfragb);

    for (int i = 0; i < 2; ++i) {
        const float* src = (i == 0) ? x_in : xs;   // layer-0 reads input directly
        ln_kernel<<<M/4, 256, 0, stream>>>(src, hbuf, n1_g + i*256, n1_b + i*256, M);
        gemm128<7,false><<<dim3(6,256), 256, 0, stream>>>(
            hbuf, wq + (size_t)i*768*256, qkv_b + i*768, nullptr, big, vtbuf, M, 768, 256);
        win_attn<<<1024, 256, 0, stream>>>(big, vtbuf, bfragb, hbuf, i);
        gemm128<3,true><<<dim3(2,256), 256, 0, stream>>>(
            hbuf, wo + (size_t)i*65536, out_b + i*256, src, xs, nullptr, M, 256, 256);
        ln_kernel<<<M/4, 256, 0, stream>>>(xs, hbuf, n2_g + i*256, n2_b + i*256, M);
        gemm128<2,false><<<dim3(8,256), 256, 0, stream>>>(
            hbuf, wf1 + (size_t)i*262144, fc1_b + i*1024, nullptr, big, nullptr, M, 1024, 256);
        if (i == 0)
            gemm128<3,true><<<dim3(2,256), 256, 0, stream>>>(
                big, wf2, fc2_b, xs, xs, nullptr, M, 256, 1024);
        else
            gemm128<8,true><<<dim3(2,256), 256, 0, stream>>>(
                big, wf2 + 262144, fc2_b + 256, xs, xs, xb, M, 256, 1024);
    }

    // ---- cross-attention ----
    tr_kernel<<<dim3(256, 4, 2), 256, 0, stream>>>(xb, xbT);
    gemm_bt<6><<<dim3(4, 16), 256, 0, stream>>>(qcvt, wcpq, nullptr, qbuf, 1024, 256, 256);
    ca_flash<<<512, 256, 0, stream>>>(qbuf, xb, xbT, pbuf);
    ca_merge<<<1024, 256, 0, stream>>>(pbuf, ctx1);
    gemm_bt<5><<<dim3(4, 16), 256, 0, stream>>>(ctx1, wcfc, cfc_b, ctx2, 1024, 256, 256);
    gemm_bt<4><<<dim3(8, 16), 256, 0, stream>>>(ctx2, wcf1, cf1_b, ctx3, 1024, 512, 256);
    gemm_bt<1><<<dim3(4, 16), 256, 0, stream>>>(ctx3, wcf2, cf2_b, ctx4, 1024, 256, 512);
    final_ln<<<256, 256, 0, stream>>>(query, ctx4, can_g, can_b, (float*)d_out);

    (void)in_sizes; (void)n_in; (void)out_size; (void)ws_size;
}